// Round 3
// baseline (14133.438 us; speedup 1.0000x reference)
//
#include <hip/hip_runtime.h>
#include <hip/hip_cooperative_groups.h>
#include <math.h>

#define B_   8
#define S_   64
#define N_   100
#define D_   1024
#define ND_  768
#define BN_  800
#define G3_  3072
#define HC7  7168
#define NBLK 512
#define RSC  0.00390625f   // 1/256 — Wmi stored x256 to avoid fp16 subnormals

typedef _Float16 f16x8 __attribute__((ext_vector_type(8)));
typedef float f32x4 __attribute__((ext_vector_type(4)));

namespace cg = cooperative_groups;

#define MFMA16(a,b,c) __builtin_amdgcn_mfma_f32_16x16x32_f16(a, b, c, 0, 0, 0)

static __device__ __forceinline__ float wave_sum(float v) {
    for (int off = 32; off > 0; off >>= 1) v += __shfl_down(v, off, 64);
    return v;
}

static __device__ __forceinline__ float wave_allsum(float v) {
    for (int off = 1; off < 64; off <<= 1) v += __shfl_xor(v, off, 64);
    return v;
}

// All 256 threads must call; returns full-block sum to every thread.
static __device__ __forceinline__ float block_sum(float v) {
    __shared__ float red_[8];
    float w = wave_sum(v);
    int lane = threadIdx.x & 63, wid = threadIdx.x >> 6;
    __syncthreads();               // protect red_ reuse across calls
    if (lane == 0) red_[wid] = w;
    __syncthreads();
    float t = 0.f;
    for (int i = 0; i < 4; ++i) t += red_[i];
    return t;
}

static __device__ __forceinline__ float gelu_f(float x) {
    return 0.5f * x * (1.f + erff(x * 0.70710678118654752f));
}

static __device__ __forceinline__ unsigned short f2h(float x) {
    union { _Float16 h; unsigned short u; } c; c.h = (_Float16)x; return c.u;
}

// ---------------------------------------------------------------------------
// fp32 -> fp16 2D convert. cols % 4 == 0.
// ---------------------------------------------------------------------------
__global__ __launch_bounds__(256) void k_f2h(
    const float* __restrict__ src, unsigned short* __restrict__ dst,
    int rows, int cols, int ldd)
{
    size_t n = (size_t)rows * cols;
    size_t i = ((size_t)blockIdx.x * 256 + threadIdx.x) * 4;
    if (i >= n) return;
    int r = (int)(i / cols);
    int c = (int)(i - (size_t)r * cols);
    float4 v = *(const float4*)(src + i);
    ushort4 o; o.x = f2h(v.x); o.y = f2h(v.y); o.z = f2h(v.z); o.w = f2h(v.w);
    *(ushort4*)(dst + (size_t)r * ldd + c) = o;
}

// ---------------------------------------------------------------------------
// fp32 -> fp16 TRANSPOSING convert: dst[rowoff + c][r] = src[r][c].
// ---------------------------------------------------------------------------
__global__ __launch_bounds__(256) void k_f2hT(
    const float* __restrict__ src, unsigned short* __restrict__ dst,
    int R, int C, int ldd, int rowoff)
{
    __shared__ _Float16 T[32][33];
    int tr = threadIdx.x >> 3, tc4 = (threadIdx.x & 7) * 4;
    int r0 = blockIdx.y * 32, c0 = blockIdx.x * 32;
    float4 v = *(const float4*)(src + (size_t)(r0 + tr) * C + c0 + tc4);
    T[tc4][tr] = (_Float16)v.x; T[tc4+1][tr] = (_Float16)v.y;
    T[tc4+2][tr] = (_Float16)v.z; T[tc4+3][tr] = (_Float16)v.w;
    __syncthreads();
    union { _Float16 h; unsigned short u; } cv;
    ushort4 o;
    cv.h = T[tr][tc4];   o.x = cv.u;
    cv.h = T[tr][tc4+1]; o.y = cv.u;
    cv.h = T[tr][tc4+2]; o.z = cv.u;
    cv.h = T[tr][tc4+3]; o.w = cv.u;
    *(ushort4*)(dst + (size_t)(rowoff + c0 + tr) * ldd + r0 + tc4) = o;
}

// ---------------------------------------------------------------------------
// FP16 MFMA GEMM (setup/epilogue only): C[M,Nc] = A16[M,K] @ W16[Nc,K]^T.
// TM=64, TN=128. If C16 != null: writes f2h(acc*oscale). Else fp32 + bias.
// ---------------------------------------------------------------------------
__global__ __launch_bounds__(256) void k_mfma16_nt(
    const unsigned short* __restrict__ A16, const unsigned short* __restrict__ W16,
    const float* __restrict__ bias, float* __restrict__ C,
    unsigned short* __restrict__ C16, float oscale,
    int M, int Nc, int K)
{
    int m0 = blockIdx.y * 64; if (m0 >= M) return;
    int n0 = blockIdx.x * 128;
    __shared__ _Float16 sA[64][72];
    __shared__ _Float16 sB[128][72];
    int tid = threadIdx.x;
    int w = tid >> 6, l = tid & 63;
    int l15 = l & 15, q = l >> 4;
    int wn = w * 32;
    int arow = tid >> 3, achk = (tid & 7) * 8;
    f32x4 acc[4][2] = {};
    for (int k0 = 0; k0 < K; k0 += 64) {
        for (int ri = 0; ri < 64; ri += 32) {
            int gm = m0 + arow + ri;
            uint4 v = make_uint4(0u, 0u, 0u, 0u);
            if (gm < M) v = *(const uint4*)(A16 + (size_t)gm * K + k0 + achk);
            *(uint4*)(&sA[arow + ri][achk]) = v;
        }
        for (int i = 0; i < 4; ++i) {
            int r = arow + 32 * i;
            *(uint4*)(&sB[r][achk]) = *(const uint4*)(W16 + (size_t)(n0 + r) * K + k0 + achk);
        }
        __syncthreads();
#pragma unroll
        for (int ks = 0; ks < 64; ks += 32) {
            f16x8 b0 = *(const f16x8*)(&sB[wn + l15][ks + q*8]);
            f16x8 b1 = *(const f16x8*)(&sB[wn + 16 + l15][ks + q*8]);
#pragma unroll
            for (int mi = 0; mi < 4; ++mi) {
                f16x8 a = *(const f16x8*)(&sA[mi*16 + l15][ks + q*8]);
                acc[mi][0] = MFMA16(a, b0, acc[mi][0]);
                acc[mi][1] = MFMA16(a, b1, acc[mi][1]);
            }
        }
        __syncthreads();
    }
    for (int mi = 0; mi < 4; ++mi)
        for (int nj = 0; nj < 2; ++nj)
            for (int r = 0; r < 4; ++r) {
                int gm = m0 + mi*16 + q*4 + r;
                int cl = wn + nj*16 + l15;
                if (gm < M) {
                    size_t off = (size_t)gm * Nc + n0 + cl;
                    float v = acc[mi][nj][r];
                    if (C16) C16[off] = f2h(v * oscale);
                    else C[off] = v + (bias ? bias[n0 + cl] : 0.f);
                }
            }
}

// ---------------------------------------------------------------------------
// h0 = mask * (type_embed[type] + LN(P, name_ln)); fp32 h + fp16 mirror
// ---------------------------------------------------------------------------
__global__ __launch_bounds__(256) void k_h0(
    const float* __restrict__ P, const int* __restrict__ etype,
    const int* __restrict__ emask, const float* __restrict__ temb,
    const float* __restrict__ g, const float* __restrict__ bt,
    float* __restrict__ h, unsigned short* __restrict__ h16)
{
    int bn = blockIdx.x, tid = threadIdx.x;
    int t = etype[bn], mk = emask[bn];
    float x[4]; float lsum = 0.f;
    for (int k = 0; k < 4; ++k) { x[k] = P[(size_t)bn*D_ + tid + 256*k]; lsum += x[k]; }
    float mean = block_sum(lsum) * (1.f / D_);
    float lv = 0.f;
    for (int k = 0; k < 4; ++k) { float d = x[k] - mean; lv += d * d; }
    float inv = rsqrtf(block_sum(lv) * (1.f / D_) + 1e-5f);
    for (int k = 0; k < 4; ++k) {
        int d = tid + 256*k;
        float y = (x[k] - mean) * inv * g[d] + bt[d];
        float hv = mk ? (temb[(size_t)t*D_ + d] + y) : 0.f;
        h[(size_t)bn*D_ + d] = hv;
        h16[(size_t)bn*D_ + d] = f2h(hv);
    }
}

// ---------------------------------------------------------------------------
// Hcat init: Hcat[bn, 0:1024|1024:4096|4096:7168] = h16[bn] @ [n2e|Wmi2|Whh]^T
// Grid (112, 25). TM=32, TN=64.
// ---------------------------------------------------------------------------
__global__ __launch_bounds__(256) void k_hcat0(
    const unsigned short* __restrict__ h16, const unsigned short* __restrict__ n2e16,
    const unsigned short* __restrict__ Wmi16, const unsigned short* __restrict__ Whh16,
    float* __restrict__ Hcat)
{
    int m0 = blockIdx.y * 32;
    int n0 = blockIdx.x * 64;
    const unsigned short* Bp; int ldb; int nl;
    if (n0 < 1024)      { Bp = n2e16;        ldb = D_;  nl = n0; }
    else if (n0 < 4096) { Bp = Wmi16 + 2048; ldb = G3_; nl = n0 - 1024; }
    else                { Bp = Whh16;        ldb = D_;  nl = n0 - 4096; }
    __shared__ _Float16 sA[32][72];
    __shared__ _Float16 sB[64][72];
    int tid = threadIdx.x;
    int w = tid >> 6, l = tid & 63;
    int l15 = l & 15, q = l >> 4;
    int wm = (w & 1) * 16, wn = (w >> 1) * 32;
    int arow = tid >> 3, achk = (tid & 7) * 8;
    int gmA = m0 + arow;
    f32x4 acc[2] = {};
    for (int k0 = 0; k0 < D_; k0 += 64) {
        *(uint4*)(&sA[arow][achk]) = *(const uint4*)(h16 + (size_t)gmA*D_ + k0 + achk);
        *(uint4*)(&sB[arow][achk])      = *(const uint4*)(Bp + (size_t)(nl + arow)*ldb + k0 + achk);
        *(uint4*)(&sB[arow + 32][achk]) = *(const uint4*)(Bp + (size_t)(nl + arow + 32)*ldb + k0 + achk);
        __syncthreads();
#pragma unroll
        for (int ks = 0; ks < 64; ks += 32) {
            f16x8 a  = *(const f16x8*)(&sA[wm + l15][ks + q*8]);
            f16x8 b0 = *(const f16x8*)(&sB[wn + l15][ks + q*8]);
            f16x8 b1 = *(const f16x8*)(&sB[wn + 16 + l15][ks + q*8]);
            acc[0] = MFMA16(a, b0, acc[0]);
            acc[1] = MFMA16(a, b1, acc[1]);
        }
        __syncthreads();
    }
    for (int j = 0; j < 2; ++j)
        for (int r = 0; r < 4; ++r) {
            int row = wm + q*4 + r;
            Hcat[(size_t)(m0 + row)*HC7 + n0 + wn + j*16 + l15] = acc[j][r];
        }
}

// ---------------------------------------------------------------------------
// K_front (fallback): blocks [0,800) rows; [800, 800+112*13) Hcat GEMM.
// ---------------------------------------------------------------------------
__global__ __launch_bounds__(256) void k_front(
    const float* __restrict__ inc, const int* __restrict__ emask,
    const float* __restrict__ Esmi, float* __restrict__ arcsum,
    int* __restrict__ cntp, int* __restrict__ lst, float* __restrict__ rro,
    float* __restrict__ scl,
    const int* __restrict__ prevcnt, const int* __restrict__ prevlist,
    const unsigned short* __restrict__ h16, const unsigned short* __restrict__ n2e16,
    const unsigned short* __restrict__ Wmi16, const unsigned short* __restrict__ Whh16,
    float* __restrict__ Hcat, float* __restrict__ gatepre,
    float* __restrict__ esumP, float* __restrict__ TmiP, float* __restrict__ wsumP,
    int s)
{
    int tid = threadIdx.x, bid = blockIdx.x;
    if (bid == 0 && tid < 32) gatepre[tid] = 0.f;
    if (bid < BN_) {
        int m = bid;
        int b = m / N_;
        float r = emask[m] ? inc[(size_t)m*S_ + s] : 0.f;
        if (r <= 0.f) return;
        __shared__ int sidx, nwa;
        __shared__ float wav[S_]; __shared__ int wai[S_];
        if (tid == 0) { sidx = atomicAdd(cntp, 1); nwa = 0; }
        __syncthreads();
        int idx = sidx;
        float denomA = fmaxf((float)(s - 1), 1.f);
        float wa = 0.f;
        if (tid < s) {
            float iv = inc[(size_t)m*S_ + tid];
            if (iv > 0.f) {
                wa = iv * r * expf(-1.f + (float)tid / denomA);
                int p = atomicAdd(&nwa, 1);
                wav[p] = wa; wai[p] = tid;
            }
        }
        float dA = block_sum(wa);
        float rm = 0.f;
        if (tid < N_) rm = emask[b*N_ + tid] ? inc[((size_t)b*N_ + tid)*S_ + s] : 0.f;
        float wsum = block_sum(rm);
        __syncthreads();
        int na = nwa;
        float sclA = 1.f / fmaxf(dA, 1e-8f);
        if (tid == 0) {
            lst[idx] = m; rro[idx] = r;
            scl[idx] = r / fmaxf(r * (wsum - r), 1e-8f);
            wsumP[b] = wsum;
        }
        float rprev = (s > 0) ? inc[(size_t)m*S_ + (s-1)] : 0.f;
        if (rprev <= 0.f) {
            const float4* hp = (const float4*)(Hcat + (size_t)m*HC7);
#pragma unroll
            for (int j2 = 0; j2 < 4; ++j2) {
                float4 hv = hp[tid + 256*j2];
                int c = (tid + 256*j2) * 4;
                float* dst = (c < 1024) ? (esumP + (size_t)b*D_ + c)
                                        : (TmiP + (size_t)b*G3_ + (c - 1024));
                atomicAdd(dst + 0, r*hv.x); atomicAdd(dst + 1, r*hv.y);
                atomicAdd(dst + 2, r*hv.z); atomicAdd(dst + 3, r*hv.w);
            }
        }
        float a12[12];
#pragma unroll
        for (int k = 0; k < 12; ++k) a12[k] = 0.f;
        for (int j = 0; j < na; ++j) {
            float wj = wav[j];
            const float* ep = Esmi + ((size_t)b*S_ + wai[j])*G3_;
#pragma unroll
            for (int k = 0; k < 12; ++k) a12[k] += wj * ep[tid + 256*k];
        }
        float* ao = arcsum + (size_t)idx*G3_;
#pragma unroll
        for (int k = 0; k < 12; ++k) ao[tid + 256*k] = a12[k] * sclA;
    } else {
        int pM = *prevcnt;
        int t = bid - BN_;
        int nt = t % 112, mt = t / 112;
        int m0 = mt * 64;
        if (m0 >= pM) return;
        int n0 = nt * 64;
        const unsigned short* Bp; int ldb; int nl;
        if (n0 < 1024)      { Bp = n2e16;        ldb = D_;  nl = n0; }
        else if (n0 < 4096) { Bp = Wmi16 + 2048; ldb = G3_; nl = n0 - 1024; }
        else                { Bp = Whh16;        ldb = D_;  nl = n0 - 4096; }
        __shared__ _Float16 sA[64][72];
        __shared__ _Float16 sB[64][72];
        __shared__ int slist[64];
        __shared__ float srn[64];
        __shared__ int sbb[64];
        if (tid < 64) {
            int gm = m0 + tid;
            int m = (gm < pM) ? prevlist[gm] : 0;
            slist[tid] = m;
            float rn = 0.f;
            if (gm < pM) rn = emask[m] ? inc[(size_t)m*S_ + s] : 0.f;
            srn[tid] = rn;
            sbb[tid] = m / N_;
        }
        __syncthreads();
        int w = tid >> 6, l = tid & 63;
        int l15 = l & 15, q = l >> 4;
        int wm = (w & 1) * 32, wn = (w >> 1) * 32;
        int arow = tid >> 3, achk = (tid & 7) * 8;
        f32x4 acc[2][2] = {};
        for (int k0 = 0; k0 < D_; k0 += 64) {
            for (int ri = 0; ri < 64; ri += 32) {
                int row = arow + ri, gm = m0 + row;
                uint4 v = make_uint4(0u,0u,0u,0u);
                if (gm < pM) v = *(const uint4*)(h16 + (size_t)slist[row]*D_ + k0 + achk);
                *(uint4*)(&sA[row][achk]) = v;
            }
            *(uint4*)(&sB[arow][achk])      = *(const uint4*)(Bp + (size_t)(nl + arow)*ldb + k0 + achk);
            *(uint4*)(&sB[arow + 32][achk]) = *(const uint4*)(Bp + (size_t)(nl + arow + 32)*ldb + k0 + achk);
            __syncthreads();
#pragma unroll
            for (int ks = 0; ks < 64; ks += 32) {
                f16x8 a0 = *(const f16x8*)(&sA[wm + l15][ks + q*8]);
                f16x8 a1 = *(const f16x8*)(&sA[wm + 16 + l15][ks + q*8]);
                f16x8 b0 = *(const f16x8*)(&sB[wn + l15][ks + q*8]);
                f16x8 b1 = *(const f16x8*)(&sB[wn + 16 + l15][ks + q*8]);
                acc[0][0] = MFMA16(a0, b0, acc[0][0]);
                acc[0][1] = MFMA16(a0, b1, acc[0][1]);
                acc[1][0] = MFMA16(a1, b0, acc[1][0]);
                acc[1][1] = MFMA16(a1, b1, acc[1][1]);
            }
            __syncthreads();
        }
        for (int mi = 0; mi < 2; ++mi)
            for (int nj = 0; nj < 2; ++nj)
                for (int r = 0; r < 4; ++r) {
                    int row = wm + mi*16 + q*4 + r;
                    int gm = m0 + row;
                    if (gm < pM) {
                        float v = acc[mi][nj][r];
                        int c = n0 + wn + nj*16 + l15;
                        Hcat[(size_t)slist[row]*HC7 + c] = v;
                        float rn = srn[row];
                        if (rn > 0.f && c < 4096) {
                            float* dst = (c < 1024)
                                ? (esumP + (size_t)sbb[row]*D_ + c)
                                : (TmiP + (size_t)sbb[row]*G3_ + (c - 1024));
                            atomicAdd(dst, rn * v);
                        }
                    }
                }
    }
}

// ---------------------------------------------------------------------------
// K_mid (fallback, grid 128): [0,32) light e_s + gate; [32,128) Emi/Esmi.
// ---------------------------------------------------------------------------
__global__ __launch_bounds__(256) void k_mid(
    const float* __restrict__ esumP, const float* __restrict__ wsumP,
    float* __restrict__ esumZ, float* __restrict__ TmiZ, float* __restrict__ wsumZ,
    const float* __restrict__ n2eb, const float* __restrict__ pre_t2e,
    const float* __restrict__ elng, const float* __restrict__ elnb,
    const float* __restrict__ gW1, const float* __restrict__ gb1,
    const float* __restrict__ gW2, const unsigned short* __restrict__ Wmi16,
    float* __restrict__ esbuf, float* __restrict__ gatepre,
    float* __restrict__ Emi, float* __restrict__ Esmi,
    int* __restrict__ ctrl, int par, int s)
{
    int bid = blockIdx.x, tid = threadIdx.x;
    if (bid < 32) {
        __shared__ float se[D_];
        int b = bid >> 2, seg = bid & 3;
        if (bid == 0 && tid == 0) ctrl[1 - par] = 0;
        esumZ[(size_t)b*D_ + seg*256 + tid] = 0.f;
#pragma unroll
        for (int j = 0; j < 3; ++j) TmiZ[(size_t)b*G3_ + seg*768 + j*256 + tid] = 0.f;
        if (seg == 0 && tid == 0) wsumZ[b] = 0.f;
        float invw = 1.f / fmaxf(wsumP[b], 1.f);
        float4 ev = ((const float4*)(esumP + (size_t)b*D_))[tid];
        float4 nb = ((const float4*)n2eb)[tid];
        float4 pt = ((const float4*)(pre_t2e + ((size_t)b*S_ + s)*D_))[tid];
        float x[4] = { ev.x*invw + nb.x + pt.x, ev.y*invw + nb.y + pt.y,
                       ev.z*invw + nb.z + pt.z, ev.w*invw + nb.w + pt.w };
        float mean = block_sum(x[0]+x[1]+x[2]+x[3]) * (1.f / D_);
        float lv = 0.f;
#pragma unroll
        for (int k = 0; k < 4; ++k) { float d = x[k] - mean; lv += d * d; }
        float inv = rsqrtf(block_sum(lv) * (1.f / D_) + 1e-5f);
        float4 lg = ((const float4*)elng)[tid];
        float4 lb = ((const float4*)elnb)[tid];
        float y0 = (x[0]-mean)*inv*lg.x + lb.x;
        float y1 = (x[1]-mean)*inv*lg.y + lb.y;
        float y2 = (x[2]-mean)*inv*lg.z + lb.z;
        float y3 = (x[3]-mean)*inv*lg.w + lb.w;
        int d4 = tid * 4;
        se[d4] = y0; se[d4+1] = y1; se[d4+2] = y2; se[d4+3] = y3;
        if (seg == 0)
            ((float4*)(esbuf + ((size_t)b*S_ + s)*D_))[tid] = make_float4(y0,y1,y2,y3);
        __syncthreads();
        if (tid < 64) {
            int u = seg * 64 + tid;
            float acc = gb1[u];
            const float* w1 = gW1 + (size_t)u * D_;
            for (int j = 0; j < D_; j += 4) {
                float4 w = *(const float4*)(w1 + j);
                acc += w.x*se[j] + w.y*se[j+1] + w.z*se[j+2] + w.w*se[j+3];
            }
            float hg = gelu_f(acc);
            for (int c = 0; c < 3; ++c) {
                float p = wave_sum(gW2[c*256 + u] * hg);
                if (tid == 0) atomicAdd(gatepre + b*4 + c, p);
            }
        }
    } else {
        __shared__ float se32[8][1028];
        int w = tid >> 6, lane = tid & 63;
        for (int bb = 0; bb < 2; ++bb) {
            int b = w*2 + bb;
            float invw = 1.f / fmaxf(wsumP[b], 1.f);
            int d0 = lane * 16;
            const float4* ep = (const float4*)(esumP + (size_t)b*D_ + d0);
            const float4* np = (const float4*)(n2eb + d0);
            const float4* pp = (const float4*)(pre_t2e + ((size_t)b*S_ + s)*D_ + d0);
            float x[16]; float sm = 0.f;
#pragma unroll
            for (int j = 0; j < 4; ++j) {
                float4 e = ep[j], n = np[j], p = pp[j];
                x[j*4+0] = e.x*invw + n.x + p.x;
                x[j*4+1] = e.y*invw + n.y + p.y;
                x[j*4+2] = e.z*invw + n.z + p.z;
                x[j*4+3] = e.w*invw + n.w + p.w;
                sm += x[j*4+0] + x[j*4+1] + x[j*4+2] + x[j*4+3];
            }
            float mean = wave_allsum(sm) * (1.f / D_);
            float lv = 0.f;
#pragma unroll
            for (int j = 0; j < 16; ++j) { float d = x[j] - mean; lv += d * d; }
            float inv = rsqrtf(wave_allsum(lv) * (1.f / D_) + 1e-5f);
            const float4* lgp = (const float4*)(elng + d0);
            const float4* lbp = (const float4*)(elnb + d0);
#pragma unroll
            for (int j = 0; j < 4; ++j) {
                float4 lg = lgp[j], lb = lbp[j];
                se32[b][d0 + j*4 + 0] = (x[j*4+0]-mean)*inv*lg.x + lb.x;
                se32[b][d0 + j*4 + 1] = (x[j*4+1]-mean)*inv*lg.y + lb.y;
                se32[b][d0 + j*4 + 2] = (x[j*4+2]-mean)*inv*lg.z + lb.z;
                se32[b][d0 + j*4 + 3] = (x[j*4+3]-mean)*inv*lg.w + lb.w;
            }
        }
        __syncthreads();
        int c0 = (bid - 32) * 32;
        int colg = tid >> 5, t31 = tid & 31;
        int cb = c0 + colg * 4;
        float accA[4][8] = {};
        float accB[4][8] = {};
#pragma unroll
        for (int i = 0; i < 8; ++i) {
            int kh = t31*4 + i*128;
            float wf[4][4];
#pragma unroll
            for (int c = 0; c < 4; ++c) {
                union { uint2 u; _Float16 h[4]; } cv;
                cv.u = *(const uint2*)(Wmi16 + (size_t)(cb + c)*G3_ + kh);
                wf[c][0] = (float)cv.h[0]; wf[c][1] = (float)cv.h[1];
                wf[c][2] = (float)cv.h[2]; wf[c][3] = (float)cv.h[3];
            }
#pragma unroll
            for (int b = 0; b < 8; ++b) {
                float4 sv = *(const float4*)(&se32[b][kh]);
#pragma unroll
                for (int c = 0; c < 4; ++c)
                    accA[c][b] += wf[c][0]*sv.x + wf[c][1]*sv.y
                                + wf[c][2]*sv.z + wf[c][3]*sv.w;
            }
        }
#pragma unroll
        for (int i = 0; i < 8; ++i) {
            int kh = t31*4 + i*128;
            float wf[4][4];
#pragma unroll
            for (int c = 0; c < 4; ++c) {
                union { uint2 u; _Float16 h[4]; } cv;
                cv.u = *(const uint2*)(Wmi16 + (size_t)(cb + c)*G3_ + 1024 + kh);
                wf[c][0] = (float)cv.h[0]; wf[c][1] = (float)cv.h[1];
                wf[c][2] = (float)cv.h[2]; wf[c][3] = (float)cv.h[3];
            }
#pragma unroll
            for (int b = 0; b < 8; ++b) {
                float4 sv = *(const float4*)(&se32[b][kh]);
#pragma unroll
                for (int c = 0; c < 4; ++c)
                    accB[c][b] += wf[c][0]*sv.x + wf[c][1]*sv.y
                                + wf[c][2]*sv.z + wf[c][3]*sv.w;
            }
        }
#pragma unroll
        for (int off = 16; off >= 1; off >>= 1) {
#pragma unroll
            for (int c = 0; c < 4; ++c)
#pragma unroll
                for (int b = 0; b < 8; ++b) {
                    accA[c][b] += __shfl_down(accA[c][b], off, 32);
                    accB[c][b] += __shfl_down(accB[c][b], off, 32);
                }
        }
        if (t31 == 0) {
#pragma unroll
            for (int c = 0; c < 4; ++c) {
                int col = cb + c;
#pragma unroll
                for (int b = 0; b < 8; ++b) {
                    Emi[(size_t)b*G3_ + col] = accA[c][b];
                    Esmi[((size_t)b*S_ + s)*G3_ + col] = accB[c][b];
                }
            }
        }
    }
}

// ---------------------------------------------------------------------------
// K_fin (fallback): GRU assembly + LN + clip + h update.
// ---------------------------------------------------------------------------
__global__ __launch_bounds__(256) void k_fin(
    const int* __restrict__ lst, const int* __restrict__ cntp,
    const float* __restrict__ rro, const float* __restrict__ scl,
    const float* __restrict__ gatepre, const float* __restrict__ gb2,
    const float* __restrict__ Hcat, const float* __restrict__ Emi,
    const float* __restrict__ arcsum, const float* __restrict__ Tmi,
    const float* __restrict__ gBm, const float* __restrict__ bih,
    const float* __restrict__ bhh,
    const float* __restrict__ ulng, const float* __restrict__ ulnb,
    float* __restrict__ h, unsigned short* __restrict__ h16, int s)
{
    int row = blockIdx.x;
    if (row >= *cntp) return;
    int bn = lst[row];
    int b = bn / N_;
    int tid = threadIdx.x;
    float t0 = gatepre[b*4+0] + gb2[0];
    float t1 = gatepre[b*4+1] + gb2[1];
    float t2 = gatepre[b*4+2] + gb2[2];
    float mx = fmaxf(t0, fmaxf(t1, t2));
    float e0 = expf(t0-mx), e1 = expf(t1-mx), e2 = expf(t2-mx);
    float si = 1.f / (e0 + e1 + e2);
    float g0 = e0*si, g1 = (s > 0) ? e1*si : 0.f, g2 = e2*si;
    float rv = rro[row];
    float sI = scl[row];
    const float* Hrow = Hcat + (size_t)bn * HC7;
    const float* em = Emi + (size_t)b * G3_;
    const float* as = arcsum + (size_t)row * G3_;
    const float* tm = Tmi + (size_t)b * G3_;
    float u[4]; float lsum = 0.f;
    for (int k = 0; k < 4; ++k) {
        int d = tid + 256*k;
        float ip[3];
#pragma unroll
        for (int c = 0; c < 3; ++c) {
            int dd = c*D_ + d;
            float gint = tm[dd] - rv * Hrow[1024 + dd];
            ip[c] = RSC * (g0*em[dd] + g1*as[dd] + g2*sI*gint)
                  + g0*gBm[dd] + g1*gBm[G3_ + dd] + g2*gBm[2*G3_ + dd]
                  + rv*gBm[3*G3_ + dd] + bih[dd];
        }
        float hr = Hrow[4096 + d]        + bhh[d];
        float hz = Hrow[4096 + D_ + d]   + bhh[D_ + d];
        float hn = Hrow[4096 + 2*D_ + d] + bhh[2*D_ + d];
        float hv = h[(size_t)bn*D_ + d];
        float r = 1.f / (1.f + expf(-(ip[0] + hr)));
        float z = 1.f / (1.f + expf(-(ip[1] + hz)));
        float nn = tanhf(ip[2] + r * hn);
        u[k] = (1.f - z) * nn + z * hv;
        lsum += u[k];
    }
    float mean = block_sum(lsum) * (1.f / D_);
    float lv = 0.f;
    for (int k = 0; k < 4; ++k) { float d = u[k] - mean; lv += d * d; }
    float inv = rsqrtf(block_sum(lv) * (1.f / D_) + 1e-5f);
    for (int k = 0; k < 4; ++k) {
        int d = tid + 256*k;
        float y = (u[k] - mean) * inv * ulng[d] + ulnb[d];
        y = fminf(fmaxf(y, -50.f), 50.f);
        h[(size_t)bn*D_ + d] = y;
        h16[(size_t)bn*D_ + d] = f2h(y);
    }
}

// ---------------------------------------------------------------------------
// Cooperative loop kernel: same dataflow as k_front/k_mid/k_fin, with
// grid.sync() replacing the kernel boundaries.
// ---------------------------------------------------------------------------
struct LoopA {
    const float* inc; const int* emask;
    float* Esmi; float* arcsum;
    int* ctrl; int* list2; float* rro2; float* scl;
    unsigned short* h16; float* hbuf;
    const unsigned short* n2e16; const unsigned short* Wmi16; const unsigned short* Whh16;
    float* Hcat; float* gatepre;
    float* esum2; float* Tmi2; float* wsum2;
    const float* pre_t2e; float* Emi; float* esbuf;
    const float* n2eb; const float* elng; const float* elnb;
    const float* gW1; const float* gb1; const float* gW2; const float* gb2;
    const float* gBm; const float* bih; const float* bhh;
    const float* ulng; const float* ulnb;
};

union SMu {
    struct { _Float16 A[64][72]; _Float16 Bm[64][72]; int slist[64]; float srn[64]; int sbb[64]; } g;
    struct { float se32[8][1028]; } e;
    struct { float se1[D_]; } t;
    struct { float wav[S_]; int wai[S_]; } r;
};

__global__ __launch_bounds__(256, 2) void k_loop(LoopA a)
{
    cg::grid_group grid = cg::this_grid();
    __shared__ SMu sm;
    __shared__ int sh_i0, sh_i1;
    int tid = threadIdx.x;
    int bid = blockIdx.x;
    int gdim = gridDim.x;

    for (int s = 0; s < S_; ++s) {
        int par = s & 1;
        int* cntp = a.ctrl + par;
        const int* pcnt = a.ctrl + (1 - par);
        int* lst = a.list2 + par * BN_;
        const int* plst = a.list2 + (1 - par) * BN_;
        float* rro = a.rro2 + par * BN_;
        float* esumP = a.esum2 + (size_t)par * B_ * D_;
        float* esumZ = a.esum2 + (size_t)(1 - par) * B_ * D_;
        float* TmiP  = a.Tmi2 + (size_t)par * B_ * G3_;
        float* TmiZ  = a.Tmi2 + (size_t)(1 - par) * B_ * G3_;
        const float* wsumP = a.wsum2 + par * 8;
        float* wsumPw = a.wsum2 + par * 8;
        float* wsumZ = a.wsum2 + (1 - par) * 8;

        // ================= PHASE 1 (k_front) =================
        for (int tk = bid; tk < BN_ + 112*13; tk += gdim) {
            __syncthreads();
            if (tk < BN_) {
                if (tk == 0 && tid < 32) a.gatepre[tid] = 0.f;
                int m = tk, b = m / N_;
                float r = a.emask[m] ? a.inc[(size_t)m*S_ + s] : 0.f;
                if (r > 0.f) {
                    if (tid == 0) { sh_i0 = atomicAdd(cntp, 1); sh_i1 = 0; }
                    __syncthreads();
                    int idx = sh_i0;
                    float denomA = fmaxf((float)(s - 1), 1.f);
                    float wa = 0.f;
                    if (tid < s) {
                        float iv = a.inc[(size_t)m*S_ + tid];
                        if (iv > 0.f) {
                            wa = iv * r * expf(-1.f + (float)tid / denomA);
                            int p = atomicAdd(&sh_i1, 1);
                            sm.r.wav[p] = wa; sm.r.wai[p] = tid;
                        }
                    }
                    float dA = block_sum(wa);
                    float rm = 0.f;
                    if (tid < N_) rm = a.emask[b*N_ + tid] ? a.inc[((size_t)b*N_ + tid)*S_ + s] : 0.f;
                    float wsum = block_sum(rm);
                    __syncthreads();
                    int na = sh_i1;
                    float sclA = 1.f / fmaxf(dA, 1e-8f);
                    if (tid == 0) {
                        lst[idx] = m; rro[idx] = r;
                        a.scl[idx] = r / fmaxf(r * (wsum - r), 1e-8f);
                        wsumPw[b] = wsum;
                    }
                    float rprev = (s > 0) ? a.inc[(size_t)m*S_ + (s-1)] : 0.f;
                    if (rprev <= 0.f) {
                        const float4* hp = (const float4*)(a.Hcat + (size_t)m*HC7);
#pragma unroll
                        for (int j2 = 0; j2 < 4; ++j2) {
                            float4 hv = hp[tid + 256*j2];
                            int c = (tid + 256*j2) * 4;
                            float* dst = (c < 1024) ? (esumP + (size_t)b*D_ + c)
                                                    : (TmiP + (size_t)b*G3_ + (c - 1024));
                            atomicAdd(dst + 0, r*hv.x); atomicAdd(dst + 1, r*hv.y);
                            atomicAdd(dst + 2, r*hv.z); atomicAdd(dst + 3, r*hv.w);
                        }
                    }
                    float a12[12];
#pragma unroll
                    for (int k = 0; k < 12; ++k) a12[k] = 0.f;
                    for (int j = 0; j < na; ++j) {
                        float wj = sm.r.wav[j];
                        const float* ep = a.Esmi + ((size_t)b*S_ + sm.r.wai[j])*G3_;
#pragma unroll
                        for (int k = 0; k < 12; ++k) a12[k] += wj * ep[tid + 256*k];
                    }
                    float* ao = a.arcsum + (size_t)idx*G3_;
#pragma unroll
                    for (int k = 0; k < 12; ++k) ao[tid + 256*k] = a12[k] * sclA;
                }
            } else {
                int pM = *pcnt;
                int t = tk - BN_;
                int nt = t % 112, mt = t / 112;
                int m0 = mt * 64;
                if (m0 < pM) {
                    int n0 = nt * 64;
                    const unsigned short* Bp; int ldb; int nl;
                    if (n0 < 1024)      { Bp = a.n2e16;        ldb = D_;  nl = n0; }
                    else if (n0 < 4096) { Bp = a.Wmi16 + 2048; ldb = G3_; nl = n0 - 1024; }
                    else                { Bp = a.Whh16;        ldb = D_;  nl = n0 - 4096; }
                    if (tid < 64) {
                        int gm = m0 + tid;
                        int m = (gm < pM) ? plst[gm] : 0;
                        sm.g.slist[tid] = m;
                        float rn = 0.f;
                        if (gm < pM) rn = a.emask[m] ? a.inc[(size_t)m*S_ + s] : 0.f;
                        sm.g.srn[tid] = rn;
                        sm.g.sbb[tid] = m / N_;
                    }
                    __syncthreads();
                    int w = tid >> 6, l = tid & 63;
                    int l15 = l & 15, q = l >> 4;
                    int wm = (w & 1) * 32, wn = (w >> 1) * 32;
                    int arow = tid >> 3, achk = (tid & 7) * 8;
                    f32x4 acc[2][2] = {};
                    for (int k0 = 0; k0 < D_; k0 += 64) {
                        for (int ri = 0; ri < 64; ri += 32) {
                            int row = arow + ri, gm = m0 + row;
                            uint4 v = make_uint4(0u,0u,0u,0u);
                            if (gm < pM) v = *(const uint4*)(a.h16 + (size_t)sm.g.slist[row]*D_ + k0 + achk);
                            *(uint4*)(&sm.g.A[row][achk]) = v;
                        }
                        *(uint4*)(&sm.g.Bm[arow][achk])      = *(const uint4*)(Bp + (size_t)(nl + arow)*ldb + k0 + achk);
                        *(uint4*)(&sm.g.Bm[arow + 32][achk]) = *(const uint4*)(Bp + (size_t)(nl + arow + 32)*ldb + k0 + achk);
                        __syncthreads();
#pragma unroll
                        for (int ks = 0; ks < 64; ks += 32) {
                            f16x8 a0 = *(const f16x8*)(&sm.g.A[wm + l15][ks + q*8]);
                            f16x8 a1 = *(const f16x8*)(&sm.g.A[wm + 16 + l15][ks + q*8]);
                            f16x8 b0 = *(const f16x8*)(&sm.g.Bm[wn + l15][ks + q*8]);
                            f16x8 b1 = *(const f16x8*)(&sm.g.Bm[wn + 16 + l15][ks + q*8]);
                            acc[0][0] = MFMA16(a0, b0, acc[0][0]);
                            acc[0][1] = MFMA16(a0, b1, acc[0][1]);
                            acc[1][0] = MFMA16(a1, b0, acc[1][0]);
                            acc[1][1] = MFMA16(a1, b1, acc[1][1]);
                        }
                        __syncthreads();
                    }
                    for (int mi = 0; mi < 2; ++mi)
                        for (int nj = 0; nj < 2; ++nj)
                            for (int r4 = 0; r4 < 4; ++r4) {
                                int row = wm + mi*16 + q*4 + r4;
                                int gm = m0 + row;
                                if (gm < pM) {
                                    float v = acc[mi][nj][r4];
                                    int c = n0 + wn + nj*16 + l15;
                                    a.Hcat[(size_t)sm.g.slist[row]*HC7 + c] = v;
                                    float rn = sm.g.srn[row];
                                    if (rn > 0.f && c < 4096) {
                                        float* dst = (c < 1024)
                                            ? (esumP + (size_t)sm.g.sbb[row]*D_ + c)
                                            : (TmiP + (size_t)sm.g.sbb[row]*G3_ + (c - 1024));
                                        atomicAdd(dst, rn * v);
                                    }
                                }
                            }
                }
            }
        }
        grid.sync();

        // ================= PHASE 2 (k_mid) =================
        for (int tk = bid; tk < 128; tk += gdim) {
            __syncthreads();
            if (tk < 32) {
                int b = tk >> 2, seg = tk & 3;
                if (tk == 0 && tid == 0) a.ctrl[1 - par] = 0;
                esumZ[(size_t)b*D_ + seg*256 + tid] = 0.f;
#pragma unroll
                for (int j = 0; j < 3; ++j) TmiZ[(size_t)b*G3_ + seg*768 + j*256 + tid] = 0.f;
                if (seg == 0 && tid == 0) wsumZ[b] = 0.f;
                float invw = 1.f / fmaxf(wsumP[b], 1.f);
                float4 ev = ((const float4*)(esumP + (size_t)b*D_))[tid];
                float4 nb = ((const float4*)a.n2eb)[tid];
                float4 pt = ((const float4*)(a.pre_t2e + ((size_t)b*S_ + s)*D_))[tid];
                float x[4] = { ev.x*invw + nb.x + pt.x, ev.y*invw + nb.y + pt.y,
                               ev.z*invw + nb.z + pt.z, ev.w*invw + nb.w + pt.w };
                float mean = block_sum(x[0]+x[1]+x[2]+x[3]) * (1.f / D_);
                float lv = 0.f;
#pragma unroll
                for (int k = 0; k < 4; ++k) { float d = x[k] - mean; lv += d * d; }
                float inv = rsqrtf(block_sum(lv) * (1.f / D_) + 1e-5f);
                float4 lg = ((const float4*)a.elng)[tid];
                float4 lb = ((const float4*)a.elnb)[tid];
                float y0 = (x[0]-mean)*inv*lg.x + lb.x;
                float y1 = (x[1]-mean)*inv*lg.y + lb.y;
                float y2 = (x[2]-mean)*inv*lg.z + lb.z;
                float y3 = (x[3]-mean)*inv*lg.w + lb.w;
                int d4 = tid * 4;
                sm.t.se1[d4] = y0; sm.t.se1[d4+1] = y1;
                sm.t.se1[d4+2] = y2; sm.t.se1[d4+3] = y3;
                if (seg == 0)
                    ((float4*)(a.esbuf + ((size_t)b*S_ + s)*D_))[tid] = make_float4(y0,y1,y2,y3);
                __syncthreads();
                if (tid < 64) {
                    int u = seg * 64 + tid;
                    float acc = a.gb1[u];
                    const float* w1 = a.gW1 + (size_t)u * D_;
                    for (int j = 0; j < D_; j += 4) {
                        float4 w = *(const float4*)(w1 + j);
                        acc += w.x*sm.t.se1[j] + w.y*sm.t.se1[j+1] + w.z*sm.t.se1[j+2] + w.w*sm.t.se1[j+3];
                    }
                    float hg = gelu_f(acc);
                    for (int c = 0; c < 3; ++c) {
                        float p = wave_sum(a.gW2[c*256 + u] * hg);
                        if (tid == 0) atomicAdd(a.gatepre + b*4 + c, p);
                    }
                }
            } else {
                int w = tid >> 6, lane = tid & 63;
                for (int bb = 0; bb < 2; ++bb) {
                    int b = w*2 + bb;
                    float invw = 1.f / fmaxf(wsumP[b], 1.f);
                    int d0 = lane * 16;
                    const float4* ep = (const float4*)(esumP + (size_t)b*D_ + d0);
                    const float4* np = (const float4*)(a.n2eb + d0);
                    const float4* pp = (const float4*)(a.pre_t2e + ((size_t)b*S_ + s)*D_ + d0);
                    float x[16]; float smv = 0.f;
#pragma unroll
                    for (int j = 0; j < 4; ++j) {
                        float4 e = ep[j], n = np[j], p = pp[j];
                        x[j*4+0] = e.x*invw + n.x + p.x;
                        x[j*4+1] = e.y*invw + n.y + p.y;
                        x[j*4+2] = e.z*invw + n.z + p.z;
                        x[j*4+3] = e.w*invw + n.w + p.w;
                        smv += x[j*4+0] + x[j*4+1] + x[j*4+2] + x[j*4+3];
                    }
                    float mean = wave_allsum(smv) * (1.f / D_);
                    float lv = 0.f;
#pragma unroll
                    for (int j = 0; j < 16; ++j) { float d = x[j] - mean; lv += d * d; }
                    float inv = rsqrtf(wave_allsum(lv) * (1.f / D_) + 1e-5f);
                    const float4* lgp = (const float4*)(a.elng + d0);
                    const float4* lbp = (const float4*)(a.elnb + d0);
#pragma unroll
                    for (int j = 0; j < 4; ++j) {
                        float4 lg = lgp[j], lb = lbp[j];
                        sm.e.se32[b][d0 + j*4 + 0] = (x[j*4+0]-mean)*inv*lg.x + lb.x;
                        sm.e.se32[b][d0 + j*4 + 1] = (x[j*4+1]-mean)*inv*lg.y + lb.y;
                        sm.e.se32[b][d0 + j*4 + 2] = (x[j*4+2]-mean)*inv*lg.z + lb.z;
                        sm.e.se32[b][d0 + j*4 + 3] = (x[j*4+3]-mean)*inv*lg.w + lb.w;
                    }
                }
                __syncthreads();
                int c0 = (tk - 32) * 32;
                int colg = tid >> 5, t31 = tid & 31;
                int cb = c0 + colg * 4;
                float accA[4][8] = {};
                float accB[4][8] = {};
#pragma unroll
                for (int i = 0; i < 8; ++i) {
                    int kh = t31*4 + i*128;
                    float wf[4][4];
#pragma unroll
                    for (int c = 0; c < 4; ++c) {
                        union { uint2 u; _Float16 hh[4]; } cv;
                        cv.u = *(const uint2*)(a.Wmi16 + (size_t)(cb + c)*G3_ + kh);
                        wf[c][0] = (float)cv.hh[0]; wf[c][1] = (float)cv.hh[1];
                        wf[c][2] = (float)cv.hh[2]; wf[c][3] = (float)cv.hh[3];
                    }
#pragma unroll
                    for (int b = 0; b < 8; ++b) {
                        float4 sv = *(const float4*)(&sm.e.se32[b][kh]);
#pragma unroll
                        for (int c = 0; c < 4; ++c)
                            accA[c][b] += wf[c][0]*sv.x + wf[c][1]*sv.y
                                        + wf[c][2]*sv.z + wf[c][3]*sv.w;
                    }
                }
#pragma unroll
                for (int i = 0; i < 8; ++i) {
                    int kh = t31*4 + i*128;
                    float wf[4][4];
#pragma unroll
                    for (int c = 0; c < 4; ++c) {
                        union { uint2 u; _Float16 hh[4]; } cv;
                        cv.u = *(const uint2*)(a.Wmi16 + (size_t)(cb + c)*G3_ + 1024 + kh);
                        wf[c][0] = (float)cv.hh[0]; wf[c][1] = (float)cv.hh[1];
                        wf[c][2] = (float)cv.hh[2]; wf[c][3] = (float)cv.hh[3];
                    }
#pragma unroll
                    for (int b = 0; b < 8; ++b) {
                        float4 sv = *(const float4*)(&sm.e.se32[b][kh]);
#pragma unroll
                        for (int c = 0; c < 4; ++c)
                            accB[c][b] += wf[c][0]*sv.x + wf[c][1]*sv.y
                                        + wf[c][2]*sv.z + wf[c][3]*sv.w;
                    }
                }
#pragma unroll
                for (int off = 16; off >= 1; off >>= 1) {
#pragma unroll
                    for (int c = 0; c < 4; ++c)
#pragma unroll
                        for (int b = 0; b < 8; ++b) {
                            accA[c][b] += __shfl_down(accA[c][b], off, 32);
                            accB[c][b] += __shfl_down(accB[c][b], off, 32);
                        }
                }
                if (t31 == 0) {
#pragma unroll
                    for (int c = 0; c < 4; ++c) {
                        int col = cb + c;
#pragma unroll
                        for (int b = 0; b < 8; ++b) {
                            a.Emi[(size_t)b*G3_ + col] = accA[c][b];
                            a.Esmi[((size_t)b*S_ + s)*G3_ + col] = accB[c][b];
                        }
                    }
                }
            }
        }
        grid.sync();

        // ================= PHASE 3 (k_fin) =================
        {
            int cnt = *cntp;
            for (int tk = bid; tk < BN_; tk += gdim) {
                __syncthreads();
                if (tk >= cnt) continue;
                int row = tk;
                int bn = lst[row];
                int b = bn / N_;
                float t0 = a.gatepre[b*4+0] + a.gb2[0];
                float t1 = a.gatepre[b*4+1] + a.gb2[1];
                float t2 = a.gatepre[b*4+2] + a.gb2[2];
                float mx = fmaxf(t0, fmaxf(t1, t2));
                float e0 = expf(t0-mx), e1 = expf(t1-mx), e2 = expf(t2-mx);
                float si = 1.f / (e0 + e1 + e2);
                float g0 = e0*si, g1 = (s > 0) ? e1*si : 0.f, g2 = e2*si;
                float rv = rro[row];
                float sI = a.scl[row];
                const float* Hrow = a.Hcat + (size_t)bn * HC7;
                const float* em = a.Emi + (size_t)b * G3_;
                const float* as = a.arcsum + (size_t)row * G3_;
                const float* tm = TmiP + (size_t)b * G3_;
                float u4[4]; float lsum = 0.f;
                for (int k = 0; k < 4; ++k) {
                    int d = tid + 256*k;
                    float ip[3];
#pragma unroll
                    for (int c = 0; c < 3; ++c) {
                        int dd = c*D_ + d;
                        float gint = tm[dd] - rv * Hrow[1024 + dd];
                        ip[c] = RSC * (g0*em[dd] + g1*as[dd] + g2*sI*gint)
                              + g0*a.gBm[dd] + g1*a.gBm[G3_ + dd] + g2*a.gBm[2*G3_ + dd]
                              + rv*a.gBm[3*G3_ + dd] + a.bih[dd];
                    }
                    float hr = Hrow[4096 + d]        + a.bhh[d];
                    float hz = Hrow[4096 + D_ + d]   + a.bhh[D_ + d];
                    float hn = Hrow[4096 + 2*D_ + d] + a.bhh[2*D_ + d];
                    float hv = a.hbuf[(size_t)bn*D_ + d];
                    float r = 1.f / (1.f + expf(-(ip[0] + hr)));
                    float z = 1.f / (1.f + expf(-(ip[1] + hz)));
                    float nn = tanhf(ip[2] + r * hn);
                    u4[k] = (1.f - z) * nn + z * hv;
                    lsum += u4[k];
                }
                float mean = block_sum(lsum) * (1.f / D_);
                float lv = 0.f;
                for (int k = 0; k < 4; ++k) { float d = u4[k] - mean; lv += d * d; }
                float inv = rsqrtf(block_sum(lv) * (1.f / D_) + 1e-5f);
                for (int k = 0; k < 4; ++k) {
                    int d = tid + 256*k;
                    float y = (u4[k] - mean) * inv * a.ulng[d] + a.ulnb[d];
                    y = fminf(fmaxf(y, -50.f), 50.f);
                    a.hbuf[(size_t)bn*D_ + d] = y;
                    a.h16[(size_t)bn*D_ + d] = f2h(y);
                }
            }
        }
        grid.sync();
    }
}

// ---------------------------------------------------------------------------
// Final: buf = LN(buf + scene, res_ln) in-place; also fp16 copy.
// ---------------------------------------------------------------------------
__global__ __launch_bounds__(256) void k_resln(
    float* __restrict__ buf, const float* __restrict__ scene,
    const float* __restrict__ g, const float* __restrict__ bt,
    unsigned short* __restrict__ H16)
{
    size_t row = blockIdx.x;
    int tid = threadIdx.x;
    float x[4]; float lsum = 0.f;
    for (int k = 0; k < 4; ++k) {
        int d = tid + 256*k;
        x[k] = buf[row*D_ + d] + scene[row*D_ + d];
        lsum += x[k];
    }
    float mean = block_sum(lsum) * (1.f / D_);
    float lv = 0.f;
    for (int k = 0; k < 4; ++k) { float d = x[k] - mean; lv += d * d; }
    float inv = rsqrtf(block_sum(lv) * (1.f / D_) + 1e-5f);
    for (int k = 0; k < 4; ++k) {
        int d = tid + 256*k;
        float y = (x[k] - mean) * inv * g[d] + bt[d];
        buf[row*D_ + d] = y;
        H16[row*D_ + d] = f2h(y);
    }
}

// ---------------------------------------------------------------------------
// Final: H = LN(gelu(G), eo_ln); plus h_fin copy blocks.
// ---------------------------------------------------------------------------
__global__ __launch_bounds__(256) void k_final(
    const float* __restrict__ G, const float* __restrict__ g, const float* __restrict__ bt,
    float* __restrict__ outH, const float* __restrict__ h, float* __restrict__ outh)
{
    int tid = threadIdx.x;
    if (blockIdx.x < B_*S_) {
        size_t row = blockIdx.x;
        float x[4]; float lsum = 0.f;
        for (int k = 0; k < 4; ++k) {
            x[k] = gelu_f(G[row*D_ + tid + 256*k]);
            lsum += x[k];
        }
        float mean = block_sum(lsum) * (1.f / D_);
        float lv = 0.f;
        for (int k = 0; k < 4; ++k) { float d = x[k] - mean; lv += d * d; }
        float inv = rsqrtf(block_sum(lv) * (1.f / D_) + 1e-5f);
        for (int k = 0; k < 4; ++k) {
            int d = tid + 256*k;
            outH[row*D_ + d] = (x[k] - mean) * inv * g[d] + bt[d];
        }
    } else {
        size_t bn = blockIdx.x - B_*S_;
        for (int d = tid; d < D_; d += 256)
            outh[bn*D_ + d] = h[bn*D_ + d];
    }
}

// ---------------------------------------------------------------------------
extern "C" void kernel_launch(void* const* d_in, const int* in_sizes, int n_in,
                              void* d_out, int out_size, void* d_ws, size_t ws_size,
                              hipStream_t stream)
{
    const float* scene = (const float*)d_in[0];
    const float* inc   = (const float*)d_in[1];
    const int*   etype = (const int*)d_in[3];
    const int*   emask = (const int*)d_in[4];
    const float* nemb  = (const float*)d_in[5];
    const float* temb  = (const float*)d_in[6];
    const float* nameW = (const float*)d_in[7];
    const float* nlg   = (const float*)d_in[8];
    const float* nlb   = (const float*)d_in[9];
    const float* n2eW  = (const float*)d_in[10];
    const float* n2eb  = (const float*)d_in[11];
    const float* t2eW  = (const float*)d_in[12];
    const float* t2eb  = (const float*)d_in[13];
    const float* elng  = (const float*)d_in[14];
    const float* elnb  = (const float*)d_in[15];
    const float* gW1   = (const float*)d_in[16];
    const float* gb1   = (const float*)d_in[17];
    const float* gW2   = (const float*)d_in[18];
    const float* gb2   = (const float*)d_in[19];
    const float* msW   = (const float*)d_in[20];
    const float* msB   = (const float*)d_in[21];
    const float* maW   = (const float*)d_in[22];
    const float* maB   = (const float*)d_in[23];
    const float* miW   = (const float*)d_in[24];
    const float* miB   = (const float*)d_in[25];
    const float* rolew = (const float*)d_in[26];
    const float* Wih   = (const float*)d_in[27];
    const float* Whh   = (const float*)d_in[28];
    const float* bih   = (const float*)d_in[29];
    const float* bhh   = (const float*)d_in[30];
    const float* ulng  = (const float*)d_in[31];
    const float* ulnb  = (const float*)d_in[32];
    const float* eoW   = (const float*)d_in[33];
    const float* eoB   = (const float*)d_in[34];
    const float* eolng = (const float*)d_in[35];
    const float* eolnb = (const float*)d_in[36];
    const float* rlng  = (const float*)d_in[37];
    const float* rlnb  = (const float*)d_in[38];

    float* outH = (float*)d_out;                    // [B,S,D] — doubles as esbuf
    float* outh = outH + (size_t)B_*S_*D_;          // [B,N,D] h_fin

    float* W = (float*)d_ws;
    size_t o = 0;
    int*   ctrl     = (int*)(W + o); o += 64;            // [cnt0, cnt1]
    float* esum2    = W + o; o += 2*(size_t)B_*D_;       // parity sum r*Hcat[:,0:1024]
    float* Tmi2     = W + o; o += 2*(size_t)B_*G3_;      // parity sum r*Hcat[:,1024:4096]
    float* wsum2    = W + o; o += 16;                    // parity per-batch sum r
    float* gatepre  = W + o; o += 32;
    float* rowrole  = W + o; o += 2*BN_;
    float* sclbuf   = W + o; o += BN_;
    int*   list     = (int*)(W + o); o += 2*BN_;
    float* hbuf     = W + o; o += (size_t)BN_*D_;
    float* Hcat     = W + o; o += (size_t)BN_*HC7;
    float* pre_t2e  = W + o; o += (size_t)B_*S_*D_;
    float* gBm      = W + o; o += 4*G3_;
    float* Emi      = W + o; o += (size_t)B_*G3_;
    float* Esmi     = W + o; o += (size_t)B_*S_*G3_;
    float* arcsum   = W + o; o += (size_t)BN_*G3_;
    float* tmp      = W + o; o += (size_t)BN_*D_;        // P (init) and G (final)
    unsigned short* U = (unsigned short*)(W + o);
    size_t uo = 0;
    unsigned short* h16    = U + uo; uo += (size_t)BN_*D_;
    unsigned short* H16    = U + uo; uo += (size_t)B_*S_*D_;
    unsigned short* Wih16  = U + uo; uo += (size_t)G3_*D_;
    unsigned short* Whh16  = U + uo; uo += (size_t)G3_*D_;
    unsigned short* n2e16  = U + uo; uo += (size_t)D_*D_;
    unsigned short* eoW16  = U + uo; uo += (size_t)D_*D_;
    unsigned short* nW16   = U + uo; uo += (size_t)D_*ND_;
    unsigned short* nE16   = U + uo; uo += (size_t)BN_*ND_;
    unsigned short* t2e16  = U + uo; uo += (size_t)D_*D_;
    unsigned short* sc16   = U + uo; uo += (size_t)B_*S_*D_;
    unsigned short* WcatT16= U + uo; uo += (size_t)G3_*D_;
    unsigned short* Wmi16  = U + uo; uo += (size_t)G3_*G3_;
    unsigned short* bias4  = U + uo; uo += 4*D_;

    // zero ctrl + both parities of esum/Tmi/wsum in one shot
    hipMemsetAsync(ctrl, 0,
        (64 + 2*(size_t)B_*D_ + 2*(size_t)B_*G3_ + 16) * sizeof(float), stream);

    // ---- conversions (per call; inputs restored each timed call) ----
    #define CVT(src, dst, r, c, ld) \
        k_f2h<<<(((size_t)(r)*(c)/4 + 255)/256), 256, 0, stream>>>(src, dst, r, c, ld)
    CVT(Wih,   Wih16, G3_, D_,  D_);
    CVT(Whh,   Whh16, G3_, D_,  D_);
    CVT(n2eW,  n2e16, D_,  D_,  D_);
    CVT(nameW, nW16,  D_,  ND_, ND_);
    CVT(nemb,  nE16,  BN_, ND_, ND_);
    CVT(eoW,   eoW16, D_,  D_,  D_);
    CVT(t2eW,  t2e16, D_,  D_,  D_);
    CVT(scene, sc16,  B_*S_, D_, D_);
    CVT(msB,   bias4 + 0,    1, D_, D_);
    CVT(maB,   bias4 + D_,   1, D_, D_);
    CVT(miB,   bias4 + 2*D_, 1, D_, D_);
    CVT(rolew, bias4 + 3*D_, 1, D_, D_);
    #undef CVT
    // WcatT16[seg*1024 + k][d] = {ms,ma,mi}W[d][k]  (transposed, fp16)
    k_f2hT<<<dim3(32,32), 256, 0, stream>>>(msW, WcatT16, D_, D_, D_, 0);
    k_f2hT<<<dim3(32,32), 256, 0, stream>>>(maW, WcatT16, D_, D_, D_, D_);
    k_f2hT<<<dim3(32,32), 256, 0, stream>>>(miW, WcatT16, D_, D_, D_, 2*D_);

    // Wmi16 = 256 * (Wih @ Wcat)  [3072,3072] fp16 (cols: es|arc|int segs)
    k_mfma16_nt<<<dim3(G3_/128, G3_/64), 256, 0, stream>>>(
        Wih16, WcatT16, nullptr, nullptr, Wmi16, 256.f, G3_, G3_, D_);
    // gBm[4,3072] = [msB|maB|miB|rolew] @ Wih^T
    k_mfma16_nt<<<dim3(G3_/128, 1), 256, 0, stream>>>(
        bias4, Wih16, nullptr, gBm, nullptr, 1.f, 4, G3_, D_);
    // pre_t2e[b,s,:] = t2e(scene) + t2eb
    k_mfma16_nt<<<dim3(D_/128, (B_*S_+63)/64), 256, 0, stream>>>(
        sc16, t2e16, t2eb, pre_t2e, nullptr, 1.f, B_*S_, D_, D_);
    // init: P = name_embs @ name_W^T ; h0 ; Hcat0
    k_mfma16_nt<<<dim3(D_/128, (BN_+63)/64), 256, 0, stream>>>(
        nE16, nW16, nullptr, tmp, nullptr, 1.f, BN_, D_, ND_);
    k_h0<<<BN_, 256, 0, stream>>>(tmp, etype, emask, temb, nlg, nlb, hbuf, h16);
    k_hcat0<<<dim3(112, 25), 256, 0, stream>>>(h16, n2e16, Wmi16, Whh16, Hcat);

    // ---- recurrence: cooperative single kernel if available, else fallback ----
    int dev = 0, coopAttr = 0, nCU = 0, mb = 0;
    hipGetDevice(&dev);
    hipDeviceGetAttribute(&coopAttr, hipDeviceAttributeCooperativeLaunch, dev);
    hipDeviceGetAttribute(&nCU, hipDeviceAttributeMultiprocessorCount, dev);
    hipOccupancyMaxActiveBlocksPerMultiprocessor(&mb, (const void*)k_loop, 256, 0);
    int coopGrid = 0;
    if (coopAttr && mb > 0 && nCU > 0) {
        long cap = (long)mb * nCU;
        coopGrid = (int)(cap < NBLK ? cap : NBLK);
    }
    hipError_t cerr = hipErrorUnknown;
    if (coopGrid >= 64) {
        LoopA la;
        la.inc = inc; la.emask = emask;
        la.Esmi = Esmi; la.arcsum = arcsum;
        la.ctrl = ctrl; la.list2 = list; la.rro2 = rowrole; la.scl = sclbuf;
        la.h16 = h16; la.hbuf = hbuf;
        la.n2e16 = n2e16; la.Wmi16 = Wmi16; la.Whh16 = Whh16;
        la.Hcat = Hcat; la.gatepre = gatepre;
        la.esum2 = esum2; la.Tmi2 = Tmi2; la.wsum2 = wsum2;
        la.pre_t2e = pre_t2e; la.Emi = Emi; la.esbuf = outH;
        la.n2eb = n2eb; la.elng = elng; la.elnb = elnb;
        la.gW1 = gW1; la.gb1 = gb1; la.gW2 = gW2; la.gb2 = gb2;
        la.gBm = gBm; la.bih = bih; la.bhh = bhh;
        la.ulng = ulng; la.ulnb = ulnb;
        void* kargs[] = { (void*)&la };
        cerr = hipLaunchCooperativeKernel((const void*)k_loop, dim3(coopGrid),
                                          dim3(256), kargs, 0, stream);
    }
    if (cerr != hipSuccess) {
        for (int s = 0; s < S_; ++s) {
            int par = s & 1;
            int*   cntp = ctrl + par;
            int*   pcnt = ctrl + (1 - par);
            int*   lst  = list + par * BN_;
            int*   plst = list + (1 - par) * BN_;
            float* rro  = rowrole + par * BN_;
            float* esumP = esum2 + (size_t)par * B_*D_;
            float* esumZ = esum2 + (size_t)(1 - par) * B_*D_;
            float* TmiP  = Tmi2 + (size_t)par * B_*G3_;
            float* TmiZ  = Tmi2 + (size_t)(1 - par) * B_*G3_;
            float* wsumP = wsum2 + par * 8;
            float* wsumZ = wsum2 + (1 - par) * 8;
            k_front<<<BN_ + 112*13, 256, 0, stream>>>(inc, emask, Esmi, arcsum,
                cntp, lst, rro, sclbuf, pcnt, plst, h16, n2e16, Wmi16, Whh16,
                Hcat, gatepre, esumP, TmiP, wsumP, s);
            k_mid<<<128, 256, 0, stream>>>(esumP, wsumP, esumZ, TmiZ, wsumZ,
                n2eb, pre_t2e, elng, elnb, gW1, gb1, gW2, Wmi16,
                outH, gatepre, Emi, Esmi, ctrl, par, s);
            k_fin<<<BN_, 256, 0, stream>>>(lst, cntp, rro, sclbuf, gatepre, gb2,
                Hcat, Emi, arcsum, TmiP, gBm, bih, bhh, ulng, ulnb, hbuf, h16, s);
        }
    }

    // epilogue: H = LN(gelu(LN(es + scene) @ eo_W^T + eo_b)); h_fin copy
    k_resln<<<B_*S_, 256, 0, stream>>>(outH, scene, rlng, rlnb, H16);
    k_mfma16_nt<<<dim3(D_/128, (B_*S_+63)/64), 256, 0, stream>>>(
        H16, eoW16, eoB, tmp, nullptr, 1.f, B_*S_, D_, D_);
    k_final<<<B_*S_ + BN_, 256, 0, stream>>>(tmp, eolng, eolnb, outH, hbuf, outh);
}

// Round 4
// 12639.375 us; speedup vs baseline: 1.1182x; 1.1182x over previous
//
#include <hip/hip_runtime.h>
#include <math.h>

#define B_   8
#define S_   64
#define N_   100
#define D_   1024
#define ND_  768
#define BN_  800
#define G3_  3072
#define HC7  7168
#define GT_  1456   // Hcat GEMM tasks: 112 col-tiles x 13 row-tiles
#define RSC  0.00390625f   // 1/256 — Wmi stored x256 to avoid fp16 subnormals

typedef _Float16 f16x8 __attribute__((ext_vector_type(8)));
typedef float f32x4 __attribute__((ext_vector_type(4)));

#define MFMA16(a,b,c) __builtin_amdgcn_mfma_f32_16x16x32_f16(a, b, c, 0, 0, 0)

static __device__ __forceinline__ float wave_sum(float v) {
    for (int off = 32; off > 0; off >>= 1) v += __shfl_down(v, off, 64);
    return v;
}

static __device__ __forceinline__ float wave_allsum(float v) {
    for (int off = 1; off < 64; off <<= 1) v += __shfl_xor(v, off, 64);
    return v;
}

// All 256 threads must call; returns full-block sum to every thread.
static __device__ __forceinline__ float block_sum(float v) {
    __shared__ float red_[8];
    float w = wave_sum(v);
    int lane = threadIdx.x & 63, wid = threadIdx.x >> 6;
    __syncthreads();               // protect red_ reuse across calls
    if (lane == 0) red_[wid] = w;
    __syncthreads();
    float t = 0.f;
    for (int i = 0; i < 4; ++i) t += red_[i];
    return t;
}

static __device__ __forceinline__ float gelu_f(float x) {
    return 0.5f * x * (1.f + erff(x * 0.70710678118654752f));
}

static __device__ __forceinline__ unsigned short f2h(float x) {
    union { _Float16 h; unsigned short u; } c; c.h = (_Float16)x; return c.u;
}

// ---------------------------------------------------------------------------
// fp32 -> fp16 2D convert. cols % 4 == 0.
// ---------------------------------------------------------------------------
__global__ __launch_bounds__(256) void k_f2h(
    const float* __restrict__ src, unsigned short* __restrict__ dst,
    int rows, int cols, int ldd)
{
    size_t n = (size_t)rows * cols;
    size_t i = ((size_t)blockIdx.x * 256 + threadIdx.x) * 4;
    if (i >= n) return;
    int r = (int)(i / cols);
    int c = (int)(i - (size_t)r * cols);
    float4 v = *(const float4*)(src + i);
    ushort4 o; o.x = f2h(v.x); o.y = f2h(v.y); o.z = f2h(v.z); o.w = f2h(v.w);
    *(ushort4*)(dst + (size_t)r * ldd + c) = o;
}

// ---------------------------------------------------------------------------
// fp32 -> fp16 TRANSPOSING convert: dst[rowoff + c][r] = src[r][c].
// ---------------------------------------------------------------------------
__global__ __launch_bounds__(256) void k_f2hT(
    const float* __restrict__ src, unsigned short* __restrict__ dst,
    int R, int C, int ldd, int rowoff)
{
    __shared__ _Float16 T[32][33];
    int tr = threadIdx.x >> 3, tc4 = (threadIdx.x & 7) * 4;
    int r0 = blockIdx.y * 32, c0 = blockIdx.x * 32;
    float4 v = *(const float4*)(src + (size_t)(r0 + tr) * C + c0 + tc4);
    T[tc4][tr] = (_Float16)v.x; T[tc4+1][tr] = (_Float16)v.y;
    T[tc4+2][tr] = (_Float16)v.z; T[tc4+3][tr] = (_Float16)v.w;
    __syncthreads();
    union { _Float16 h; unsigned short u; } cv;
    ushort4 o;
    cv.h = T[tr][tc4];   o.x = cv.u;
    cv.h = T[tr][tc4+1]; o.y = cv.u;
    cv.h = T[tr][tc4+2]; o.z = cv.u;
    cv.h = T[tr][tc4+3]; o.w = cv.u;
    *(ushort4*)(dst + (size_t)(rowoff + c0 + tr) * ldd + r0 + tc4) = o;
}

// ---------------------------------------------------------------------------
// FP16 MFMA GEMM (setup/epilogue only): C[M,Nc] = A16[M,K] @ W16[Nc,K]^T.
// ---------------------------------------------------------------------------
__global__ __launch_bounds__(256) void k_mfma16_nt(
    const unsigned short* __restrict__ A16, const unsigned short* __restrict__ W16,
    const float* __restrict__ bias, float* __restrict__ C,
    unsigned short* __restrict__ C16, float oscale,
    int M, int Nc, int K)
{
    int m0 = blockIdx.y * 64; if (m0 >= M) return;
    int n0 = blockIdx.x * 128;
    __shared__ _Float16 sA[64][72];
    __shared__ _Float16 sB[128][72];
    int tid = threadIdx.x;
    int w = tid >> 6, l = tid & 63;
    int l15 = l & 15, q = l >> 4;
    int wn = w * 32;
    int arow = tid >> 3, achk = (tid & 7) * 8;
    f32x4 acc[4][2] = {};
    for (int k0 = 0; k0 < K; k0 += 64) {
        for (int ri = 0; ri < 64; ri += 32) {
            int gm = m0 + arow + ri;
            uint4 v = make_uint4(0u, 0u, 0u, 0u);
            if (gm < M) v = *(const uint4*)(A16 + (size_t)gm * K + k0 + achk);
            *(uint4*)(&sA[arow + ri][achk]) = v;
        }
        for (int i = 0; i < 4; ++i) {
            int r = arow + 32 * i;
            *(uint4*)(&sB[r][achk]) = *(const uint4*)(W16 + (size_t)(n0 + r) * K + k0 + achk);
        }
        __syncthreads();
#pragma unroll
        for (int ks = 0; ks < 64; ks += 32) {
            f16x8 b0 = *(const f16x8*)(&sB[wn + l15][ks + q*8]);
            f16x8 b1 = *(const f16x8*)(&sB[wn + 16 + l15][ks + q*8]);
#pragma unroll
            for (int mi = 0; mi < 4; ++mi) {
                f16x8 a = *(const f16x8*)(&sA[mi*16 + l15][ks + q*8]);
                acc[mi][0] = MFMA16(a, b0, acc[mi][0]);
                acc[mi][1] = MFMA16(a, b1, acc[mi][1]);
            }
        }
        __syncthreads();
    }
    for (int mi = 0; mi < 4; ++mi)
        for (int nj = 0; nj < 2; ++nj)
            for (int r = 0; r < 4; ++r) {
                int gm = m0 + mi*16 + q*4 + r;
                int cl = wn + nj*16 + l15;
                if (gm < M) {
                    size_t off = (size_t)gm * Nc + n0 + cl;
                    float v = acc[mi][nj][r];
                    if (C16) C16[off] = f2h(v * oscale);
                    else C[off] = v + (bias ? bias[n0 + cl] : 0.f);
                }
            }
}

// ---------------------------------------------------------------------------
// h0 = mask * (type_embed[type] + LN(P, name_ln)); fp32 h + fp16 mirror
// ---------------------------------------------------------------------------
__global__ __launch_bounds__(256) void k_h0(
    const float* __restrict__ P, const int* __restrict__ etype,
    const int* __restrict__ emask, const float* __restrict__ temb,
    const float* __restrict__ g, const float* __restrict__ bt,
    float* __restrict__ h, unsigned short* __restrict__ h16)
{
    int bn = blockIdx.x, tid = threadIdx.x;
    int t = etype[bn], mk = emask[bn];
    float x[4]; float lsum = 0.f;
    for (int k = 0; k < 4; ++k) { x[k] = P[(size_t)bn*D_ + tid + 256*k]; lsum += x[k]; }
    float mean = block_sum(lsum) * (1.f / D_);
    float lv = 0.f;
    for (int k = 0; k < 4; ++k) { float d = x[k] - mean; lv += d * d; }
    float inv = rsqrtf(block_sum(lv) * (1.f / D_) + 1e-5f);
    for (int k = 0; k < 4; ++k) {
        int d = tid + 256*k;
        float y = (x[k] - mean) * inv * g[d] + bt[d];
        float hv = mk ? (temb[(size_t)t*D_ + d] + y) : 0.f;
        h[(size_t)bn*D_ + d] = hv;
        h16[(size_t)bn*D_ + d] = f2h(hv);
    }
}

// ---------------------------------------------------------------------------
// Hcat init: Hcat[bn, 0:1024|1024:4096|4096:7168] = h16[bn] @ [n2e|Wmi2|Whh]^T
// ---------------------------------------------------------------------------
__global__ __launch_bounds__(256) void k_hcat0(
    const unsigned short* __restrict__ h16, const unsigned short* __restrict__ n2e16,
    const unsigned short* __restrict__ Wmi16, const unsigned short* __restrict__ Whh16,
    float* __restrict__ Hcat)
{
    int m0 = blockIdx.y * 32;
    int n0 = blockIdx.x * 64;
    const unsigned short* Bp; int ldb; int nl;
    if (n0 < 1024)      { Bp = n2e16;        ldb = D_;  nl = n0; }
    else if (n0 < 4096) { Bp = Wmi16 + 2048; ldb = G3_; nl = n0 - 1024; }
    else                { Bp = Whh16;        ldb = D_;  nl = n0 - 4096; }
    __shared__ _Float16 sA[32][72];
    __shared__ _Float16 sB[64][72];
    int tid = threadIdx.x;
    int w = tid >> 6, l = tid & 63;
    int l15 = l & 15, q = l >> 4;
    int wm = (w & 1) * 16, wn = (w >> 1) * 32;
    int arow = tid >> 3, achk = (tid & 7) * 8;
    int gmA = m0 + arow;
    f32x4 acc[2] = {};
    for (int k0 = 0; k0 < D_; k0 += 64) {
        *(uint4*)(&sA[arow][achk]) = *(const uint4*)(h16 + (size_t)gmA*D_ + k0 + achk);
        *(uint4*)(&sB[arow][achk])      = *(const uint4*)(Bp + (size_t)(nl + arow)*ldb + k0 + achk);
        *(uint4*)(&sB[arow + 32][achk]) = *(const uint4*)(Bp + (size_t)(nl + arow + 32)*ldb + k0 + achk);
        __syncthreads();
#pragma unroll
        for (int ks = 0; ks < 64; ks += 32) {
            f16x8 a  = *(const f16x8*)(&sA[wm + l15][ks + q*8]);
            f16x8 b0 = *(const f16x8*)(&sB[wn + l15][ks + q*8]);
            f16x8 b1 = *(const f16x8*)(&sB[wn + 16 + l15][ks + q*8]);
            acc[0] = MFMA16(a, b0, acc[0]);
            acc[1] = MFMA16(a, b1, acc[1]);
        }
        __syncthreads();
    }
    for (int j = 0; j < 2; ++j)
        for (int r = 0; r < 4; ++r) {
            int row = wm + q*4 + r;
            Hcat[(size_t)(m0 + row)*HC7 + n0 + wn + j*16 + l15] = acc[j][r];
        }
}

// ---------------------------------------------------------------------------
// Shared-memory union for k_step1 (one allocation, three block roles)
// ---------------------------------------------------------------------------
union SM1 {
    struct { _Float16 A[64][72]; _Float16 Bm[64][72]; int slist[64]; float srn[64]; int sbb[64]; } g;
    struct { float se32[8][1028]; } e;
    struct { float se1[D_]; } t;
    struct { float wav[S_]; int wai[S_]; } r;
};

// ---------------------------------------------------------------------------
// k_step1: blocks [0,GT_): Hcat update GEMM for prev-active rows + fresh
//          esum/Tmi contributions; release-increment dcnt when done.
//          blocks [GT_, GT_+800): arcsum for rows active at s (reads Esmi<s).
//          blocks [GT_+800, GT_+928): acquire-wait dcnt==GT_, then
//            [0,32): e_s LN + gate MLP + esbuf + zero next-parity accums
//            [32,128): Emi/Esmi GEMV batched over all 8 b (Wmi read once)
// ---------------------------------------------------------------------------
__global__ __launch_bounds__(256) void k_step1(
    const float* __restrict__ inc, const int* __restrict__ emask,
    float* __restrict__ Esmi, float* __restrict__ arcsum,
    const int* __restrict__ pcnt, const int* __restrict__ plst,
    const int* invb,
    const unsigned short* __restrict__ h16,
    const unsigned short* __restrict__ n2e16,
    const unsigned short* __restrict__ Wmi16,
    const unsigned short* __restrict__ Whh16,
    float* __restrict__ Hcat,
    float* __restrict__ esumP, float* __restrict__ TmiP,
    const float* __restrict__ wsumP,
    float* __restrict__ esumZ, float* __restrict__ TmiZ,
    float* __restrict__ wsumZ, int* __restrict__ ctrlZ,
    const float* __restrict__ n2eb, const float* __restrict__ pre_t2e,
    const float* __restrict__ elng, const float* __restrict__ elnb,
    const float* __restrict__ gW1, const float* __restrict__ gb1,
    const float* __restrict__ gW2,
    float* __restrict__ esbuf, float* __restrict__ gatepre,
    float* __restrict__ Emi,
    int* __restrict__ dcnt, int s)
{
    __shared__ SM1 sm;
    __shared__ int sh_i1;
    int tid = threadIdx.x, bid = blockIdx.x;

    if (bid < GT_) {
        // ---------------- Hcat update GEMM ----------------
        int pM = *pcnt;
        int nt = bid % 112, mt = bid / 112;
        int m0 = mt * 64;
        if (m0 < pM) {
            int n0 = nt * 64;
            const unsigned short* Bp; int ldb; int nl;
            if (n0 < 1024)      { Bp = n2e16;        ldb = D_;  nl = n0; }
            else if (n0 < 4096) { Bp = Wmi16 + 2048; ldb = G3_; nl = n0 - 1024; }
            else                { Bp = Whh16;        ldb = D_;  nl = n0 - 4096; }
            if (tid < 64) {
                int gm = m0 + tid;
                int m = (gm < pM) ? plst[gm] : 0;
                sm.g.slist[tid] = m;
                float rn = 0.f;
                if (gm < pM) rn = emask[m] ? inc[(size_t)m*S_ + s] : 0.f;
                sm.g.srn[tid] = rn;
                sm.g.sbb[tid] = m / N_;
            }
            __syncthreads();
            int w = tid >> 6, l = tid & 63;
            int l15 = l & 15, q = l >> 4;
            int wm = (w & 1) * 32, wn = (w >> 1) * 32;
            int arow = tid >> 3, achk = (tid & 7) * 8;
            f32x4 acc[2][2] = {};
            for (int k0 = 0; k0 < D_; k0 += 64) {
                for (int ri = 0; ri < 64; ri += 32) {
                    int row = arow + ri, gm = m0 + row;
                    uint4 v = make_uint4(0u,0u,0u,0u);
                    if (gm < pM) v = *(const uint4*)(h16 + (size_t)sm.g.slist[row]*D_ + k0 + achk);
                    *(uint4*)(&sm.g.A[row][achk]) = v;
                }
                *(uint4*)(&sm.g.Bm[arow][achk])      = *(const uint4*)(Bp + (size_t)(nl + arow)*ldb + k0 + achk);
                *(uint4*)(&sm.g.Bm[arow + 32][achk]) = *(const uint4*)(Bp + (size_t)(nl + arow + 32)*ldb + k0 + achk);
                __syncthreads();
#pragma unroll
                for (int ks = 0; ks < 64; ks += 32) {
                    f16x8 a0 = *(const f16x8*)(&sm.g.A[wm + l15][ks + q*8]);
                    f16x8 a1 = *(const f16x8*)(&sm.g.A[wm + 16 + l15][ks + q*8]);
                    f16x8 b0 = *(const f16x8*)(&sm.g.Bm[wn + l15][ks + q*8]);
                    f16x8 b1 = *(const f16x8*)(&sm.g.Bm[wn + 16 + l15][ks + q*8]);
                    acc[0][0] = MFMA16(a0, b0, acc[0][0]);
                    acc[0][1] = MFMA16(a0, b1, acc[0][1]);
                    acc[1][0] = MFMA16(a1, b0, acc[1][0]);
                    acc[1][1] = MFMA16(a1, b1, acc[1][1]);
                }
                __syncthreads();
            }
            for (int mi = 0; mi < 2; ++mi)
                for (int nj = 0; nj < 2; ++nj)
                    for (int r4 = 0; r4 < 4; ++r4) {
                        int row = wm + mi*16 + q*4 + r4;
                        int gm = m0 + row;
                        if (gm < pM) {
                            float v = acc[mi][nj][r4];
                            int c = n0 + wn + nj*16 + l15;
                            Hcat[(size_t)sm.g.slist[row]*HC7 + c] = v;
                            float rn = sm.g.srn[row];
                            if (rn > 0.f && c < 4096) {
                                float* dst = (c < 1024)
                                    ? (esumP + (size_t)sm.g.sbb[row]*D_ + c)
                                    : (TmiP + (size_t)sm.g.sbb[row]*G3_ + (c - 1024));
                                atomicAdd(dst, rn * v);
                            }
                        }
                    }
        }
        // release: this block's contributions are visible
        __threadfence();
        __syncthreads();
        if (tid == 0)
            __hip_atomic_fetch_add(dcnt, 1, __ATOMIC_RELEASE, __HIP_MEMORY_SCOPE_AGENT);
    } else if (bid < GT_ + BN_) {
        // ---------------- arcsum for rows active at s ----------------
        int m = bid - GT_;
        int b = m / N_;
        float r = emask[m] ? inc[(size_t)m*S_ + s] : 0.f;
        if (r > 0.f) {
            if (tid == 0) sh_i1 = 0;
            __syncthreads();
            float denomA = fmaxf((float)(s - 1), 1.f);
            float wa = 0.f;
            if (tid < s) {
                float iv = inc[(size_t)m*S_ + tid];
                if (iv > 0.f) {
                    wa = iv * r * expf(-1.f + (float)tid / denomA);
                    int p = atomicAdd(&sh_i1, 1);
                    sm.r.wav[p] = wa; sm.r.wai[p] = tid;
                }
            }
            float dA = block_sum(wa);
            int na = sh_i1;
            float sclA = 1.f / fmaxf(dA, 1e-8f);
            int idx = invb[m];
            float a12[12];
#pragma unroll
            for (int k = 0; k < 12; ++k) a12[k] = 0.f;
            for (int j = 0; j < na; ++j) {
                float wj = sm.r.wav[j];
                const float* ep = Esmi + ((size_t)b*S_ + sm.r.wai[j])*G3_;
#pragma unroll
                for (int k = 0; k < 12; ++k) a12[k] += wj * ep[tid + 256*k];
            }
            float* ao = arcsum + (size_t)idx*G3_;
#pragma unroll
            for (int k = 0; k < 12; ++k) ao[tid + 256*k] = a12[k] * sclA;
        }
    } else {
        // ---------------- mid: wait for all GEMM contributions ----------------
        if (tid == 0) {
            while (__hip_atomic_load(dcnt, __ATOMIC_ACQUIRE, __HIP_MEMORY_SCOPE_AGENT) < GT_)
                __builtin_amdgcn_s_sleep(8);
        }
        __syncthreads();
        int mb = bid - (GT_ + BN_);
        if (mb < 32) {
            int b = mb >> 2, seg = mb & 3;
            if (mb == 0 && tid == 0) *ctrlZ = 0;
            esumZ[(size_t)b*D_ + seg*256 + tid] = 0.f;
#pragma unroll
            for (int j = 0; j < 3; ++j) TmiZ[(size_t)b*G3_ + seg*768 + j*256 + tid] = 0.f;
            if (seg == 0 && tid == 0) wsumZ[b] = 0.f;
            float invw = 1.f / fmaxf(wsumP[b], 1.f);
            float4 ev = ((const float4*)(esumP + (size_t)b*D_))[tid];
            float4 nb = ((const float4*)n2eb)[tid];
            float4 pt = ((const float4*)(pre_t2e + ((size_t)b*S_ + s)*D_))[tid];
            float x[4] = { ev.x*invw + nb.x + pt.x, ev.y*invw + nb.y + pt.y,
                           ev.z*invw + nb.z + pt.z, ev.w*invw + nb.w + pt.w };
            float mean = block_sum(x[0]+x[1]+x[2]+x[3]) * (1.f / D_);
            float lv = 0.f;
#pragma unroll
            for (int k = 0; k < 4; ++k) { float d = x[k] - mean; lv += d * d; }
            float inv = rsqrtf(block_sum(lv) * (1.f / D_) + 1e-5f);
            float4 lg = ((const float4*)elng)[tid];
            float4 lb = ((const float4*)elnb)[tid];
            float y0 = (x[0]-mean)*inv*lg.x + lb.x;
            float y1 = (x[1]-mean)*inv*lg.y + lb.y;
            float y2 = (x[2]-mean)*inv*lg.z + lb.z;
            float y3 = (x[3]-mean)*inv*lg.w + lb.w;
            int d4 = tid * 4;
            sm.t.se1[d4] = y0; sm.t.se1[d4+1] = y1;
            sm.t.se1[d4+2] = y2; sm.t.se1[d4+3] = y3;
            if (seg == 0)
                ((float4*)(esbuf + ((size_t)b*S_ + s)*D_))[tid] = make_float4(y0,y1,y2,y3);
            __syncthreads();
            if (tid < 64) {
                int u = seg * 64 + tid;
                float acc = gb1[u];
                const float* w1 = gW1 + (size_t)u * D_;
                for (int j = 0; j < D_; j += 4) {
                    float4 w = *(const float4*)(w1 + j);
                    acc += w.x*sm.t.se1[j] + w.y*sm.t.se1[j+1] + w.z*sm.t.se1[j+2] + w.w*sm.t.se1[j+3];
                }
                float hg = gelu_f(acc);
                for (int c = 0; c < 3; ++c) {
                    float p = wave_sum(gW2[c*256 + u] * hg);
                    if (tid == 0) atomicAdd(gatepre + b*4 + c, p);
                }
            }
        } else {
            int w = tid >> 6, lane = tid & 63;
            for (int bb = 0; bb < 2; ++bb) {
                int b = w*2 + bb;
                float invw = 1.f / fmaxf(wsumP[b], 1.f);
                int d0 = lane * 16;
                const float4* ep = (const float4*)(esumP + (size_t)b*D_ + d0);
                const float4* np = (const float4*)(n2eb + d0);
                const float4* pp = (const float4*)(pre_t2e + ((size_t)b*S_ + s)*D_ + d0);
                float x[16]; float smv = 0.f;
#pragma unroll
                for (int j = 0; j < 4; ++j) {
                    float4 e = ep[j], n = np[j], p = pp[j];
                    x[j*4+0] = e.x*invw + n.x + p.x;
                    x[j*4+1] = e.y*invw + n.y + p.y;
                    x[j*4+2] = e.z*invw + n.z + p.z;
                    x[j*4+3] = e.w*invw + n.w + p.w;
                    smv += x[j*4+0] + x[j*4+1] + x[j*4+2] + x[j*4+3];
                }
                float mean = wave_allsum(smv) * (1.f / D_);
                float lv = 0.f;
#pragma unroll
                for (int j = 0; j < 16; ++j) { float d = x[j] - mean; lv += d * d; }
                float inv = rsqrtf(wave_allsum(lv) * (1.f / D_) + 1e-5f);
                const float4* lgp = (const float4*)(elng + d0);
                const float4* lbp = (const float4*)(elnb + d0);
#pragma unroll
                for (int j = 0; j < 4; ++j) {
                    float4 lg = lgp[j], lb = lbp[j];
                    sm.e.se32[b][d0 + j*4 + 0] = (x[j*4+0]-mean)*inv*lg.x + lb.x;
                    sm.e.se32[b][d0 + j*4 + 1] = (x[j*4+1]-mean)*inv*lg.y + lb.y;
                    sm.e.se32[b][d0 + j*4 + 2] = (x[j*4+2]-mean)*inv*lg.z + lb.z;
                    sm.e.se32[b][d0 + j*4 + 3] = (x[j*4+3]-mean)*inv*lg.w + lb.w;
                }
            }
            __syncthreads();
            int c0 = (mb - 32) * 32;
            int colg = tid >> 5, t31 = tid & 31;
            int cb = c0 + colg * 4;
            float accA[4][8] = {};
            float accB[4][8] = {};
#pragma unroll
            for (int i = 0; i < 8; ++i) {
                int kh = t31*4 + i*128;
                float wf[4][4];
#pragma unroll
                for (int c = 0; c < 4; ++c) {
                    union { uint2 u; _Float16 hh[4]; } cv;
                    cv.u = *(const uint2*)(Wmi16 + (size_t)(cb + c)*G3_ + kh);
                    wf[c][0] = (float)cv.hh[0]; wf[c][1] = (float)cv.hh[1];
                    wf[c][2] = (float)cv.hh[2]; wf[c][3] = (float)cv.hh[3];
                }
#pragma unroll
                for (int b = 0; b < 8; ++b) {
                    float4 sv = *(const float4*)(&sm.e.se32[b][kh]);
#pragma unroll
                    for (int c = 0; c < 4; ++c)
                        accA[c][b] += wf[c][0]*sv.x + wf[c][1]*sv.y
                                    + wf[c][2]*sv.z + wf[c][3]*sv.w;
                }
            }
#pragma unroll
            for (int i = 0; i < 8; ++i) {
                int kh = t31*4 + i*128;
                float wf[4][4];
#pragma unroll
                for (int c = 0; c < 4; ++c) {
                    union { uint2 u; _Float16 hh[4]; } cv;
                    cv.u = *(const uint2*)(Wmi16 + (size_t)(cb + c)*G3_ + 1024 + kh);
                    wf[c][0] = (float)cv.hh[0]; wf[c][1] = (float)cv.hh[1];
                    wf[c][2] = (float)cv.hh[2]; wf[c][3] = (float)cv.hh[3];
                }
#pragma unroll
                for (int b = 0; b < 8; ++b) {
                    float4 sv = *(const float4*)(&sm.e.se32[b][kh]);
#pragma unroll
                    for (int c = 0; c < 4; ++c)
                        accB[c][b] += wf[c][0]*sv.x + wf[c][1]*sv.y
                                    + wf[c][2]*sv.z + wf[c][3]*sv.w;
                }
            }
#pragma unroll
            for (int off = 16; off >= 1; off >>= 1) {
#pragma unroll
                for (int c = 0; c < 4; ++c)
#pragma unroll
                    for (int b = 0; b < 8; ++b) {
                        accA[c][b] += __shfl_down(accA[c][b], off, 32);
                        accB[c][b] += __shfl_down(accB[c][b], off, 32);
                    }
            }
            if (t31 == 0) {
#pragma unroll
                for (int c = 0; c < 4; ++c) {
                    int col = cb + c;
#pragma unroll
                    for (int b = 0; b < 8; ++b) {
                        Emi[(size_t)b*G3_ + col] = accA[c][b];
                        Esmi[((size_t)b*S_ + s)*G3_ + col] = accB[c][b];
                    }
                }
            }
        }
    }
}

// ---------------------------------------------------------------------------
// k_step2: one block per row m.
//   Part A (sfin>=0, row active at sfin): GRU assembly + LN + clip + h update.
//   Part B (s=sfin+1 < S): compaction for step s (cnt/lst/inv/wsum) + stale
//   esum/Tmi contributions (rows whose Hcat was not updated at sfin).
// ---------------------------------------------------------------------------
__global__ __launch_bounds__(256) void k_step2(
    const float* __restrict__ inc, const int* __restrict__ emask,
    const float* __restrict__ gatepreP, const float* __restrict__ gb2,
    const float* __restrict__ Hcat, const float* __restrict__ Emi,
    const float* __restrict__ arcsum, const float* __restrict__ TmiP,
    const float* __restrict__ wsumP, int* invb,
    const float* __restrict__ gBm, const float* __restrict__ bih,
    const float* __restrict__ bhh,
    const float* __restrict__ ulng, const float* __restrict__ ulnb,
    float* __restrict__ h, unsigned short* __restrict__ h16,
    int* __restrict__ cntN, int* __restrict__ lstN,
    float* __restrict__ wsumN,
    float* __restrict__ esumN, float* __restrict__ TmiN,
    float* __restrict__ gatepreN,
    int sfin)
{
    int m = blockIdx.x, tid = threadIdx.x;
    int b = m / N_;

    // ---------------- Part A: GRU update ----------------
    if (sfin >= 0) {
        float rv = emask[m] ? inc[(size_t)m*S_ + sfin] : 0.f;
        if (rv > 0.f) {
            int idx = invb[m];
            float wsum = wsumP[b];
            float sI = rv / fmaxf(rv * (wsum - rv), 1e-8f);
            float t0 = gatepreP[b*4+0] + gb2[0];
            float t1 = gatepreP[b*4+1] + gb2[1];
            float t2 = gatepreP[b*4+2] + gb2[2];
            float mx = fmaxf(t0, fmaxf(t1, t2));
            float e0 = expf(t0-mx), e1 = expf(t1-mx), e2 = expf(t2-mx);
            float si = 1.f / (e0 + e1 + e2);
            float g0 = e0*si, g1 = (sfin > 0) ? e1*si : 0.f, g2 = e2*si;
            const float* Hrow = Hcat + (size_t)m * HC7;
            const float* em = Emi + (size_t)b * G3_;
            const float* as = arcsum + (size_t)idx * G3_;
            const float* tm = TmiP + (size_t)b * G3_;
            float u4[4]; float lsum = 0.f;
            for (int k = 0; k < 4; ++k) {
                int d = tid + 256*k;
                float ip[3];
#pragma unroll
                for (int c = 0; c < 3; ++c) {
                    int dd = c*D_ + d;
                    float gint = tm[dd] - rv * Hrow[1024 + dd];
                    ip[c] = RSC * (g0*em[dd] + g1*as[dd] + g2*sI*gint)
                          + g0*gBm[dd] + g1*gBm[G3_ + dd] + g2*gBm[2*G3_ + dd]
                          + rv*gBm[3*G3_ + dd] + bih[dd];
                }
                float hr = Hrow[4096 + d]        + bhh[d];
                float hz = Hrow[4096 + D_ + d]   + bhh[D_ + d];
                float hn = Hrow[4096 + 2*D_ + d] + bhh[2*D_ + d];
                float hv = h[(size_t)m*D_ + d];
                float r = 1.f / (1.f + expf(-(ip[0] + hr)));
                float z = 1.f / (1.f + expf(-(ip[1] + hz)));
                float nn = tanhf(ip[2] + r * hn);
                u4[k] = (1.f - z) * nn + z * hv;
                lsum += u4[k];
            }
            float mean = block_sum(lsum) * (1.f / D_);
            float lv = 0.f;
            for (int k = 0; k < 4; ++k) { float d = u4[k] - mean; lv += d * d; }
            float inv = rsqrtf(block_sum(lv) * (1.f / D_) + 1e-5f);
            for (int k = 0; k < 4; ++k) {
                int d = tid + 256*k;
                float y = (u4[k] - mean) * inv * ulng[d] + ulnb[d];
                y = fminf(fmaxf(y, -50.f), 50.f);
                h[(size_t)m*D_ + d] = y;
                h16[(size_t)m*D_ + d] = f2h(y);
            }
        }
    }

    // ---------------- Part B: compaction for step s = sfin+1 ----------------
    int s = sfin + 1;
    if (s < S_) {
        if (m == 0 && tid < 32) gatepreN[tid] = 0.f;
        float rm = 0.f;
        if (tid < N_) rm = emask[b*N_ + tid] ? inc[((size_t)b*N_ + tid)*S_ + s] : 0.f;
        float wsum = block_sum(rm);
        float r = emask[m] ? inc[(size_t)m*S_ + s] : 0.f;
        if (r > 0.f) {
            __shared__ int sidx2;
            if (tid == 0) sidx2 = atomicAdd(cntN, 1);
            __syncthreads();
            int idx = sidx2;
            if (tid == 0) { lstN[idx] = m; invb[m] = idx; wsumN[b] = wsum; }
            float rprev = (s > 0 && sfin >= 0) ? inc[(size_t)m*S_ + (s-1)] : 0.f;
            if (rprev <= 0.f) {
                // stale contribution: Hcat[m] is current (not updated at sfin)
                const float4* hp = (const float4*)(Hcat + (size_t)m*HC7);
#pragma unroll
                for (int j2 = 0; j2 < 4; ++j2) {
                    float4 hv = hp[tid + 256*j2];
                    int c = (tid + 256*j2) * 4;
                    float* dst = (c < 1024) ? (esumN + (size_t)b*D_ + c)
                                            : (TmiN + (size_t)b*G3_ + (c - 1024));
                    atomicAdd(dst + 0, r*hv.x); atomicAdd(dst + 1, r*hv.y);
                    atomicAdd(dst + 2, r*hv.z); atomicAdd(dst + 3, r*hv.w);
                }
            }
        }
    }
}

// ---------------------------------------------------------------------------
// Final: buf = LN(buf + scene, res_ln) in-place; also fp16 copy.
// ---------------------------------------------------------------------------
__global__ __launch_bounds__(256) void k_resln(
    float* __restrict__ buf, const float* __restrict__ scene,
    const float* __restrict__ g, const float* __restrict__ bt,
    unsigned short* __restrict__ H16)
{
    size_t row = blockIdx.x;
    int tid = threadIdx.x;
    float x[4]; float lsum = 0.f;
    for (int k = 0; k < 4; ++k) {
        int d = tid + 256*k;
        x[k] = buf[row*D_ + d] + scene[row*D_ + d];
        lsum += x[k];
    }
    float mean = block_sum(lsum) * (1.f / D_);
    float lv = 0.f;
    for (int k = 0; k < 4; ++k) { float d = x[k] - mean; lv += d * d; }
    float inv = rsqrtf(block_sum(lv) * (1.f / D_) + 1e-5f);
    for (int k = 0; k < 4; ++k) {
        int d = tid + 256*k;
        float y = (x[k] - mean) * inv * g[d] + bt[d];
        buf[row*D_ + d] = y;
        H16[row*D_ + d] = f2h(y);
    }
}

// ---------------------------------------------------------------------------
// Final: H = LN(gelu(G), eo_ln); plus h_fin copy blocks.
// ---------------------------------------------------------------------------
__global__ __launch_bounds__(256) void k_final(
    const float* __restrict__ G, const float* __restrict__ g, const float* __restrict__ bt,
    float* __restrict__ outH, const float* __restrict__ h, float* __restrict__ outh)
{
    int tid = threadIdx.x;
    if (blockIdx.x < B_*S_) {
        size_t row = blockIdx.x;
        float x[4]; float lsum = 0.f;
        for (int k = 0; k < 4; ++k) {
            x[k] = gelu_f(G[row*D_ + tid + 256*k]);
            lsum += x[k];
        }
        float mean = block_sum(lsum) * (1.f / D_);
        float lv = 0.f;
        for (int k = 0; k < 4; ++k) { float d = x[k] - mean; lv += d * d; }
        float inv = rsqrtf(block_sum(lv) * (1.f / D_) + 1e-5f);
        for (int k = 0; k < 4; ++k) {
            int d = tid + 256*k;
            outH[row*D_ + d] = (x[k] - mean) * inv * g[d] + bt[d];
        }
    } else {
        size_t bn = blockIdx.x - B_*S_;
        for (int d = tid; d < D_; d += 256)
            outh[bn*D_ + d] = h[bn*D_ + d];
    }
}

// ---------------------------------------------------------------------------
extern "C" void kernel_launch(void* const* d_in, const int* in_sizes, int n_in,
                              void* d_out, int out_size, void* d_ws, size_t ws_size,
                              hipStream_t stream)
{
    const float* scene = (const float*)d_in[0];
    const float* inc   = (const float*)d_in[1];
    const int*   etype = (const int*)d_in[3];
    const int*   emask = (const int*)d_in[4];
    const float* nemb  = (const float*)d_in[5];
    const float* temb  = (const float*)d_in[6];
    const float* nameW = (const float*)d_in[7];
    const float* nlg   = (const float*)d_in[8];
    const float* nlb   = (const float*)d_in[9];
    const float* n2eW  = (const float*)d_in[10];
    const float* n2eb  = (const float*)d_in[11];
    const float* t2eW  = (const float*)d_in[12];
    const float* t2eb  = (const float*)d_in[13];
    const float* elng  = (const float*)d_in[14];
    const float* elnb  = (const float*)d_in[15];
    const float* gW1   = (const float*)d_in[16];
    const float* gb1   = (const float*)d_in[17];
    const float* gW2   = (const float*)d_in[18];
    const float* gb2   = (const float*)d_in[19];
    const float* msW   = (const float*)d_in[20];
    const float* msB   = (const float*)d_in[21];
    const float* maW   = (const float*)d_in[22];
    const float* maB   = (const float*)d_in[23];
    const float* miW   = (const float*)d_in[24];
    const float* miB   = (const float*)d_in[25];
    const float* rolew = (const float*)d_in[26];
    const float* Wih   = (const float*)d_in[27];
    const float* Whh   = (const float*)d_in[28];
    const float* bih   = (const float*)d_in[29];
    const float* bhh   = (const float*)d_in[30];
    const float* ulng  = (const float*)d_in[31];
    const float* ulnb  = (const float*)d_in[32];
    const float* eoW   = (const float*)d_in[33];
    const float* eoB   = (const float*)d_in[34];
    const float* eolng = (const float*)d_in[35];
    const float* eolnb = (const float*)d_in[36];
    const float* rlng  = (const float*)d_in[37];
    const float* rlnb  = (const float*)d_in[38];

    float* outH = (float*)d_out;                    // [B,S,D] — doubles as esbuf
    float* outh = outH + (size_t)B_*S_*D_;          // [B,N,D] h_fin

    float* W = (float*)d_ws;
    size_t o = 0;
    int*   ctrl     = (int*)(W + o); o += 128;           // [cnt0, cnt1, pad..., dcnt[64]]
    float* esum2    = W + o; o += 2*(size_t)B_*D_;       // parity sum r*Hcat[:,0:1024]
    float* Tmi2     = W + o; o += 2*(size_t)B_*G3_;      // parity sum r*Hcat[:,1024:4096]
    float* wsum2    = W + o; o += 16;                    // parity per-batch sum r
    float* gatepre2 = W + o; o += 64;                    // parity gate pre-acts
    int*   list     = (int*)(W + o); o += 2*BN_;
    int*   invb     = (int*)(W + o); o += BN_;
    float* hbuf     = W + o; o += (size_t)BN_*D_;
    float* Hcat     = W + o; o += (size_t)BN_*HC7;
    float* pre_t2e  = W + o; o += (size_t)B_*S_*D_;
    float* gBm      = W + o; o += 4*G3_;
    float* Emi      = W + o; o += (size_t)B_*G3_;
    float* Esmi     = W + o; o += (size_t)B_*S_*G3_;
    float* arcsum   = W + o; o += (size_t)BN_*G3_;
    float* tmp      = W + o; o += (size_t)BN_*D_;        // P (init) and G (final)
    unsigned short* U = (unsigned short*)(W + o);
    size_t uo = 0;
    unsigned short* h16    = U + uo; uo += (size_t)BN_*D_;
    unsigned short* H16    = U + uo; uo += (size_t)B_*S_*D_;
    unsigned short* Wih16  = U + uo; uo += (size_t)G3_*D_;
    unsigned short* Whh16  = U + uo; uo += (size_t)G3_*D_;
    unsigned short* n2e16  = U + uo; uo += (size_t)D_*D_;
    unsigned short* eoW16  = U + uo; uo += (size_t)D_*D_;
    unsigned short* nW16   = U + uo; uo += (size_t)D_*ND_;
    unsigned short* nE16   = U + uo; uo += (size_t)BN_*ND_;
    unsigned short* t2e16  = U + uo; uo += (size_t)D_*D_;
    unsigned short* sc16   = U + uo; uo += (size_t)B_*S_*D_;
    unsigned short* WcatT16= U + uo; uo += (size_t)G3_*D_;
    unsigned short* Wmi16  = U + uo; uo += (size_t)G3_*G3_;
    unsigned short* bias4  = U + uo; uo += 4*D_;

    int* dcnt = ctrl + 64;   // 64 per-step done-counters

    // zero ctrl+dcnt + both parities of esum/Tmi/wsum/gatepre (contiguous)
    hipMemsetAsync(ctrl, 0,
        (128 + 2*(size_t)B_*D_ + 2*(size_t)B_*G3_ + 16 + 64) * sizeof(float), stream);

    // ---- conversions (per call; inputs restored each timed call) ----
    #define CVT(src, dst, r, c, ld) \
        k_f2h<<<(((size_t)(r)*(c)/4 + 255)/256), 256, 0, stream>>>(src, dst, r, c, ld)
    CVT(Wih,   Wih16, G3_, D_,  D_);
    CVT(Whh,   Whh16, G3_, D_,  D_);
    CVT(n2eW,  n2e16, D_,  D_,  D_);
    CVT(nameW, nW16,  D_,  ND_, ND_);
    CVT(nemb,  nE16,  BN_, ND_, ND_);
    CVT(eoW,   eoW16, D_,  D_,  D_);
    CVT(t2eW,  t2e16, D_,  D_,  D_);
    CVT(scene, sc16,  B_*S_, D_, D_);
    CVT(msB,   bias4 + 0,    1, D_, D_);
    CVT(maB,   bias4 + D_,   1, D_, D_);
    CVT(miB,   bias4 + 2*D_, 1, D_, D_);
    CVT(rolew, bias4 + 3*D_, 1, D_, D_);
    #undef CVT
    // WcatT16[seg*1024 + k][d] = {ms,ma,mi}W[d][k]  (transposed, fp16)
    k_f2hT<<<dim3(32,32), 256, 0, stream>>>(msW, WcatT16, D_, D_, D_, 0);
    k_f2hT<<<dim3(32,32), 256, 0, stream>>>(maW, WcatT16, D_, D_, D_, D_);
    k_f2hT<<<dim3(32,32), 256, 0, stream>>>(miW, WcatT16, D_, D_, D_, 2*D_);

    // Wmi16 = 256 * (Wih @ Wcat)  [3072,3072] fp16 (cols: es|arc|int segs)
    k_mfma16_nt<<<dim3(G3_/128, G3_/64), 256, 0, stream>>>(
        Wih16, WcatT16, nullptr, nullptr, Wmi16, 256.f, G3_, G3_, D_);
    // gBm[4,3072] = [msB|maB|miB|rolew] @ Wih^T
    k_mfma16_nt<<<dim3(G3_/128, 1), 256, 0, stream>>>(
        bias4, Wih16, nullptr, gBm, nullptr, 1.f, 4, G3_, D_);
    // pre_t2e[b,s,:] = t2e(scene) + t2eb
    k_mfma16_nt<<<dim3(D_/128, (B_*S_+63)/64), 256, 0, stream>>>(
        sc16, t2e16, t2eb, pre_t2e, nullptr, 1.f, B_*S_, D_, D_);
    // init: P = name_embs @ name_W^T ; h0 ; Hcat0
    k_mfma16_nt<<<dim3(D_/128, (BN_+63)/64), 256, 0, stream>>>(
        nE16, nW16, nullptr, tmp, nullptr, 1.f, BN_, D_, ND_);
    k_h0<<<BN_, 256, 0, stream>>>(tmp, etype, emask, temb, nlg, nlb, hbuf, h16);
    k_hcat0<<<dim3(112, 25), 256, 0, stream>>>(h16, n2e16, Wmi16, Whh16, Hcat);

    // ---- pre-loop: compaction for step 0 (fin part disabled via sfin=-1) ----
    k_step2<<<BN_, 256, 0, stream>>>(inc, emask, gatepre2, gb2, Hcat, Emi,
        arcsum, Tmi2, wsum2, invb, gBm, bih, bhh, ulng, ulnb, hbuf, h16,
        ctrl + 0, list + 0, wsum2 + 0, esum2, Tmi2, gatepre2, -1);

    // ---- 64-step recurrence: 2 launches/step ----
    for (int s = 0; s < S_; ++s) {
        int par = s & 1, parn = 1 - par;
        k_step1<<<GT_ + BN_ + 128, 256, 0, stream>>>(
            inc, emask, Esmi, arcsum,
            ctrl + parn /*prev count*/, list + parn * BN_, invb,
            h16, n2e16, Wmi16, Whh16, Hcat,
            esum2 + (size_t)par * B_ * D_, Tmi2 + (size_t)par * B_ * G3_,
            wsum2 + par * 8,
            esum2 + (size_t)parn * B_ * D_, Tmi2 + (size_t)parn * B_ * G3_,
            wsum2 + parn * 8, ctrl + parn,
            n2eb, pre_t2e, elng, elnb, gW1, gb1, gW2,
            outH, gatepre2 + par * 32, Emi,
            dcnt + s, s);
        k_step2<<<BN_, 256, 0, stream>>>(
            inc, emask, gatepre2 + par * 32, gb2, Hcat, Emi, arcsum,
            Tmi2 + (size_t)par * B_ * G3_, wsum2 + par * 8, invb,
            gBm, bih, bhh, ulng, ulnb, hbuf, h16,
            ctrl + parn, list + parn * BN_, wsum2 + parn * 8,
            esum2 + (size_t)parn * B_ * D_, Tmi2 + (size_t)parn * B_ * G3_,
            gatepre2 + parn * 32, s);
    }

    // epilogue: H = LN(gelu(LN(es + scene) @ eo_W^T + eo_b)); h_fin copy
    k_resln<<<B_*S_, 256, 0, stream>>>(outH, scene, rlng, rlnb, H16);
    k_mfma16_nt<<<dim3(D_/128, (B_*S_+63)/64), 256, 0, stream>>>(
        H16, eoW16, eoB, tmp, nullptr, 1.f, B_*S_, D_, D_);
    k_final<<<B_*S_ + BN_, 256, 0, stream>>>(tmp, eolng, eolnb, outH, hbuf, outh);
}

// Round 5
// 7569.741 us; speedup vs baseline: 1.8671x; 1.6697x over previous
//
#include <hip/hip_runtime.h>
#include <math.h>

#define B_   8
#define S_   64
#define N_   100
#define D_   1024
#define ND_  768
#define BN_  800
#define G3_  3072
#define HC7  7168
#define GMT  448    // GEMM tasks: 112 col-tiles x 4 m-groups (256 rows each)
#define RSC  0.00390625f   // 1/256 — Wmi stored x256 to avoid fp16 subnormals

typedef _Float16 f16x8 __attribute__((ext_vector_type(8)));
typedef float f32x4 __attribute__((ext_vector_type(4)));

#define MFMA16(a,b,c) __builtin_amdgcn_mfma_f32_16x16x32_f16(a, b, c, 0, 0, 0)

static __device__ __forceinline__ float wave_sum(float v) {
    for (int off = 32; off > 0; off >>= 1) v += __shfl_down(v, off, 64);
    return v;
}

static __device__ __forceinline__ float wave_allsum(float v) {
    for (int off = 1; off < 64; off <<= 1) v += __shfl_xor(v, off, 64);
    return v;
}

// All 256 threads must call; returns full-block sum to every thread.
static __device__ __forceinline__ float block_sum(float v) {
    __shared__ float red_[8];
    float w = wave_sum(v);
    int lane = threadIdx.x & 63, wid = threadIdx.x >> 6;
    __syncthreads();               // protect red_ reuse across calls
    if (lane == 0) red_[wid] = w;
    __syncthreads();
    float t = 0.f;
    for (int i = 0; i < 4; ++i) t += red_[i];
    return t;
}

static __device__ __forceinline__ float gelu_f(float x) {
    return 0.5f * x * (1.f + erff(x * 0.70710678118654752f));
}

static __device__ __forceinline__ unsigned short f2h(float x) {
    union { _Float16 h; unsigned short u; } c; c.h = (_Float16)x; return c.u;
}

// ---------------------------------------------------------------------------
// fp32 -> fp16 2D convert. cols % 4 == 0.
// ---------------------------------------------------------------------------
__global__ __launch_bounds__(256) void k_f2h(
    const float* __restrict__ src, unsigned short* __restrict__ dst,
    int rows, int cols, int ldd)
{
    size_t n = (size_t)rows * cols;
    size_t i = ((size_t)blockIdx.x * 256 + threadIdx.x) * 4;
    if (i >= n) return;
    int r = (int)(i / cols);
    int c = (int)(i - (size_t)r * cols);
    float4 v = *(const float4*)(src + i);
    ushort4 o; o.x = f2h(v.x); o.y = f2h(v.y); o.z = f2h(v.z); o.w = f2h(v.w);
    *(ushort4*)(dst + (size_t)r * ldd + c) = o;
}

// ---------------------------------------------------------------------------
// fp32 -> fp16 TRANSPOSING convert: dst[rowoff + c][r] = src[r][c].
// ---------------------------------------------------------------------------
__global__ __launch_bounds__(256) void k_f2hT(
    const float* __restrict__ src, unsigned short* __restrict__ dst,
    int R, int C, int ldd, int rowoff)
{
    __shared__ _Float16 T[32][33];
    int tr = threadIdx.x >> 3, tc4 = (threadIdx.x & 7) * 4;
    int r0 = blockIdx.y * 32, c0 = blockIdx.x * 32;
    float4 v = *(const float4*)(src + (size_t)(r0 + tr) * C + c0 + tc4);
    T[tc4][tr] = (_Float16)v.x; T[tc4+1][tr] = (_Float16)v.y;
    T[tc4+2][tr] = (_Float16)v.z; T[tc4+3][tr] = (_Float16)v.w;
    __syncthreads();
    union { _Float16 h; unsigned short u; } cv;
    ushort4 o;
    cv.h = T[tr][tc4];   o.x = cv.u;
    cv.h = T[tr][tc4+1]; o.y = cv.u;
    cv.h = T[tr][tc4+2]; o.z = cv.u;
    cv.h = T[tr][tc4+3]; o.w = cv.u;
    *(ushort4*)(dst + (size_t)(rowoff + c0 + tr) * ldd + r0 + tc4) = o;
}

// ---------------------------------------------------------------------------
// FP16 MFMA GEMM (setup/epilogue only): C[M,Nc] = A16[M,K] @ W16[Nc,K]^T.
// ---------------------------------------------------------------------------
__global__ __launch_bounds__(256) void k_mfma16_nt(
    const unsigned short* __restrict__ A16, const unsigned short* __restrict__ W16,
    const float* __restrict__ bias, float* __restrict__ C,
    unsigned short* __restrict__ C16, float oscale,
    int M, int Nc, int K)
{
    int m0 = blockIdx.y * 64; if (m0 >= M) return;
    int n0 = blockIdx.x * 128;
    __shared__ _Float16 sA[64][72];
    __shared__ _Float16 sB[128][72];
    int tid = threadIdx.x;
    int w = tid >> 6, l = tid & 63;
    int l15 = l & 15, q = l >> 4;
    int wn = w * 32;
    int arow = tid >> 3, achk = (tid & 7) * 8;
    f32x4 acc[4][2] = {};
    for (int k0 = 0; k0 < K; k0 += 64) {
        for (int ri = 0; ri < 64; ri += 32) {
            int gm = m0 + arow + ri;
            uint4 v = make_uint4(0u, 0u, 0u, 0u);
            if (gm < M) v = *(const uint4*)(A16 + (size_t)gm * K + k0 + achk);
            *(uint4*)(&sA[arow + ri][achk]) = v;
        }
        for (int i = 0; i < 4; ++i) {
            int r = arow + 32 * i;
            *(uint4*)(&sB[r][achk]) = *(const uint4*)(W16 + (size_t)(n0 + r) * K + k0 + achk);
        }
        __syncthreads();
#pragma unroll
        for (int ks = 0; ks < 64; ks += 32) {
            f16x8 b0 = *(const f16x8*)(&sB[wn + l15][ks + q*8]);
            f16x8 b1 = *(const f16x8*)(&sB[wn + 16 + l15][ks + q*8]);
#pragma unroll
            for (int mi = 0; mi < 4; ++mi) {
                f16x8 a = *(const f16x8*)(&sA[mi*16 + l15][ks + q*8]);
                acc[mi][0] = MFMA16(a, b0, acc[mi][0]);
                acc[mi][1] = MFMA16(a, b1, acc[mi][1]);
            }
        }
        __syncthreads();
    }
    for (int mi = 0; mi < 4; ++mi)
        for (int nj = 0; nj < 2; ++nj)
            for (int r = 0; r < 4; ++r) {
                int gm = m0 + mi*16 + q*4 + r;
                int cl = wn + nj*16 + l15;
                if (gm < M) {
                    size_t off = (size_t)gm * Nc + n0 + cl;
                    float v = acc[mi][nj][r];
                    if (C16) C16[off] = f2h(v * oscale);
                    else C[off] = v + (bias ? bias[n0 + cl] : 0.f);
                }
            }
}

// ---------------------------------------------------------------------------
// h0 = mask * (type_embed[type] + LN(P, name_ln)); fp32 h + fp16 mirror
// ---------------------------------------------------------------------------
__global__ __launch_bounds__(256) void k_h0(
    const float* __restrict__ P, const int* __restrict__ etype,
    const int* __restrict__ emask, const float* __restrict__ temb,
    const float* __restrict__ g, const float* __restrict__ bt,
    float* __restrict__ h, unsigned short* __restrict__ h16)
{
    int bn = blockIdx.x, tid = threadIdx.x;
    int t = etype[bn], mk = emask[bn];
    float x[4]; float lsum = 0.f;
    for (int k = 0; k < 4; ++k) { x[k] = P[(size_t)bn*D_ + tid + 256*k]; lsum += x[k]; }
    float mean = block_sum(lsum) * (1.f / D_);
    float lv = 0.f;
    for (int k = 0; k < 4; ++k) { float d = x[k] - mean; lv += d * d; }
    float inv = rsqrtf(block_sum(lv) * (1.f / D_) + 1e-5f);
    for (int k = 0; k < 4; ++k) {
        int d = tid + 256*k;
        float y = (x[k] - mean) * inv * g[d] + bt[d];
        float hv = mk ? (temb[(size_t)t*D_ + d] + y) : 0.f;
        h[(size_t)bn*D_ + d] = hv;
        h16[(size_t)bn*D_ + d] = f2h(hv);
    }
}

// ---------------------------------------------------------------------------
// Hcat init: Hcat[bn, 0:1024|1024:4096|4096:7168] = h16[bn] @ [n2e|Wmi2|Whh]^T
// Grid (112, 25). TM=32, TN=64.
// ---------------------------------------------------------------------------
__global__ __launch_bounds__(256) void k_hcat0(
    const unsigned short* __restrict__ h16, const unsigned short* __restrict__ n2e16,
    const unsigned short* __restrict__ Wmi16, const unsigned short* __restrict__ Whh16,
    float* __restrict__ Hcat)
{
    int m0 = blockIdx.y * 32;
    int n0 = blockIdx.x * 64;
    const unsigned short* Bp; int ldb; int nl;
    if (n0 < 1024)      { Bp = n2e16;        ldb = D_;  nl = n0; }
    else if (n0 < 4096) { Bp = Wmi16 + 2048; ldb = G3_; nl = n0 - 1024; }
    else                { Bp = Whh16;        ldb = D_;  nl = n0 - 4096; }
    __shared__ _Float16 sA[32][72];
    __shared__ _Float16 sB[64][72];
    int tid = threadIdx.x;
    int w = tid >> 6, l = tid & 63;
    int l15 = l & 15, q = l >> 4;
    int wm = (w & 1) * 16, wn = (w >> 1) * 32;
    int arow = tid >> 3, achk = (tid & 7) * 8;
    int gmA = m0 + arow;
    f32x4 acc[2] = {};
    for (int k0 = 0; k0 < D_; k0 += 64) {
        *(uint4*)(&sA[arow][achk]) = *(const uint4*)(h16 + (size_t)gmA*D_ + k0 + achk);
        *(uint4*)(&sB[arow][achk])      = *(const uint4*)(Bp + (size_t)(nl + arow)*ldb + k0 + achk);
        *(uint4*)(&sB[arow + 32][achk]) = *(const uint4*)(Bp + (size_t)(nl + arow + 32)*ldb + k0 + achk);
        __syncthreads();
#pragma unroll
        for (int ks = 0; ks < 64; ks += 32) {
            f16x8 a  = *(const f16x8*)(&sA[wm + l15][ks + q*8]);
            f16x8 b0 = *(const f16x8*)(&sB[wn + l15][ks + q*8]);
            f16x8 b1 = *(const f16x8*)(&sB[wn + 16 + l15][ks + q*8]);
            acc[0] = MFMA16(a, b0, acc[0]);
            acc[1] = MFMA16(a, b1, acc[1]);
        }
        __syncthreads();
    }
    for (int j = 0; j < 2; ++j)
        for (int r = 0; r < 4; ++r) {
            int row = wm + q*4 + r;
            Hcat[(size_t)(m0 + row)*HC7 + n0 + wn + j*16 + l15] = acc[j][r];
        }
}

// ---------------------------------------------------------------------------
// K_front: blocks [0,800): compaction + arcsum (float4) + scalars + stale
//          esum/Tmi contributions for rows whose Hcat is current.
//          blocks [800, 800+448): Hcat update GEMM, 4 m-tiles (256 rows) per
//          block sharing one B-tile read — weights read ONCE per step.
// Block 0 zeroes gatepre.
// ---------------------------------------------------------------------------
union SMF {
    struct { _Float16 A[256][72]; _Float16 Bm[64][72];
             int slist[256]; float srn[256]; int sbb[256]; } g;   // 49.2+3 KB
    struct { float wav[S_]; int wai[S_]; } r;
};

__global__ __launch_bounds__(256) void k_front(
    const float* __restrict__ inc, const int* __restrict__ emask,
    const float* __restrict__ Esmi, float* __restrict__ arcsum,
    int* __restrict__ cntp, int* __restrict__ lst, float* __restrict__ rro,
    float* __restrict__ scl,
    const int* __restrict__ prevcnt, const int* __restrict__ prevlist,
    const unsigned short* __restrict__ h16, const unsigned short* __restrict__ n2e16,
    const unsigned short* __restrict__ Wmi16, const unsigned short* __restrict__ Whh16,
    float* __restrict__ Hcat, float* __restrict__ gatepre,
    float* __restrict__ esumP, float* __restrict__ TmiP, float* __restrict__ wsumP,
    int s)
{
    __shared__ SMF sm;
    __shared__ int sidx, nwa;
    int tid = threadIdx.x, bid = blockIdx.x;
    if (bid == 0 && tid < 32) gatepre[tid] = 0.f;
    if (bid < BN_) {
        int m = bid;
        int b = m / N_;
        float r = emask[m] ? inc[(size_t)m*S_ + s] : 0.f;
        if (r <= 0.f) return;
        if (tid == 0) { sidx = atomicAdd(cntp, 1); nwa = 0; }
        __syncthreads();
        int idx = sidx;
        float denomA = fmaxf((float)(s - 1), 1.f);
        float wa = 0.f;
        if (tid < s) {
            float iv = inc[(size_t)m*S_ + tid];
            if (iv > 0.f) {
                wa = iv * r * expf(-1.f + (float)tid / denomA);
                int p = atomicAdd(&nwa, 1);
                sm.r.wav[p] = wa; sm.r.wai[p] = tid;
            }
        }
        float dA = block_sum(wa);
        float rm = 0.f;
        if (tid < N_) rm = emask[b*N_ + tid] ? inc[((size_t)b*N_ + tid)*S_ + s] : 0.f;
        float wsum = block_sum(rm);
        __syncthreads();
        int na = nwa;
        float sclA = 1.f / fmaxf(dA, 1e-8f);
        if (tid == 0) {
            lst[idx] = m; rro[idx] = r;
            scl[idx] = r / fmaxf(r * (wsum - r), 1e-8f);
            wsumP[b] = wsum;
        }
        // esum/Tmi: rows NOT updated at s-1 have current Hcat -> accumulate here.
        float rprev = (s > 0) ? inc[(size_t)m*S_ + (s-1)] : 0.f;
        if (rprev <= 0.f) {
            const float4* hp = (const float4*)(Hcat + (size_t)m*HC7);
#pragma unroll
            for (int j2 = 0; j2 < 4; ++j2) {
                float4 hv = hp[tid + 256*j2];
                int c = (tid + 256*j2) * 4;
                float* dst = (c < 1024) ? (esumP + (size_t)b*D_ + c)
                                        : (TmiP + (size_t)b*G3_ + (c - 1024));
                atomicAdd(dst + 0, r*hv.x); atomicAdd(dst + 1, r*hv.y);
                atomicAdd(dst + 2, r*hv.z); atomicAdd(dst + 3, r*hv.w);
            }
        }
        // arcsum [3072]: float4-vectorized (3 x float4 per thread)
        float4 a4[3];
#pragma unroll
        for (int k = 0; k < 3; ++k) a4[k] = make_float4(0.f,0.f,0.f,0.f);
        for (int j = 0; j < na; ++j) {
            float wj = sm.r.wav[j];
            const float4* ep = (const float4*)(Esmi + ((size_t)b*S_ + sm.r.wai[j])*G3_);
#pragma unroll
            for (int k = 0; k < 3; ++k) {
                float4 e = ep[tid + 256*k];
                a4[k].x += wj*e.x; a4[k].y += wj*e.y;
                a4[k].z += wj*e.z; a4[k].w += wj*e.w;
            }
        }
        float4* ao = (float4*)(arcsum + (size_t)idx*G3_);
#pragma unroll
        for (int k = 0; k < 3; ++k) {
            float4 v = make_float4(a4[k].x*sclA, a4[k].y*sclA,
                                   a4[k].z*sclA, a4[k].w*sclA);
            ao[tid + 256*k] = v;
        }
    } else {
        int pM = *prevcnt;
        int t = bid - BN_;
        int nt = t % 112, mg = t / 112;
        int m0 = mg * 256;
        if (m0 >= pM) return;
        int n0 = nt * 64;
        const unsigned short* Bp; int ldb; int nl;
        if (n0 < 1024)      { Bp = n2e16;        ldb = D_;  nl = n0; }
        else if (n0 < 4096) { Bp = Wmi16 + 2048; ldb = G3_; nl = n0 - 1024; }
        else                { Bp = Whh16;        ldb = D_;  nl = n0 - 4096; }
        {
            int gm = m0 + tid;
            int m = (gm < pM) ? prevlist[gm] : 0;
            sm.g.slist[tid] = m;
            float rn = 0.f;
            if (gm < pM) rn = emask[m] ? inc[(size_t)m*S_ + s] : 0.f;
            sm.g.srn[tid] = rn;
            sm.g.sbb[tid] = m / N_;
        }
        __syncthreads();
        int w = tid >> 6, l = tid & 63;
        int l15 = l & 15, q = l >> 4;
        int wm = (w & 1) * 32, wn = (w >> 1) * 32;
        int arow = tid >> 3, achk = (tid & 7) * 8;
        int nmt = (pM - m0 + 63) >> 6; if (nmt > 4) nmt = 4;
        int nrow = nmt * 64;
        f32x4 acc[4][2][2] = {};
        for (int k0 = 0; k0 < D_; k0 += 64) {
            for (int ri = 0; ri < nrow; ri += 32) {
                int row = arow + ri, gm = m0 + row;
                uint4 v = make_uint4(0u,0u,0u,0u);
                if (gm < pM) v = *(const uint4*)(h16 + (size_t)sm.g.slist[row]*D_ + k0 + achk);
                *(uint4*)(&sm.g.A[row][achk]) = v;
            }
            *(uint4*)(&sm.g.Bm[arow][achk])      = *(const uint4*)(Bp + (size_t)(nl + arow)*ldb + k0 + achk);
            *(uint4*)(&sm.g.Bm[arow + 32][achk]) = *(const uint4*)(Bp + (size_t)(nl + arow + 32)*ldb + k0 + achk);
            __syncthreads();
#pragma unroll
            for (int ks = 0; ks < 64; ks += 32) {
                f16x8 b0 = *(const f16x8*)(&sm.g.Bm[wn + l15][ks + q*8]);
                f16x8 b1 = *(const f16x8*)(&sm.g.Bm[wn + 16 + l15][ks + q*8]);
#pragma unroll
                for (int mt = 0; mt < 4; ++mt) {
                    if (mt < nmt) {
                        f16x8 a0 = *(const f16x8*)(&sm.g.A[mt*64 + wm + l15][ks + q*8]);
                        f16x8 a1 = *(const f16x8*)(&sm.g.A[mt*64 + wm + 16 + l15][ks + q*8]);
                        acc[mt][0][0] = MFMA16(a0, b0, acc[mt][0][0]);
                        acc[mt][0][1] = MFMA16(a0, b1, acc[mt][0][1]);
                        acc[mt][1][0] = MFMA16(a1, b0, acc[mt][1][0]);
                        acc[mt][1][1] = MFMA16(a1, b1, acc[mt][1][1]);
                    }
                }
            }
            __syncthreads();
        }
#pragma unroll
        for (int mt = 0; mt < 4; ++mt) {
            if (mt >= nmt) continue;
            for (int mi = 0; mi < 2; ++mi)
                for (int nj = 0; nj < 2; ++nj)
                    for (int r4 = 0; r4 < 4; ++r4) {
                        int row = mt*64 + wm + mi*16 + q*4 + r4;
                        int gm = m0 + row;
                        if (gm < pM) {
                            float v = acc[mt][mi][nj][r4];
                            int c = n0 + wn + nj*16 + l15;
                            Hcat[(size_t)sm.g.slist[row]*HC7 + c] = v;
                            float rn = sm.g.srn[row];
                            if (rn > 0.f && c < 4096) {
                                float* dst = (c < 1024)
                                    ? (esumP + (size_t)sm.g.sbb[row]*D_ + c)
                                    : (TmiP + (size_t)sm.g.sbb[row]*G3_ + (c - 1024));
                                atomicAdd(dst, rn * v);
                            }
                        }
                    }
        }
    }
}

// ---------------------------------------------------------------------------
// K_mid (grid 128): [0,32) light e_s + gate MLP; [32,128) Emi/Esmi GEMV,
// all 8 batches sharing one Wmi16 read. Block 0 resets next step's counter.
// ---------------------------------------------------------------------------
__global__ __launch_bounds__(256) void k_mid(
    const float* __restrict__ esumP, const float* __restrict__ wsumP,
    float* __restrict__ esumZ, float* __restrict__ TmiZ, float* __restrict__ wsumZ,
    const float* __restrict__ n2eb, const float* __restrict__ pre_t2e,
    const float* __restrict__ elng, const float* __restrict__ elnb,
    const float* __restrict__ gW1, const float* __restrict__ gb1,
    const float* __restrict__ gW2, const unsigned short* __restrict__ Wmi16,
    float* __restrict__ esbuf, float* __restrict__ gatepre,
    float* __restrict__ Emi, float* __restrict__ Esmi,
    int* __restrict__ ctrl, int par, int s)
{
    int bid = blockIdx.x, tid = threadIdx.x;
    if (bid < 32) {
        __shared__ float se[D_];
        int b = bid >> 2, seg = bid & 3;
        if (bid == 0 && tid == 0) ctrl[1 - par] = 0;
        esumZ[(size_t)b*D_ + seg*256 + tid] = 0.f;
#pragma unroll
        for (int j = 0; j < 3; ++j) TmiZ[(size_t)b*G3_ + seg*768 + j*256 + tid] = 0.f;
        if (seg == 0 && tid == 0) wsumZ[b] = 0.f;
        float invw = 1.f / fmaxf(wsumP[b], 1.f);
        float4 ev = ((const float4*)(esumP + (size_t)b*D_))[tid];
        float4 nb = ((const float4*)n2eb)[tid];
        float4 pt = ((const float4*)(pre_t2e + ((size_t)b*S_ + s)*D_))[tid];
        float x[4] = { ev.x*invw + nb.x + pt.x, ev.y*invw + nb.y + pt.y,
                       ev.z*invw + nb.z + pt.z, ev.w*invw + nb.w + pt.w };
        float mean = block_sum(x[0]+x[1]+x[2]+x[3]) * (1.f / D_);
        float lv = 0.f;
#pragma unroll
        for (int k = 0; k < 4; ++k) { float d = x[k] - mean; lv += d * d; }
        float inv = rsqrtf(block_sum(lv) * (1.f / D_) + 1e-5f);
        float4 lg = ((const float4*)elng)[tid];
        float4 lb = ((const float4*)elnb)[tid];
        float y0 = (x[0]-mean)*inv*lg.x + lb.x;
        float y1 = (x[1]-mean)*inv*lg.y + lb.y;
        float y2 = (x[2]-mean)*inv*lg.z + lb.z;
        float y3 = (x[3]-mean)*inv*lg.w + lb.w;
        int d4 = tid * 4;
        se[d4] = y0; se[d4+1] = y1; se[d4+2] = y2; se[d4+3] = y3;
        if (seg == 0)
            ((float4*)(esbuf + ((size_t)b*S_ + s)*D_))[tid] = make_float4(y0,y1,y2,y3);
        __syncthreads();
        if (tid < 64) {
            int u = seg * 64 + tid;
            float acc = gb1[u];
            const float* w1 = gW1 + (size_t)u * D_;
            for (int j = 0; j < D_; j += 4) {
                float4 w = *(const float4*)(w1 + j);
                acc += w.x*se[j] + w.y*se[j+1] + w.z*se[j+2] + w.w*se[j+3];
            }
            float hg = gelu_f(acc);
            for (int c = 0; c < 3; ++c) {
                float p = wave_sum(gW2[c*256 + u] * hg);
                if (tid == 0) atomicAdd(gatepre + b*4 + c, p);
            }
        }
    } else {
        __shared__ float se32[8][1028];
        int w = tid >> 6, lane = tid & 63;
        for (int bb = 0; bb < 2; ++bb) {
            int b = w*2 + bb;
            float invw = 1.f / fmaxf(wsumP[b], 1.f);
            int d0 = lane * 16;
            const float4* ep = (const float4*)(esumP + (size_t)b*D_ + d0);
            const float4* np = (const float4*)(n2eb + d0);
            const float4* pp = (const float4*)(pre_t2e + ((size_t)b*S_ + s)*D_ + d0);
            float x[16]; float smv = 0.f;
#pragma unroll
            for (int j = 0; j < 4; ++j) {
                float4 e = ep[j], n = np[j], p = pp[j];
                x[j*4+0] = e.x*invw + n.x + p.x;
                x[j*4+1] = e.y*invw + n.y + p.y;
                x[j*4+2] = e.z*invw + n.z + p.z;
                x[j*4+3] = e.w*invw + n.w + p.w;
                smv += x[j*4+0] + x[j*4+1] + x[j*4+2] + x[j*4+3];
            }
            float mean = wave_allsum(smv) * (1.f / D_);
            float lv = 0.f;
#pragma unroll
            for (int j = 0; j < 16; ++j) { float d = x[j] - mean; lv += d * d; }
            float inv = rsqrtf(wave_allsum(lv) * (1.f / D_) + 1e-5f);
            const float4* lgp = (const float4*)(elng + d0);
            const float4* lbp = (const float4*)(elnb + d0);
#pragma unroll
            for (int j = 0; j < 4; ++j) {
                float4 lg = lgp[j], lb = lbp[j];
                se32[b][d0 + j*4 + 0] = (x[j*4+0]-mean)*inv*lg.x + lb.x;
                se32[b][d0 + j*4 + 1] = (x[j*4+1]-mean)*inv*lg.y + lb.y;
                se32[b][d0 + j*4 + 2] = (x[j*4+2]-mean)*inv*lg.z + lb.z;
                se32[b][d0 + j*4 + 3] = (x[j*4+3]-mean)*inv*lg.w + lb.w;
            }
        }
        __syncthreads();
        int c0 = (bid - 32) * 32;
        int colg = tid >> 5, t31 = tid & 31;
        int cb = c0 + colg * 4;
        float accA[4][8] = {};
        float accB[4][8] = {};
#pragma unroll
        for (int i = 0; i < 8; ++i) {
            int kh = t31*4 + i*128;
            float wf[4][4];
#pragma unroll
            for (int c = 0; c < 4; ++c) {
                union { uint2 u; _Float16 h[4]; } cv;
                cv.u = *(const uint2*)(Wmi16 + (size_t)(cb + c)*G3_ + kh);
                wf[c][0] = (float)cv.h[0]; wf[c][1] = (float)cv.h[1];
                wf[c][2] = (float)cv.h[2]; wf[c][3] = (float)cv.h[3];
            }
#pragma unroll
            for (int b = 0; b < 8; ++b) {
                float4 sv = *(const float4*)(&se32[b][kh]);
#pragma unroll
                for (int c = 0; c < 4; ++c)
                    accA[c][b] += wf[c][0]*sv.x + wf[c][1]*sv.y
                                + wf[c][2]*sv.z + wf[c][3]*sv.w;
            }
        }
#pragma unroll
        for (int i = 0; i < 8; ++i) {
            int kh = t31*4 + i*128;
            float wf[4][4];
#pragma unroll
            for (int c = 0; c < 4; ++c) {
                union { uint2 u; _Float16 h[4]; } cv;
                cv.u = *(const uint2*)(Wmi16 + (size_t)(cb + c)*G3_ + 1024 + kh);
                wf[c][0] = (float)cv.h[0]; wf[c][1] = (float)cv.h[1];
                wf[c][2] = (float)cv.h[2]; wf[c][3] = (float)cv.h[3];
            }
#pragma unroll
            for (int b = 0; b < 8; ++b) {
                float4 sv = *(const float4*)(&se32[b][kh]);
#pragma unroll
                for (int c = 0; c < 4; ++c)
                    accB[c][b] += wf[c][0]*sv.x + wf[c][1]*sv.y
                                + wf[c][2]*sv.z + wf[c][3]*sv.w;
            }
        }
#pragma unroll
        for (int off = 16; off >= 1; off >>= 1) {
#pragma unroll
            for (int c = 0; c < 4; ++c)
#pragma unroll
                for (int b = 0; b < 8; ++b) {
                    accA[c][b] += __shfl_down(accA[c][b], off, 32);
                    accB[c][b] += __shfl_down(accB[c][b], off, 32);
                }
        }
        if (t31 == 0) {
#pragma unroll
            for (int c = 0; c < 4; ++c) {
                int col = cb + c;
#pragma unroll
                for (int b = 0; b < 8; ++b) {
                    Emi[(size_t)b*G3_ + col] = accA[c][b];
                    Esmi[((size_t)b*S_ + s)*G3_ + col] = accB[c][b];
                }
            }
        }
    }
}

// ---------------------------------------------------------------------------
// K_fin: GRU assembly + LN + clip + h update.
// ---------------------------------------------------------------------------
__global__ __launch_bounds__(256) void k_fin(
    const int* __restrict__ lst, const int* __restrict__ cntp,
    const float* __restrict__ rro, const float* __restrict__ scl,
    const float* __restrict__ gatepre, const float* __restrict__ gb2,
    const float* __restrict__ Hcat, const float* __restrict__ Emi,
    const float* __restrict__ arcsum, const float* __restrict__ Tmi,
    const float* __restrict__ gBm, const float* __restrict__ bih,
    const float* __restrict__ bhh,
    const float* __restrict__ ulng, const float* __restrict__ ulnb,
    float* __restrict__ h, unsigned short* __restrict__ h16, int s)
{
    int row = blockIdx.x;
    if (row >= *cntp) return;
    int bn = lst[row];
    int b = bn / N_;
    int tid = threadIdx.x;
    float t0 = gatepre[b*4+0] + gb2[0];
    float t1 = gatepre[b*4+1] + gb2[1];
    float t2 = gatepre[b*4+2] + gb2[2];
    float mx = fmaxf(t0, fmaxf(t1, t2));
    float e0 = expf(t0-mx), e1 = expf(t1-mx), e2 = expf(t2-mx);
    float si = 1.f / (e0 + e1 + e2);
    float g0 = e0*si, g1 = (s > 0) ? e1*si : 0.f, g2 = e2*si;
    float rv = rro[row];
    float sI = scl[row];
    const float* Hrow = Hcat + (size_t)bn * HC7;
    const float* em = Emi + (size_t)b * G3_;
    const float* as = arcsum + (size_t)row * G3_;
    const float* tm = Tmi + (size_t)b * G3_;
    float u[4]; float lsum = 0.f;
    for (int k = 0; k < 4; ++k) {
        int d = tid + 256*k;
        float ip[3];
#pragma unroll
        for (int c = 0; c < 3; ++c) {
            int dd = c*D_ + d;
            float gint = tm[dd] - rv * Hrow[1024 + dd];
            ip[c] = RSC * (g0*em[dd] + g1*as[dd] + g2*sI*gint)
                  + g0*gBm[dd] + g1*gBm[G3_ + dd] + g2*gBm[2*G3_ + dd]
                  + rv*gBm[3*G3_ + dd] + bih[dd];
        }
        float hr = Hrow[4096 + d]        + bhh[d];
        float hz = Hrow[4096 + D_ + d]   + bhh[D_ + d];
        float hn = Hrow[4096 + 2*D_ + d] + bhh[2*D_ + d];
        float hv = h[(size_t)bn*D_ + d];
        float r = 1.f / (1.f + expf(-(ip[0] + hr)));
        float z = 1.f / (1.f + expf(-(ip[1] + hz)));
        float nn = tanhf(ip[2] + r * hn);
        u[k] = (1.f - z) * nn + z * hv;
        lsum += u[k];
    }
    float mean = block_sum(lsum) * (1.f / D_);
    float lv = 0.f;
    for (int k = 0; k < 4; ++k) { float d = u[k] - mean; lv += d * d; }
    float inv = rsqrtf(block_sum(lv) * (1.f / D_) + 1e-5f);
    for (int k = 0; k < 4; ++k) {
        int d = tid + 256*k;
        float y = (u[k] - mean) * inv * ulng[d] + ulnb[d];
        y = fminf(fmaxf(y, -50.f), 50.f);
        h[(size_t)bn*D_ + d] = y;
        h16[(size_t)bn*D_ + d] = f2h(y);
    }
}

// ---------------------------------------------------------------------------
// Final: buf = LN(buf + scene, res_ln) in-place; also fp16 copy.
// ---------------------------------------------------------------------------
__global__ __launch_bounds__(256) void k_resln(
    float* __restrict__ buf, const float* __restrict__ scene,
    const float* __restrict__ g, const float* __restrict__ bt,
    unsigned short* __restrict__ H16)
{
    size_t row = blockIdx.x;
    int tid = threadIdx.x;
    float x[4]; float lsum = 0.f;
    for (int k = 0; k < 4; ++k) {
        int d = tid + 256*k;
        x[k] = buf[row*D_ + d] + scene[row*D_ + d];
        lsum += x[k];
    }
    float mean = block_sum(lsum) * (1.f / D_);
    float lv = 0.f;
    for (int k = 0; k < 4; ++k) { float d = x[k] - mean; lv += d * d; }
    float inv = rsqrtf(block_sum(lv) * (1.f / D_) + 1e-5f);
    for (int k = 0; k < 4; ++k) {
        int d = tid + 256*k;
        float y = (x[k] - mean) * inv * g[d] + bt[d];
        buf[row*D_ + d] = y;
        H16[row*D_ + d] = f2h(y);
    }
}

// ---------------------------------------------------------------------------
// Final: H = LN(gelu(G), eo_ln); plus h_fin copy blocks.
// ---------------------------------------------------------------------------
__global__ __launch_bounds__(256) void k_final(
    const float* __restrict__ G, const float* __restrict__ g, const float* __restrict__ bt,
    float* __restrict__ outH, const float* __restrict__ h, float* __restrict__ outh)
{
    int tid = threadIdx.x;
    if (blockIdx.x < B_*S_) {
        size_t row = blockIdx.x;
        float x[4]; float lsum = 0.f;
        for (int k = 0; k < 4; ++k) {
            x[k] = gelu_f(G[row*D_ + tid + 256*k]);
            lsum += x[k];
        }
        float mean = block_sum(lsum) * (1.f / D_);
        float lv = 0.f;
        for (int k = 0; k < 4; ++k) { float d = x[k] - mean; lv += d * d; }
        float inv = rsqrtf(block_sum(lv) * (1.f / D_) + 1e-5f);
        for (int k = 0; k < 4; ++k) {
            int d = tid + 256*k;
            outH[row*D_ + d] = (x[k] - mean) * inv * g[d] + bt[d];
        }
    } else {
        size_t bn = blockIdx.x - B_*S_;
        for (int d = tid; d < D_; d += 256)
            outh[bn*D_ + d] = h[bn*D_ + d];
    }
}

// ---------------------------------------------------------------------------
extern "C" void kernel_launch(void* const* d_in, const int* in_sizes, int n_in,
                              void* d_out, int out_size, void* d_ws, size_t ws_size,
                              hipStream_t stream)
{
    const float* scene = (const float*)d_in[0];
    const float* inc   = (const float*)d_in[1];
    const int*   etype = (const int*)d_in[3];
    const int*   emask = (const int*)d_in[4];
    const float* nemb  = (const float*)d_in[5];
    const float* temb  = (const float*)d_in[6];
    const float* nameW = (const float*)d_in[7];
    const float* nlg   = (const float*)d_in[8];
    const float* nlb   = (const float*)d_in[9];
    const float* n2eW  = (const float*)d_in[10];
    const float* n2eb  = (const float*)d_in[11];
    const float* t2eW  = (const float*)d_in[12];
    const float* t2eb  = (const float*)d_in[13];
    const float* elng  = (const float*)d_in[14];
    const float* elnb  = (const float*)d_in[15];
    const float* gW1   = (const float*)d_in[16];
    const float* gb1   = (const float*)d_in[17];
    const float* gW2   = (const float*)d_in[18];
    const float* gb2   = (const float*)d_in[19];
    const float* msW   = (const float*)d_in[20];
    const float* msB   = (const float*)d_in[21];
    const float* maW   = (const float*)d_in[22];
    const float* maB   = (const float*)d_in[23];
    const float* miW   = (const float*)d_in[24];
    const float* miB   = (const float*)d_in[25];
    const float* rolew = (const float*)d_in[26];
    const float* Wih   = (const float*)d_in[27];
    const float* Whh   = (const float*)d_in[28];
    const float* bih   = (const float*)d_in[29];
    const float* bhh   = (const float*)d_in[30];
    const float* ulng  = (const float*)d_in[31];
    const float* ulnb  = (const float*)d_in[32];
    const float* eoW   = (const float*)d_in[33];
    const float* eoB   = (const float*)d_in[34];
    const float* eolng = (const float*)d_in[35];
    const float* eolnb = (const float*)d_in[36];
    const float* rlng  = (const float*)d_in[37];
    const float* rlnb  = (const float*)d_in[38];

    float* outH = (float*)d_out;                    // [B,S,D] — doubles as esbuf
    float* outh = outH + (size_t)B_*S_*D_;          // [B,N,D] h_fin

    float* W = (float*)d_ws;
    size_t o = 0;
    int*   ctrl     = (int*)(W + o); o += 64;            // [cnt0, cnt1]
    float* esum2    = W + o; o += 2*(size_t)B_*D_;       // parity sum r*Hcat[:,0:1024]
    float* Tmi2     = W + o; o += 2*(size_t)B_*G3_;      // parity sum r*Hcat[:,1024:4096]
    float* wsum2    = W + o; o += 16;                    // parity per-batch sum r
    float* gatepre  = W + o; o += 32;
    float* rowrole  = W + o; o += 2*BN_;
    float* sclbuf   = W + o; o += BN_;
    int*   list     = (int*)(W + o); o += 2*BN_;
    float* hbuf     = W + o; o += (size_t)BN_*D_;
    float* Hcat     = W + o; o += (size_t)BN_*HC7;
    float* pre_t2e  = W + o; o += (size_t)B_*S_*D_;
    float* gBm      = W + o; o += 4*G3_;
    float* Emi      = W + o; o += (size_t)B_*G3_;
    float* Esmi     = W + o; o += (size_t)B_*S_*G3_;
    float* arcsum   = W + o; o += (size_t)BN_*G3_;
    float* tmp      = W + o; o += (size_t)BN_*D_;        // P (init) and G (final)
    unsigned short* U = (unsigned short*)(W + o);
    size_t uo = 0;
    unsigned short* h16    = U + uo; uo += (size_t)BN_*D_;
    unsigned short* H16    = U + uo; uo += (size_t)B_*S_*D_;
    unsigned short* Wih16  = U + uo; uo += (size_t)G3_*D_;
    unsigned short* Whh16  = U + uo; uo += (size_t)G3_*D_;
    unsigned short* n2e16  = U + uo; uo += (size_t)D_*D_;
    unsigned short* eoW16  = U + uo; uo += (size_t)D_*D_;
    unsigned short* nW16   = U + uo; uo += (size_t)D_*ND_;
    unsigned short* nE16   = U + uo; uo += (size_t)BN_*ND_;
    unsigned short* t2e16  = U + uo; uo += (size_t)D_*D_;
    unsigned short* sc16   = U + uo; uo += (size_t)B_*S_*D_;
    unsigned short* WcatT16= U + uo; uo += (size_t)G3_*D_;
    unsigned short* Wmi16  = U + uo; uo += (size_t)G3_*G3_;
    unsigned short* bias4  = U + uo; uo += 4*D_;

    // zero ctrl + both parities of esum/Tmi/wsum in one shot
    hipMemsetAsync(ctrl, 0,
        (64 + 2*(size_t)B_*D_ + 2*(size_t)B_*G3_ + 16) * sizeof(float), stream);

    // ---- conversions (per call; inputs restored each timed call) ----
    #define CVT(src, dst, r, c, ld) \
        k_f2h<<<(((size_t)(r)*(c)/4 + 255)/256), 256, 0, stream>>>(src, dst, r, c, ld)
    CVT(Wih,   Wih16, G3_, D_,  D_);
    CVT(Whh,   Whh16, G3_, D_,  D_);
    CVT(n2eW,  n2e16, D_,  D_,  D_);
    CVT(nameW, nW16,  D_,  ND_, ND_);
    CVT(nemb,  nE16,  BN_, ND_, ND_);
    CVT(eoW,   eoW16, D_,  D_,  D_);
    CVT(t2eW,  t2e16, D_,  D_,  D_);
    CVT(scene, sc16,  B_*S_, D_, D_);
    CVT(msB,   bias4 + 0,    1, D_, D_);
    CVT(maB,   bias4 + D_,   1, D_, D_);
    CVT(miB,   bias4 + 2*D_, 1, D_, D_);
    CVT(rolew, bias4 + 3*D_, 1, D_, D_);
    #undef CVT
    // WcatT16[seg*1024 + k][d] = {ms,ma,mi}W[d][k]  (transposed, fp16)
    k_f2hT<<<dim3(32,32), 256, 0, stream>>>(msW, WcatT16, D_, D_, D_, 0);
    k_f2hT<<<dim3(32,32), 256, 0, stream>>>(maW, WcatT16, D_, D_, D_, D_);
    k_f2hT<<<dim3(32,32), 256, 0, stream>>>(miW, WcatT16, D_, D_, D_, 2*D_);

    // Wmi16 = 256 * (Wih @ Wcat)  [3072,3072] fp16 (cols: es|arc|int segs)
    k_mfma16_nt<<<dim3(G3_/128, G3_/64), 256, 0, stream>>>(
        Wih16, WcatT16, nullptr, nullptr, Wmi16, 256.f, G3_, G3_, D_);
    // gBm[4,3072] = [msB|maB|miB|rolew] @ Wih^T
    k_mfma16_nt<<<dim3(G3_/128, 1), 256, 0, stream>>>(
        bias4, Wih16, nullptr, gBm, nullptr, 1.f, 4, G3_, D_);
    // pre_t2e[b,s,:] = t2e(scene) + t2eb
    k_mfma16_nt<<<dim3(D_/128, (B_*S_+63)/64), 256, 0, stream>>>(
        sc16, t2e16, t2eb, pre_t2e, nullptr, 1.f, B_*S_, D_, D_);
    // init: P = name_embs @ name_W^T ; h0 ; Hcat0
    k_mfma16_nt<<<dim3(D_/128, (BN_+63)/64), 256, 0, stream>>>(
        nE16, nW16, nullptr, tmp, nullptr, 1.f, BN_, D_, ND_);
    k_h0<<<BN_, 256, 0, stream>>>(tmp, etype, emask, temb, nlg, nlb, hbuf, h16);
    k_hcat0<<<dim3(112, 25), 256, 0, stream>>>(h16, n2e16, Wmi16, Whh16, Hcat);

    for (int s = 0; s < S_; ++s) {
        int par = s & 1;
        int*   cntp = ctrl + par;
        int*   pcnt = ctrl + (1 - par);
        int*   lst  = list + par * BN_;
        int*   plst = list + (1 - par) * BN_;
        float* rro  = rowrole + par * BN_;
        float* esumP = esum2 + (size_t)par * B_*D_;
        float* esumZ = esum2 + (size_t)(1 - par) * B_*D_;
        float* TmiP  = Tmi2 + (size_t)par * B_*G3_;
        float* TmiZ  = Tmi2 + (size_t)(1 - par) * B_*G3_;
        float* wsumP = wsum2 + par * 8;
        float* wsumZ = wsum2 + (1 - par) * 8;
        k_front<<<BN_ + GMT, 256, 0, stream>>>(inc, emask, Esmi, arcsum,
            cntp, lst, rro, sclbuf, pcnt, plst, h16, n2e16, Wmi16, Whh16,
            Hcat, gatepre, esumP, TmiP, wsumP, s);
        k_mid<<<128, 256, 0, stream>>>(esumP, wsumP, esumZ, TmiZ, wsumZ,
            n2eb, pre_t2e, elng, elnb, gW1, gb1, gW2, Wmi16,
            outH, gatepre, Emi, Esmi, ctrl, par, s);
        k_fin<<<BN_, 256, 0, stream>>>(lst, cntp, rro, sclbuf, gatepre, gb2,
            Hcat, Emi, arcsum, TmiP, gBm, bih, bhh, ulng, ulnb, hbuf, h16, s);
    }

    // epilogue: H = LN(gelu(LN(es + scene) @ eo_W^T + eo_b)); h_fin copy
    k_resln<<<B_*S_, 256, 0, stream>>>(outH, scene, rlng, rlnb, H16);
    k_mfma16_nt<<<dim3(D_/128, (B_*S_+63)/64), 256, 0, stream>>>(
        H16, eoW16, eoB, tmp, nullptr, 1.f, B_*S_, D_, D_);
    k_final<<<B_*S_ + BN_, 256, 0, stream>>>(tmp, eolng, eolnb, outH, hbuf, outh);
}

// Round 6
// 4078.760 us; speedup vs baseline: 3.4651x; 1.8559x over previous
//
#include <hip/hip_runtime.h>
#include <math.h>

#define B_   8
#define S_   64
#define N_   100
#define D_   1024
#define ND_  768
#define BN_  800
#define G3_  3072
#define HC7  7168
#define RSC  0.00390625f   // 1/256 — Wmi stored x256 to avoid fp16 subnormals

typedef _Float16 f16x8 __attribute__((ext_vector_type(8)));
typedef float f32x4 __attribute__((ext_vector_type(4)));

#define MFMA16(a,b,c) __builtin_amdgcn_mfma_f32_16x16x32_f16(a, b, c, 0, 0, 0)

static __device__ __forceinline__ float wave_sum(float v) {
    for (int off = 32; off > 0; off >>= 1) v += __shfl_down(v, off, 64);
    return v;
}

static __device__ __forceinline__ float wave_allsum(float v) {
    for (int off = 1; off < 64; off <<= 1) v += __shfl_xor(v, off, 64);
    return v;
}

// All 256 threads must call; returns full-block sum to every thread.
static __device__ __forceinline__ float block_sum(float v) {
    __shared__ float red_[8];
    float w = wave_sum(v);
    int lane = threadIdx.x & 63, wid = threadIdx.x >> 6;
    __syncthreads();               // protect red_ reuse across calls
    if (lane == 0) red_[wid] = w;
    __syncthreads();
    float t = 0.f;
    for (int i = 0; i < 4; ++i) t += red_[i];
    return t;
}

static __device__ __forceinline__ float gelu_f(float x) {
    return 0.5f * x * (1.f + erff(x * 0.70710678118654752f));
}

static __device__ __forceinline__ unsigned short f2h(float x) {
    union { _Float16 h; unsigned short u; } c; c.h = (_Float16)x; return c.u;
}

// ---------------------------------------------------------------------------
// fp32 -> fp16 2D convert. cols % 4 == 0.
// ---------------------------------------------------------------------------
__global__ __launch_bounds__(256) void k_f2h(
    const float* __restrict__ src, unsigned short* __restrict__ dst,
    int rows, int cols, int ldd)
{
    size_t n = (size_t)rows * cols;
    size_t i = ((size_t)blockIdx.x * 256 + threadIdx.x) * 4;
    if (i >= n) return;
    int r = (int)(i / cols);
    int c = (int)(i - (size_t)r * cols);
    float4 v = *(const float4*)(src + i);
    ushort4 o; o.x = f2h(v.x); o.y = f2h(v.y); o.z = f2h(v.z); o.w = f2h(v.w);
    *(ushort4*)(dst + (size_t)r * ldd + c) = o;
}

// ---------------------------------------------------------------------------
// fp32 -> fp16 TRANSPOSING convert: dst[rowoff + c][r] = src[r][c].
// ---------------------------------------------------------------------------
__global__ __launch_bounds__(256) void k_f2hT(
    const float* __restrict__ src, unsigned short* __restrict__ dst,
    int R, int C, int ldd, int rowoff)
{
    __shared__ _Float16 T[32][33];
    int tr = threadIdx.x >> 3, tc4 = (threadIdx.x & 7) * 4;
    int r0 = blockIdx.y * 32, c0 = blockIdx.x * 32;
    float4 v = *(const float4*)(src + (size_t)(r0 + tr) * C + c0 + tc4);
    T[tc4][tr] = (_Float16)v.x; T[tc4+1][tr] = (_Float16)v.y;
    T[tc4+2][tr] = (_Float16)v.z; T[tc4+3][tr] = (_Float16)v.w;
    __syncthreads();
    union { _Float16 h; unsigned short u; } cv;
    ushort4 o;
    cv.h = T[tr][tc4];   o.x = cv.u;
    cv.h = T[tr][tc4+1]; o.y = cv.u;
    cv.h = T[tr][tc4+2]; o.z = cv.u;
    cv.h = T[tr][tc4+3]; o.w = cv.u;
    *(ushort4*)(dst + (size_t)(rowoff + c0 + tr) * ldd + r0 + tc4) = o;
}

// ---------------------------------------------------------------------------
// FP16 MFMA GEMM (setup/epilogue only): C[M,Nc] = A16[M,K] @ W16[Nc,K]^T.
// TM=64, TN=128. If C16 != null: writes f2h(acc*oscale). Else fp32 + bias.
// ---------------------------------------------------------------------------
__global__ __launch_bounds__(256) void k_mfma16_nt(
    const unsigned short* __restrict__ A16, const unsigned short* __restrict__ W16,
    const float* __restrict__ bias, float* __restrict__ C,
    unsigned short* __restrict__ C16, float oscale,
    int M, int Nc, int K)
{
    int m0 = blockIdx.y * 64; if (m0 >= M) return;
    int n0 = blockIdx.x * 128;
    __shared__ _Float16 sA[64][72];
    __shared__ _Float16 sB[128][72];
    int tid = threadIdx.x;
    int w = tid >> 6, l = tid & 63;
    int l15 = l & 15, q = l >> 4;
    int wn = w * 32;
    int arow = tid >> 3, achk = (tid & 7) * 8;
    f32x4 acc[4][2] = {};
    for (int k0 = 0; k0 < K; k0 += 64) {
        for (int ri = 0; ri < 64; ri += 32) {
            int gm = m0 + arow + ri;
            uint4 v = make_uint4(0u, 0u, 0u, 0u);
            if (gm < M) v = *(const uint4*)(A16 + (size_t)gm * K + k0 + achk);
            *(uint4*)(&sA[arow + ri][achk]) = v;
        }
        for (int i = 0; i < 4; ++i) {
            int r = arow + 32 * i;
            *(uint4*)(&sB[r][achk]) = *(const uint4*)(W16 + (size_t)(n0 + r) * K + k0 + achk);
        }
        __syncthreads();
#pragma unroll
        for (int ks = 0; ks < 64; ks += 32) {
            f16x8 b0 = *(const f16x8*)(&sB[wn + l15][ks + q*8]);
            f16x8 b1 = *(const f16x8*)(&sB[wn + 16 + l15][ks + q*8]);
#pragma unroll
            for (int mi = 0; mi < 4; ++mi) {
                f16x8 a = *(const f16x8*)(&sA[mi*16 + l15][ks + q*8]);
                acc[mi][0] = MFMA16(a, b0, acc[mi][0]);
                acc[mi][1] = MFMA16(a, b1, acc[mi][1]);
            }
        }
        __syncthreads();
    }
    for (int mi = 0; mi < 4; ++mi)
        for (int nj = 0; nj < 2; ++nj)
            for (int r = 0; r < 4; ++r) {
                int gm = m0 + mi*16 + q*4 + r;
                int cl = wn + nj*16 + l15;
                if (gm < M) {
                    size_t off = (size_t)gm * Nc + n0 + cl;
                    float v = acc[mi][nj][r];
                    if (C16) C16[off] = f2h(v * oscale);
                    else C[off] = v + (bias ? bias[n0 + cl] : 0.f);
                }
            }
}

// ---------------------------------------------------------------------------
// h0 = mask * (type_embed[type] + LN(P, name_ln)); fp32 h + fp16 mirror
// ---------------------------------------------------------------------------
__global__ __launch_bounds__(256) void k_h0(
    const float* __restrict__ P, const int* __restrict__ etype,
    const int* __restrict__ emask, const float* __restrict__ temb,
    const float* __restrict__ g, const float* __restrict__ bt,
    float* __restrict__ h, unsigned short* __restrict__ h16)
{
    int bn = blockIdx.x, tid = threadIdx.x;
    int t = etype[bn], mk = emask[bn];
    float x[4]; float lsum = 0.f;
    for (int k = 0; k < 4; ++k) { x[k] = P[(size_t)bn*D_ + tid + 256*k]; lsum += x[k]; }
    float mean = block_sum(lsum) * (1.f / D_);
    float lv = 0.f;
    for (int k = 0; k < 4; ++k) { float d = x[k] - mean; lv += d * d; }
    float inv = rsqrtf(block_sum(lv) * (1.f / D_) + 1e-5f);
    for (int k = 0; k < 4; ++k) {
        int d = tid + 256*k;
        float y = (x[k] - mean) * inv * g[d] + bt[d];
        float hv = mk ? (temb[(size_t)t*D_ + d] + y) : 0.f;
        h[(size_t)bn*D_ + d] = hv;
        h16[(size_t)bn*D_ + d] = f2h(hv);
    }
}

// ---------------------------------------------------------------------------
// Hcat init: Hcat[bn, 0:1024|1024:4096|4096:7168] = h16[bn] @ [n2e|Wmi2|Whh]^T
// Grid (112, 25). TM=32, TN=64.
// ---------------------------------------------------------------------------
__global__ __launch_bounds__(256) void k_hcat0(
    const unsigned short* __restrict__ h16, const unsigned short* __restrict__ n2e16,
    const unsigned short* __restrict__ Wmi16, const unsigned short* __restrict__ Whh16,
    float* __restrict__ Hcat)
{
    int m0 = blockIdx.y * 32;
    int n0 = blockIdx.x * 64;
    const unsigned short* Bp; int ldb; int nl;
    if (n0 < 1024)      { Bp = n2e16;        ldb = D_;  nl = n0; }
    else if (n0 < 4096) { Bp = Wmi16 + 2048; ldb = G3_; nl = n0 - 1024; }
    else                { Bp = Whh16;        ldb = D_;  nl = n0 - 4096; }
    __shared__ _Float16 sA[32][72];
    __shared__ _Float16 sB[64][72];
    int tid = threadIdx.x;
    int w = tid >> 6, l = tid & 63;
    int l15 = l & 15, q = l >> 4;
    int wm = (w & 1) * 16, wn = (w >> 1) * 32;
    int arow = tid >> 3, achk = (tid & 7) * 8;
    int gmA = m0 + arow;
    f32x4 acc[2] = {};
    for (int k0 = 0; k0 < D_; k0 += 64) {
        *(uint4*)(&sA[arow][achk]) = *(const uint4*)(h16 + (size_t)gmA*D_ + k0 + achk);
        *(uint4*)(&sB[arow][achk])      = *(const uint4*)(Bp + (size_t)(nl + arow)*ldb + k0 + achk);
        *(uint4*)(&sB[arow + 32][achk]) = *(const uint4*)(Bp + (size_t)(nl + arow + 32)*ldb + k0 + achk);
        __syncthreads();
#pragma unroll
        for (int ks = 0; ks < 64; ks += 32) {
            f16x8 a  = *(const f16x8*)(&sA[wm + l15][ks + q*8]);
            f16x8 b0 = *(const f16x8*)(&sB[wn + l15][ks + q*8]);
            f16x8 b1 = *(const f16x8*)(&sB[wn + 16 + l15][ks + q*8]);
            acc[0] = MFMA16(a, b0, acc[0]);
            acc[1] = MFMA16(a, b1, acc[1]);
        }
        __syncthreads();
    }
    for (int j = 0; j < 2; ++j)
        for (int r = 0; r < 4; ++r) {
            int row = wm + q*4 + r;
            Hcat[(size_t)(m0 + row)*HC7 + n0 + wn + j*16 + l15] = acc[j][r];
        }
}

// ---------------------------------------------------------------------------
// K_front: blocks [0,800): compaction + arcsum (float4) + per-row scalars +
//          stale esum/Tmi contributions for rows whose Hcat is current.
//          blocks [800, 800+112*13): Hcat update GEMM TM=64/TN=64 for PREV
//          rows; GEMM blocks contribute fresh esum/Tmi for rows also active
//          at s (atomics; partition by prev-active keeps it race-free).
// Block 0 zeroes gatepre.
// ---------------------------------------------------------------------------
__global__ __launch_bounds__(256) void k_front(
    const float* __restrict__ inc, const int* __restrict__ emask,
    const float* __restrict__ Esmi, float* __restrict__ arcsum,
    int* __restrict__ cntp, int* __restrict__ lst, float* __restrict__ rro,
    float* __restrict__ scl,
    const int* __restrict__ prevcnt, const int* __restrict__ prevlist,
    const unsigned short* __restrict__ h16, const unsigned short* __restrict__ n2e16,
    const unsigned short* __restrict__ Wmi16, const unsigned short* __restrict__ Whh16,
    float* __restrict__ Hcat, float* __restrict__ gatepre,
    float* __restrict__ esumP, float* __restrict__ TmiP, float* __restrict__ wsumP,
    int s)
{
    int tid = threadIdx.x, bid = blockIdx.x;
    if (bid == 0 && tid < 32) gatepre[tid] = 0.f;
    if (bid < BN_) {
        int m = bid;
        int b = m / N_;
        float r = emask[m] ? inc[(size_t)m*S_ + s] : 0.f;
        if (r <= 0.f) return;
        __shared__ int sidx, nwa;
        __shared__ float wav[S_]; __shared__ int wai[S_];
        if (tid == 0) { sidx = atomicAdd(cntp, 1); nwa = 0; }
        __syncthreads();
        int idx = sidx;
        float denomA = fmaxf((float)(s - 1), 1.f);
        float wa = 0.f;
        if (tid < s) {
            float iv = inc[(size_t)m*S_ + tid];
            if (iv > 0.f) {
                wa = iv * r * expf(-1.f + (float)tid / denomA);
                int p = atomicAdd(&nwa, 1);
                wav[p] = wa; wai[p] = tid;
            }
        }
        float dA = block_sum(wa);
        float rm = 0.f;
        if (tid < N_) rm = emask[b*N_ + tid] ? inc[((size_t)b*N_ + tid)*S_ + s] : 0.f;
        float wsum = block_sum(rm);
        __syncthreads();
        int na = nwa;
        float sclA = 1.f / fmaxf(dA, 1e-8f);
        if (tid == 0) {
            lst[idx] = m; rro[idx] = r;
            scl[idx] = r / fmaxf(r * (wsum - r), 1e-8f);
            wsumP[b] = wsum;
        }
        // esum/Tmi: rows NOT updated at s-1 have current Hcat -> accumulate here.
        float rprev = (s > 0) ? inc[(size_t)m*S_ + (s-1)] : 0.f;
        if (rprev <= 0.f) {
            const float4* hp = (const float4*)(Hcat + (size_t)m*HC7);
#pragma unroll
            for (int j2 = 0; j2 < 4; ++j2) {
                float4 hv = hp[tid + 256*j2];
                int c = (tid + 256*j2) * 4;
                float* dst = (c < 1024) ? (esumP + (size_t)b*D_ + c)
                                        : (TmiP + (size_t)b*G3_ + (c - 1024));
                atomicAdd(dst + 0, r*hv.x); atomicAdd(dst + 1, r*hv.y);
                atomicAdd(dst + 2, r*hv.z); atomicAdd(dst + 3, r*hv.w);
            }
        }
        // arcsum [3072]: 3 x float4 per thread (numerics identical to scalar)
        f32x4 a4[3];
#pragma unroll
        for (int k = 0; k < 3; ++k) a4[k] = (f32x4){0.f,0.f,0.f,0.f};
        for (int j = 0; j < na; ++j) {
            float wj = wav[j];
            const f32x4* ep = (const f32x4*)(Esmi + ((size_t)b*S_ + wai[j])*G3_);
#pragma unroll
            for (int k = 0; k < 3; ++k) {
                f32x4 e = ep[tid + 256*k];
#pragma unroll
                for (int q = 0; q < 4; ++q) a4[k][q] += wj * e[q];
            }
        }
        f32x4* ao = (f32x4*)(arcsum + (size_t)idx*G3_);
#pragma unroll
        for (int k = 0; k < 3; ++k) {
            f32x4 v;
#pragma unroll
            for (int q = 0; q < 4; ++q) v[q] = a4[k][q] * sclA;
            ao[tid + 256*k] = v;
        }
    } else {
        int pM = *prevcnt;
        int t = bid - BN_;
        int nt = t % 112, mt = t / 112;
        int m0 = mt * 64;
        if (m0 >= pM) return;
        int n0 = nt * 64;
        const unsigned short* Bp; int ldb; int nl;
        if (n0 < 1024)      { Bp = n2e16;        ldb = D_;  nl = n0; }
        else if (n0 < 4096) { Bp = Wmi16 + 2048; ldb = G3_; nl = n0 - 1024; }
        else                { Bp = Whh16;        ldb = D_;  nl = n0 - 4096; }
        __shared__ _Float16 sA[64][72];
        __shared__ _Float16 sB[64][72];
        __shared__ int slist[64];
        __shared__ float srn[64];
        __shared__ int sbb[64];
        if (tid < 64) {
            int gm = m0 + tid;
            int m = (gm < pM) ? prevlist[gm] : 0;
            slist[tid] = m;
            float rn = 0.f;
            if (gm < pM) rn = emask[m] ? inc[(size_t)m*S_ + s] : 0.f;
            srn[tid] = rn;
            sbb[tid] = m / N_;
        }
        __syncthreads();
        int w = tid >> 6, l = tid & 63;
        int l15 = l & 15, q = l >> 4;
        int wm = (w & 1) * 32, wn = (w >> 1) * 32;
        int arow = tid >> 3, achk = (tid & 7) * 8;
        f32x4 acc[2][2] = {};
        for (int k0 = 0; k0 < D_; k0 += 64) {
            for (int ri = 0; ri < 64; ri += 32) {
                int row = arow + ri, gm = m0 + row;
                uint4 v = make_uint4(0u,0u,0u,0u);
                if (gm < pM) v = *(const uint4*)(h16 + (size_t)slist[row]*D_ + k0 + achk);
                *(uint4*)(&sA[row][achk]) = v;
            }
            *(uint4*)(&sB[arow][achk])      = *(const uint4*)(Bp + (size_t)(nl + arow)*ldb + k0 + achk);
            *(uint4*)(&sB[arow + 32][achk]) = *(const uint4*)(Bp + (size_t)(nl + arow + 32)*ldb + k0 + achk);
            __syncthreads();
#pragma unroll
            for (int ks = 0; ks < 64; ks += 32) {
                f16x8 a0 = *(const f16x8*)(&sA[wm + l15][ks + q*8]);
                f16x8 a1 = *(const f16x8*)(&sA[wm + 16 + l15][ks + q*8]);
                f16x8 b0 = *(const f16x8*)(&sB[wn + l15][ks + q*8]);
                f16x8 b1 = *(const f16x8*)(&sB[wn + 16 + l15][ks + q*8]);
                acc[0][0] = MFMA16(a0, b0, acc[0][0]);
                acc[0][1] = MFMA16(a0, b1, acc[0][1]);
                acc[1][0] = MFMA16(a1, b0, acc[1][0]);
                acc[1][1] = MFMA16(a1, b1, acc[1][1]);
            }
            __syncthreads();
        }
        for (int mi = 0; mi < 2; ++mi)
            for (int nj = 0; nj < 2; ++nj)
                for (int r = 0; r < 4; ++r) {
                    int row = wm + mi*16 + q*4 + r;
                    int gm = m0 + row;
                    if (gm < pM) {
                        float v = acc[mi][nj][r];
                        int c = n0 + wn + nj*16 + l15;
                        Hcat[(size_t)slist[row]*HC7 + c] = v;
                        float rn = srn[row];
                        if (rn > 0.f && c < 4096) {
                            float* dst = (c < 1024)
                                ? (esumP + (size_t)sbb[row]*D_ + c)
                                : (TmiP + (size_t)sbb[row]*G3_ + (c - 1024));
                            atomicAdd(dst, rn * v);
                        }
                    }
                }
    }
}

// ---------------------------------------------------------------------------
// K_mid (grid 128): [0,32) light e_s + gate MLP; [32,128) Emi/Esmi GEMV,
// all 8 batches sharing one Wmi16 read. Block 0 resets next step's counter.
// ---------------------------------------------------------------------------
__global__ __launch_bounds__(256) void k_mid(
    const float* __restrict__ esumP, const float* __restrict__ wsumP,
    float* __restrict__ esumZ, float* __restrict__ TmiZ, float* __restrict__ wsumZ,
    const float* __restrict__ n2eb, const float* __restrict__ pre_t2e,
    const float* __restrict__ elng, const float* __restrict__ elnb,
    const float* __restrict__ gW1, const float* __restrict__ gb1,
    const float* __restrict__ gW2, const unsigned short* __restrict__ Wmi16,
    float* __restrict__ esbuf, float* __restrict__ gatepre,
    float* __restrict__ Emi, float* __restrict__ Esmi,
    int* __restrict__ ctrl, int par, int s)
{
    int bid = blockIdx.x, tid = threadIdx.x;
    if (bid < 32) {
        __shared__ float se[D_];
        int b = bid >> 2, seg = bid & 3;
        if (bid == 0 && tid == 0) ctrl[1 - par] = 0;
        esumZ[(size_t)b*D_ + seg*256 + tid] = 0.f;
#pragma unroll
        for (int j = 0; j < 3; ++j) TmiZ[(size_t)b*G3_ + seg*768 + j*256 + tid] = 0.f;
        if (seg == 0 && tid == 0) wsumZ[b] = 0.f;
        float invw = 1.f / fmaxf(wsumP[b], 1.f);
        float4 ev = ((const float4*)(esumP + (size_t)b*D_))[tid];
        float4 nb = ((const float4*)n2eb)[tid];
        float4 pt = ((const float4*)(pre_t2e + ((size_t)b*S_ + s)*D_))[tid];
        float x[4] = { ev.x*invw + nb.x + pt.x, ev.y*invw + nb.y + pt.y,
                       ev.z*invw + nb.z + pt.z, ev.w*invw + nb.w + pt.w };
        float mean = block_sum(x[0]+x[1]+x[2]+x[3]) * (1.f / D_);
        float lv = 0.f;
#pragma unroll
        for (int k = 0; k < 4; ++k) { float d = x[k] - mean; lv += d * d; }
        float inv = rsqrtf(block_sum(lv) * (1.f / D_) + 1e-5f);
        float4 lg = ((const float4*)elng)[tid];
        float4 lb = ((const float4*)elnb)[tid];
        float y0 = (x[0]-mean)*inv*lg.x + lb.x;
        float y1 = (x[1]-mean)*inv*lg.y + lb.y;
        float y2 = (x[2]-mean)*inv*lg.z + lb.z;
        float y3 = (x[3]-mean)*inv*lg.w + lb.w;
        int d4 = tid * 4;
        se[d4] = y0; se[d4+1] = y1; se[d4+2] = y2; se[d4+3] = y3;
        if (seg == 0)
            ((float4*)(esbuf + ((size_t)b*S_ + s)*D_))[tid] = make_float4(y0,y1,y2,y3);
        __syncthreads();
        if (tid < 64) {
            int u = seg * 64 + tid;
            float acc = gb1[u];
            const float* w1 = gW1 + (size_t)u * D_;
            for (int j = 0; j < D_; j += 4) {
                float4 w = *(const float4*)(w1 + j);
                acc += w.x*se[j] + w.y*se[j+1] + w.z*se[j+2] + w.w*se[j+3];
            }
            float hg = gelu_f(acc);
            for (int c = 0; c < 3; ++c) {
                float p = wave_sum(gW2[c*256 + u] * hg);
                if (tid == 0) atomicAdd(gatepre + b*4 + c, p);
            }
        }
    } else {
        __shared__ float se32[8][1028];
        int w = tid >> 6, lane = tid & 63;
        for (int bb = 0; bb < 2; ++bb) {
            int b = w*2 + bb;
            float invw = 1.f / fmaxf(wsumP[b], 1.f);
            int d0 = lane * 16;
            const float4* ep = (const float4*)(esumP + (size_t)b*D_ + d0);
            const float4* np = (const float4*)(n2eb + d0);
            const float4* pp = (const float4*)(pre_t2e + ((size_t)b*S_ + s)*D_ + d0);
            float x[16]; float sm = 0.f;
#pragma unroll
            for (int j = 0; j < 4; ++j) {
                float4 e = ep[j], n = np[j], p = pp[j];
                x[j*4+0] = e.x*invw + n.x + p.x;
                x[j*4+1] = e.y*invw + n.y + p.y;
                x[j*4+2] = e.z*invw + n.z + p.z;
                x[j*4+3] = e.w*invw + n.w + p.w;
                sm += x[j*4+0] + x[j*4+1] + x[j*4+2] + x[j*4+3];
            }
            float mean = wave_allsum(sm) * (1.f / D_);
            float lv = 0.f;
#pragma unroll
            for (int j = 0; j < 16; ++j) { float d = x[j] - mean; lv += d * d; }
            float inv = rsqrtf(wave_allsum(lv) * (1.f / D_) + 1e-5f);
            const float4* lgp = (const float4*)(elng + d0);
            const float4* lbp = (const float4*)(elnb + d0);
#pragma unroll
            for (int j = 0; j < 4; ++j) {
                float4 lg = lgp[j], lb = lbp[j];
                se32[b][d0 + j*4 + 0] = (x[j*4+0]-mean)*inv*lg.x + lb.x;
                se32[b][d0 + j*4 + 1] = (x[j*4+1]-mean)*inv*lg.y + lb.y;
                se32[b][d0 + j*4 + 2] = (x[j*4+2]-mean)*inv*lg.z + lb.z;
                se32[b][d0 + j*4 + 3] = (x[j*4+3]-mean)*inv*lg.w + lb.w;
            }
        }
        __syncthreads();
        int c0 = (bid - 32) * 32;
        int colg = tid >> 5, t31 = tid & 31;
        int cb = c0 + colg * 4;
        float accA[4][8] = {};
        float accB[4][8] = {};
#pragma unroll
        for (int i = 0; i < 8; ++i) {
            int kh = t31*4 + i*128;
            float wf[4][4];
#pragma unroll
            for (int c = 0; c < 4; ++c) {
                union { uint2 u; _Float16 h[4]; } cv;
                cv.u = *(const uint2*)(Wmi16 + (size_t)(cb + c)*G3_ + kh);
                wf[c][0] = (float)cv.h[0]; wf[c][1] = (float)cv.h[1];
                wf[c][2] = (float)cv.h[2]; wf[c][3] = (float)cv.h[3];
            }
#pragma unroll
            for (int b = 0; b < 8; ++b) {
                float4 sv = *(const float4*)(&se32[b][kh]);
#pragma unroll
                for (int c = 0; c < 4; ++c)
                    accA[c][b] += wf[c][0]*sv.x + wf[c][1]*sv.y
                                + wf[c][2]*sv.z + wf[c][3]*sv.w;
            }
        }
#pragma unroll
        for (int i = 0; i < 8; ++i) {
            int kh = t31*4 + i*128;
            float wf[4][4];
#pragma unroll
            for (int c = 0; c < 4; ++c) {
                union { uint2 u; _Float16 h[4]; } cv;
                cv.u = *(const uint2*)(Wmi16 + (size_t)(cb + c)*G3_ + 1024 + kh);
                wf[c][0] = (float)cv.h[0]; wf[c][1] = (float)cv.h[1];
                wf[c][2] = (float)cv.h[2]; wf[c][3] = (float)cv.h[3];
            }
#pragma unroll
            for (int b = 0; b < 8; ++b) {
                float4 sv = *(const float4*)(&se32[b][kh]);
#pragma unroll
                for (int c = 0; c < 4; ++c)
                    accB[c][b] += wf[c][0]*sv.x + wf[c][1]*sv.y
                                + wf[c][2]*sv.z + wf[c][3]*sv.w;
            }
        }
#pragma unroll
        for (int off = 16; off >= 1; off >>= 1) {
#pragma unroll
            for (int c = 0; c < 4; ++c)
#pragma unroll
                for (int b = 0; b < 8; ++b) {
                    accA[c][b] += __shfl_down(accA[c][b], off, 32);
                    accB[c][b] += __shfl_down(accB[c][b], off, 32);
                }
        }
        if (t31 == 0) {
#pragma unroll
            for (int c = 0; c < 4; ++c) {
                int col = cb + c;
#pragma unroll
                for (int b = 0; b < 8; ++b) {
                    Emi[(size_t)b*G3_ + col] = accA[c][b];
                    Esmi[((size_t)b*S_ + s)*G3_ + col] = accB[c][b];
                }
            }
        }
    }
}

// ---------------------------------------------------------------------------
// K_fin: GRU assembly + LN + clip + h update. Single-pass float4 loads
// (latency-bound kernel: ~180 blocks over 256 CUs; fewer, wider loads).
// ---------------------------------------------------------------------------
__global__ __launch_bounds__(256) void k_fin(
    const int* __restrict__ lst, const int* __restrict__ cntp,
    const float* __restrict__ rro, const float* __restrict__ scl,
    const float* __restrict__ gatepre, const float* __restrict__ gb2,
    const float* __restrict__ Hcat, const float* __restrict__ Emi,
    const float* __restrict__ arcsum, const float* __restrict__ Tmi,
    const float* __restrict__ gBm, const float* __restrict__ bih,
    const float* __restrict__ bhh,
    const float* __restrict__ ulng, const float* __restrict__ ulnb,
    float* __restrict__ h, unsigned short* __restrict__ h16, int s)
{
    int row = blockIdx.x;
    if (row >= *cntp) return;
    int bn = lst[row];
    int b = bn / N_;
    int tid = threadIdx.x;
    float t0 = gatepre[b*4+0] + gb2[0];
    float t1 = gatepre[b*4+1] + gb2[1];
    float t2 = gatepre[b*4+2] + gb2[2];
    float mx = fmaxf(t0, fmaxf(t1, t2));
    float e0 = expf(t0-mx), e1 = expf(t1-mx), e2 = expf(t2-mx);
    float si = 1.f / (e0 + e1 + e2);
    float g0 = e0*si, g1 = (s > 0) ? e1*si : 0.f, g2 = e2*si;
    float rv = rro[row];
    float sI = scl[row];
    const f32x4* Hmi4 = (const f32x4*)(Hcat + (size_t)bn*HC7 + 1024);
    const f32x4* Hhh4 = (const f32x4*)(Hcat + (size_t)bn*HC7 + 4096);
    const f32x4* em4  = (const f32x4*)(Emi + (size_t)b*G3_);
    const f32x4* as4  = (const f32x4*)(arcsum + (size_t)row*G3_);
    const f32x4* tm4  = (const f32x4*)(Tmi + (size_t)b*G3_);
    const f32x4* gB4  = (const f32x4*)gBm;
    const f32x4* bih4 = (const f32x4*)bih;
    const f32x4* bhh4 = (const f32x4*)bhh;
    const f32x4* h4   = (const f32x4*)(h + (size_t)bn*D_);
    f32x4 ip[3];
#pragma unroll
    for (int c = 0; c < 3; ++c) {
        int dd4 = c*256 + tid;
        f32x4 tm_ = tm4[dd4], hm_ = Hmi4[dd4], em_ = em4[dd4], as_ = as4[dd4];
        f32x4 b0 = gB4[dd4], b1 = gB4[768 + dd4];
        f32x4 b2 = gB4[1536 + dd4], b3 = gB4[2304 + dd4];
        f32x4 bi = bih4[dd4];
#pragma unroll
        for (int j = 0; j < 4; ++j) {
            float gint = tm_[j] - rv * hm_[j];
            ip[c][j] = RSC * (g0*em_[j] + g1*as_[j] + g2*sI*gint)
                     + g0*b0[j] + g1*b1[j] + g2*b2[j] + rv*b3[j] + bi[j];
        }
    }
    f32x4 a0 = Hhh4[tid],       c0 = bhh4[tid];
    f32x4 a1 = Hhh4[256 + tid], c1 = bhh4[256 + tid];
    f32x4 a2 = Hhh4[512 + tid], c2 = bhh4[512 + tid];
    f32x4 hvv = h4[tid];
    f32x4 u4; float lsum = 0.f;
#pragma unroll
    for (int j = 0; j < 4; ++j) {
        float r = 1.f / (1.f + expf(-(ip[0][j] + a0[j] + c0[j])));
        float z = 1.f / (1.f + expf(-(ip[1][j] + a1[j] + c1[j])));
        float nn = tanhf(ip[2][j] + r * (a2[j] + c2[j]));
        u4[j] = (1.f - z) * nn + z * hvv[j];
        lsum += u4[j];
    }
    float mean = block_sum(lsum) * (1.f / D_);
    float lv = 0.f;
#pragma unroll
    for (int j = 0; j < 4; ++j) { float d = u4[j] - mean; lv += d * d; }
    float inv = rsqrtf(block_sum(lv) * (1.f / D_) + 1e-5f);
    f32x4 lg = ((const f32x4*)ulng)[tid];
    f32x4 lb = ((const f32x4*)ulnb)[tid];
    f32x4 y4; ushort4 o;
#pragma unroll
    for (int j = 0; j < 4; ++j) {
        float y = (u4[j] - mean) * inv * lg[j] + lb[j];
        y4[j] = fminf(fmaxf(y, -50.f), 50.f);
    }
    *(f32x4*)(h + (size_t)bn*D_ + tid*4) = y4;
    o.x = f2h(y4[0]); o.y = f2h(y4[1]); o.z = f2h(y4[2]); o.w = f2h(y4[3]);
    *(ushort4*)(h16 + (size_t)bn*D_ + tid*4) = o;
}

// ---------------------------------------------------------------------------
// Final: buf = LN(buf + scene, res_ln) in-place; also fp16 copy.
// ---------------------------------------------------------------------------
__global__ __launch_bounds__(256) void k_resln(
    float* __restrict__ buf, const float* __restrict__ scene,
    const float* __restrict__ g, const float* __restrict__ bt,
    unsigned short* __restrict__ H16)
{
    size_t row = blockIdx.x;
    int tid = threadIdx.x;
    float x[4]; float lsum = 0.f;
    for (int k = 0; k < 4; ++k) {
        int d = tid + 256*k;
        x[k] = buf[row*D_ + d] + scene[row*D_ + d];
        lsum += x[k];
    }
    float mean = block_sum(lsum) * (1.f / D_);
    float lv = 0.f;
    for (int k = 0; k < 4; ++k) { float d = x[k] - mean; lv += d * d; }
    float inv = rsqrtf(block_sum(lv) * (1.f / D_) + 1e-5f);
    for (int k = 0; k < 4; ++k) {
        int d = tid + 256*k;
        float y = (x[k] - mean) * inv * g[d] + bt[d];
        buf[row*D_ + d] = y;
        H16[row*D_ + d] = f2h(y);
    }
}

// ---------------------------------------------------------------------------
// Final: H = LN(gelu(G), eo_ln); plus h_fin copy blocks.
// ---------------------------------------------------------------------------
__global__ __launch_bounds__(256) void k_final(
    const float* __restrict__ G, const float* __restrict__ g, const float* __restrict__ bt,
    float* __restrict__ outH, const float* __restrict__ h, float* __restrict__ outh)
{
    int tid = threadIdx.x;
    if (blockIdx.x < B_*S_) {
        size_t row = blockIdx.x;
        float x[4]; float lsum = 0.f;
        for (int k = 0; k < 4; ++k) {
            x[k] = gelu_f(G[row*D_ + tid + 256*k]);
            lsum += x[k];
        }
        float mean = block_sum(lsum) * (1.f / D_);
        float lv = 0.f;
        for (int k = 0; k < 4; ++k) { float d = x[k] - mean; lv += d * d; }
        float inv = rsqrtf(block_sum(lv) * (1.f / D_) + 1e-5f);
        for (int k = 0; k < 4; ++k) {
            int d = tid + 256*k;
            outH[row*D_ + d] = (x[k] - mean) * inv * g[d] + bt[d];
        }
    } else {
        size_t bn = blockIdx.x - B_*S_;
        for (int d = tid; d < D_; d += 256)
            outh[bn*D_ + d] = h[bn*D_ + d];
    }
}

// ---------------------------------------------------------------------------
extern "C" void kernel_launch(void* const* d_in, const int* in_sizes, int n_in,
                              void* d_out, int out_size, void* d_ws, size_t ws_size,
                              hipStream_t stream)
{
    const float* scene = (const float*)d_in[0];
    const float* inc   = (const float*)d_in[1];
    const int*   etype = (const int*)d_in[3];
    const int*   emask = (const int*)d_in[4];
    const float* nemb  = (const float*)d_in[5];
    const float* temb  = (const float*)d_in[6];
    const float* nameW = (const float*)d_in[7];
    const float* nlg   = (const float*)d_in[8];
    const float* nlb   = (const float*)d_in[9];
    const float* n2eW  = (const float*)d_in[10];
    const float* n2eb  = (const float*)d_in[11];
    const float* t2eW  = (const float*)d_in[12];
    const float* t2eb  = (const float*)d_in[13];
    const float* elng  = (const float*)d_in[14];
    const float* elnb  = (const float*)d_in[15];
    const float* gW1   = (const float*)d_in[16];
    const float* gb1   = (const float*)d_in[17];
    const float* gW2   = (const float*)d_in[18];
    const float* gb2   = (const float*)d_in[19];
    const float* msW   = (const float*)d_in[20];
    const float* msB   = (const float*)d_in[21];
    const float* maW   = (const float*)d_in[22];
    const float* maB   = (const float*)d_in[23];
    const float* miW   = (const float*)d_in[24];
    const float* miB   = (const float*)d_in[25];
    const float* rolew = (const float*)d_in[26];
    const float* Wih   = (const float*)d_in[27];
    const float* Whh   = (const float*)d_in[28];
    const float* bih   = (const float*)d_in[29];
    const float* bhh   = (const float*)d_in[30];
    const float* ulng  = (const float*)d_in[31];
    const float* ulnb  = (const float*)d_in[32];
    const float* eoW   = (const float*)d_in[33];
    const float* eoB   = (const float*)d_in[34];
    const float* eolng = (const float*)d_in[35];
    const float* eolnb = (const float*)d_in[36];
    const float* rlng  = (const float*)d_in[37];
    const float* rlnb  = (const float*)d_in[38];

    float* outH = (float*)d_out;                    // [B,S,D] — doubles as esbuf
    float* outh = outH + (size_t)B_*S_*D_;          // [B,N,D] h_fin

    float* W = (float*)d_ws;
    size_t o = 0;
    int*   ctrl     = (int*)(W + o); o += 64;            // [cnt0, cnt1]
    float* esum2    = W + o; o += 2*(size_t)B_*D_;       // parity sum r*Hcat[:,0:1024]
    float* Tmi2     = W + o; o += 2*(size_t)B_*G3_;      // parity sum r*Hcat[:,1024:4096]
    float* wsum2    = W + o; o += 16;                    // parity per-batch sum r
    float* gatepre  = W + o; o += 32;
    float* rowrole  = W + o; o += 2*BN_;
    float* sclbuf   = W + o; o += BN_;
    int*   list     = (int*)(W + o); o += 2*BN_;
    float* hbuf     = W + o; o += (size_t)BN_*D_;
    float* Hcat     = W + o; o += (size_t)BN_*HC7;
    float* pre_t2e  = W + o; o += (size_t)B_*S_*D_;
    float* gBm      = W + o; o += 4*G3_;
    float* Emi      = W + o; o += (size_t)B_*G3_;
    float* Esmi     = W + o; o += (size_t)B_*S_*G3_;
    float* arcsum   = W + o; o += (size_t)BN_*G3_;
    float* tmp      = W + o; o += (size_t)BN_*D_;        // P (init) and G (final)
    unsigned short* U = (unsigned short*)(W + o);
    size_t uo = 0;
    unsigned short* h16    = U + uo; uo += (size_t)BN_*D_;
    unsigned short* H16    = U + uo; uo += (size_t)B_*S_*D_;
    unsigned short* Wih16  = U + uo; uo += (size_t)G3_*D_;
    unsigned short* Whh16  = U + uo; uo += (size_t)G3_*D_;
    unsigned short* n2e16  = U + uo; uo += (size_t)D_*D_;
    unsigned short* eoW16  = U + uo; uo += (size_t)D_*D_;
    unsigned short* nW16   = U + uo; uo += (size_t)D_*ND_;
    unsigned short* nE16   = U + uo; uo += (size_t)BN_*ND_;
    unsigned short* t2e16  = U + uo; uo += (size_t)D_*D_;
    unsigned short* sc16   = U + uo; uo += (size_t)B_*S_*D_;
    unsigned short* WcatT16= U + uo; uo += (size_t)G3_*D_;
    unsigned short* Wmi16  = U + uo; uo += (size_t)G3_*G3_;
    unsigned short* bias4  = U + uo; uo += 4*D_;

    // zero ctrl + both parities of esum/Tmi/wsum in one shot
    hipMemsetAsync(ctrl, 0,
        (64 + 2*(size_t)B_*D_ + 2*(size_t)B_*G3_ + 16) * sizeof(float), stream);

    // ---- conversions (per call; inputs restored each timed call) ----
    #define CVT(src, dst, r, c, ld) \
        k_f2h<<<(((size_t)(r)*(c)/4 + 255)/256), 256, 0, stream>>>(src, dst, r, c, ld)
    CVT(Wih,   Wih16, G3_, D_,  D_);
    CVT(Whh,   Whh16, G3_, D_,  D_);
    CVT(n2eW,  n2e16, D_,  D_,  D_);
    CVT(nameW, nW16,  D_,  ND_, ND_);
    CVT(nemb,  nE16,  BN_, ND_, ND_);
    CVT(eoW,   eoW16, D_,  D_,  D_);
    CVT(t2eW,  t2e16, D_,  D_,  D_);
    CVT(scene, sc16,  B_*S_, D_, D_);
    CVT(msB,   bias4 + 0,    1, D_, D_);
    CVT(maB,   bias4 + D_,   1, D_, D_);
    CVT(miB,   bias4 + 2*D_, 1, D_, D_);
    CVT(rolew, bias4 + 3*D_, 1, D_, D_);
    #undef CVT
    // WcatT16[seg*1024 + k][d] = {ms,ma,mi}W[d][k]  (transposed, fp16)
    k_f2hT<<<dim3(32,32), 256, 0, stream>>>(msW, WcatT16, D_, D_, D_, 0);
    k_f2hT<<<dim3(32,32), 256, 0, stream>>>(maW, WcatT16, D_, D_, D_, D_);
    k_f2hT<<<dim3(32,32), 256, 0, stream>>>(miW, WcatT16, D_, D_, D_, 2*D_);

    // Wmi16 = 256 * (Wih @ Wcat)  [3072,3072] fp16 (cols: es|arc|int segs)
    k_mfma16_nt<<<dim3(G3_/128, G3_/64), 256, 0, stream>>>(
        Wih16, WcatT16, nullptr, nullptr, Wmi16, 256.f, G3_, G3_, D_);
    // gBm[4,3072] = [msB|maB|miB|rolew] @ Wih^T
    k_mfma16_nt<<<dim3(G3_/128, 1), 256, 0, stream>>>(
        bias4, Wih16, nullptr, gBm, nullptr, 1.f, 4, G3_, D_);
    // pre_t2e[b,s,:] = t2e(scene) + t2eb
    k_mfma16_nt<<<dim3(D_/128, (B_*S_+63)/64), 256, 0, stream>>>(
        sc16, t2e16, t2eb, pre_t2e, nullptr, 1.f, B_*S_, D_, D_);
    // init: P = name_embs @ name_W^T ; h0 ; Hcat0
    k_mfma16_nt<<<dim3(D_/128, (BN_+63)/64), 256, 0, stream>>>(
        nE16, nW16, nullptr, tmp, nullptr, 1.f, BN_, D_, ND_);
    k_h0<<<BN_, 256, 0, stream>>>(tmp, etype, emask, temb, nlg, nlb, hbuf, h16);
    k_hcat0<<<dim3(112, 25), 256, 0, stream>>>(h16, n2e16, Wmi16, Whh16, Hcat);

    for (int s = 0; s < S_; ++s) {
        int par = s & 1;
        int*   cntp = ctrl + par;
        int*   pcnt = ctrl + (1 - par);
        int*   lst  = list + par * BN_;
        int*   plst = list + (1 - par) * BN_;
        float* rro  = rowrole + par * BN_;
        float* esumP = esum2 + (size_t)par * B_*D_;
        float* esumZ = esum2 + (size_t)(1 - par) * B_*D_;
        float* TmiP  = Tmi2 + (size_t)par * B_*G3_;
        float* TmiZ  = Tmi2 + (size_t)(1 - par) * B_*G3_;
        float* wsumP = wsum2 + par * 8;
        float* wsumZ = wsum2 + (1 - par) * 8;
        k_front<<<BN_ + 112*13, 256, 0, stream>>>(inc, emask, Esmi, arcsum,
            cntp, lst, rro, sclbuf, pcnt, plst, h16, n2e16, Wmi16, Whh16,
            Hcat, gatepre, esumP, TmiP, wsumP, s);
        k_mid<<<128, 256, 0, stream>>>(esumP, wsumP, esumZ, TmiZ, wsumZ,
            n2eb, pre_t2e, elng, elnb, gW1, gb1, gW2, Wmi16,
            outH, gatepre, Emi, Esmi, ctrl, par, s);
        k_fin<<<BN_, 256, 0, stream>>>(lst, cntp, rro, sclbuf, gatepre, gb2,
            Hcat, Emi, arcsum, TmiP, gBm, bih, bhh, ulng, ulnb, hbuf, h16, s);
    }

    // epilogue: H = LN(gelu(LN(es + scene) @ eo_W^T + eo_b)); h_fin copy
    k_resln<<<B_*S_, 256, 0, stream>>>(outH, scene, rlng, rlnb, H16);
    k_mfma16_nt<<<dim3(D_/128, (B_*S_+63)/64), 256, 0, stream>>>(
        H16, eoW16, eoB, tmp, nullptr, 1.f, B_*S_, D_, D_);
    k_final<<<B_*S_ + BN_, 256, 0, stream>>>(tmp, eolng, eolnb, outH, hbuf, outh);
}

// Round 7
// 4033.424 us; speedup vs baseline: 3.5041x; 1.0112x over previous
//
#include <hip/hip_runtime.h>
#include <math.h>

#define B_   8
#define S_   64
#define N_   100
#define D_   1024
#define ND_  768
#define BN_  800
#define G3_  3072
#define HC7  7168
#define RSC  0.00390625f   // 1/256 — Wmi stored x256 to avoid fp16 subnormals

typedef _Float16 f16x8 __attribute__((ext_vector_type(8)));
typedef float f32x4 __attribute__((ext_vector_type(4)));

#define MFMA16(a,b,c) __builtin_amdgcn_mfma_f32_16x16x32_f16(a, b, c, 0, 0, 0)

static __device__ __forceinline__ float wave_sum(float v) {
    for (int off = 32; off > 0; off >>= 1) v += __shfl_down(v, off, 64);
    return v;
}

static __device__ __forceinline__ float wave_allsum(float v) {
    for (int off = 1; off < 64; off <<= 1) v += __shfl_xor(v, off, 64);
    return v;
}

// All 256 threads must call; returns full-block sum to every thread.
static __device__ __forceinline__ float block_sum(float v) {
    __shared__ float red_[8];
    float w = wave_sum(v);
    int lane = threadIdx.x & 63, wid = threadIdx.x >> 6;
    __syncthreads();               // protect red_ reuse across calls
    if (lane == 0) red_[wid] = w;
    __syncthreads();
    float t = 0.f;
    for (int i = 0; i < 4; ++i) t += red_[i];
    return t;
}

static __device__ __forceinline__ float gelu_f(float x) {
    return 0.5f * x * (1.f + erff(x * 0.70710678118654752f));
}

static __device__ __forceinline__ unsigned short f2h(float x) {
    union { _Float16 h; unsigned short u; } c; c.h = (_Float16)x; return c.u;
}

// ---------------------------------------------------------------------------
// fp32 -> fp16 2D convert. cols % 4 == 0.
// ---------------------------------------------------------------------------
__global__ __launch_bounds__(256) void k_f2h(
    const float* __restrict__ src, unsigned short* __restrict__ dst,
    int rows, int cols, int ldd)
{
    size_t n = (size_t)rows * cols;
    size_t i = ((size_t)blockIdx.x * 256 + threadIdx.x) * 4;
    if (i >= n) return;
    int r = (int)(i / cols);
    int c = (int)(i - (size_t)r * cols);
    float4 v = *(const float4*)(src + i);
    ushort4 o; o.x = f2h(v.x); o.y = f2h(v.y); o.z = f2h(v.z); o.w = f2h(v.w);
    *(ushort4*)(dst + (size_t)r * ldd + c) = o;
}

// ---------------------------------------------------------------------------
// fp32 -> fp16 TRANSPOSING convert: dst[rowoff + c][r] = src[r][c].
// ---------------------------------------------------------------------------
__global__ __launch_bounds__(256) void k_f2hT(
    const float* __restrict__ src, unsigned short* __restrict__ dst,
    int R, int C, int ldd, int rowoff)
{
    __shared__ _Float16 T[32][33];
    int tr = threadIdx.x >> 3, tc4 = (threadIdx.x & 7) * 4;
    int r0 = blockIdx.y * 32, c0 = blockIdx.x * 32;
    float4 v = *(const float4*)(src + (size_t)(r0 + tr) * C + c0 + tc4);
    T[tc4][tr] = (_Float16)v.x; T[tc4+1][tr] = (_Float16)v.y;
    T[tc4+2][tr] = (_Float16)v.z; T[tc4+3][tr] = (_Float16)v.w;
    __syncthreads();
    union { _Float16 h; unsigned short u; } cv;
    ushort4 o;
    cv.h = T[tr][tc4];   o.x = cv.u;
    cv.h = T[tr][tc4+1]; o.y = cv.u;
    cv.h = T[tr][tc4+2]; o.z = cv.u;
    cv.h = T[tr][tc4+3]; o.w = cv.u;
    *(ushort4*)(dst + (size_t)(rowoff + c0 + tr) * ldd + r0 + tc4) = o;
}

// ---------------------------------------------------------------------------
// FP16 MFMA GEMM (setup/epilogue only): C[M,Nc] = A16[M,K] @ W16[Nc,K]^T.
// TM=64, TN=128. If C16 != null: writes f2h(acc*oscale). Else fp32 + bias.
// ---------------------------------------------------------------------------
__global__ __launch_bounds__(256) void k_mfma16_nt(
    const unsigned short* __restrict__ A16, const unsigned short* __restrict__ W16,
    const float* __restrict__ bias, float* __restrict__ C,
    unsigned short* __restrict__ C16, float oscale,
    int M, int Nc, int K)
{
    int m0 = blockIdx.y * 64; if (m0 >= M) return;
    int n0 = blockIdx.x * 128;
    __shared__ _Float16 sA[64][72];
    __shared__ _Float16 sB[128][72];
    int tid = threadIdx.x;
    int w = tid >> 6, l = tid & 63;
    int l15 = l & 15, q = l >> 4;
    int wn = w * 32;
    int arow = tid >> 3, achk = (tid & 7) * 8;
    f32x4 acc[4][2] = {};
    for (int k0 = 0; k0 < K; k0 += 64) {
        for (int ri = 0; ri < 64; ri += 32) {
            int gm = m0 + arow + ri;
            uint4 v = make_uint4(0u, 0u, 0u, 0u);
            if (gm < M) v = *(const uint4*)(A16 + (size_t)gm * K + k0 + achk);
            *(uint4*)(&sA[arow + ri][achk]) = v;
        }
        for (int i = 0; i < 4; ++i) {
            int r = arow + 32 * i;
            *(uint4*)(&sB[r][achk]) = *(const uint4*)(W16 + (size_t)(n0 + r) * K + k0 + achk);
        }
        __syncthreads();
#pragma unroll
        for (int ks = 0; ks < 64; ks += 32) {
            f16x8 b0 = *(const f16x8*)(&sB[wn + l15][ks + q*8]);
            f16x8 b1 = *(const f16x8*)(&sB[wn + 16 + l15][ks + q*8]);
#pragma unroll
            for (int mi = 0; mi < 4; ++mi) {
                f16x8 a = *(const f16x8*)(&sA[mi*16 + l15][ks + q*8]);
                acc[mi][0] = MFMA16(a, b0, acc[mi][0]);
                acc[mi][1] = MFMA16(a, b1, acc[mi][1]);
            }
        }
        __syncthreads();
    }
    for (int mi = 0; mi < 4; ++mi)
        for (int nj = 0; nj < 2; ++nj)
            for (int r = 0; r < 4; ++r) {
                int gm = m0 + mi*16 + q*4 + r;
                int cl = wn + nj*16 + l15;
                if (gm < M) {
                    size_t off = (size_t)gm * Nc + n0 + cl;
                    float v = acc[mi][nj][r];
                    if (C16) C16[off] = f2h(v * oscale);
                    else C[off] = v + (bias ? bias[n0 + cl] : 0.f);
                }
            }
}

// ---------------------------------------------------------------------------
// h0 = mask * (type_embed[type] + LN(P, name_ln)); fp32 h + fp16 mirror
// ---------------------------------------------------------------------------
__global__ __launch_bounds__(256) void k_h0(
    const float* __restrict__ P, const int* __restrict__ etype,
    const int* __restrict__ emask, const float* __restrict__ temb,
    const float* __restrict__ g, const float* __restrict__ bt,
    float* __restrict__ h, unsigned short* __restrict__ h16)
{
    int bn = blockIdx.x, tid = threadIdx.x;
    int t = etype[bn], mk = emask[bn];
    float x[4]; float lsum = 0.f;
    for (int k = 0; k < 4; ++k) { x[k] = P[(size_t)bn*D_ + tid + 256*k]; lsum += x[k]; }
    float mean = block_sum(lsum) * (1.f / D_);
    float lv = 0.f;
    for (int k = 0; k < 4; ++k) { float d = x[k] - mean; lv += d * d; }
    float inv = rsqrtf(block_sum(lv) * (1.f / D_) + 1e-5f);
    for (int k = 0; k < 4; ++k) {
        int d = tid + 256*k;
        float y = (x[k] - mean) * inv * g[d] + bt[d];
        float hv = mk ? (temb[(size_t)t*D_ + d] + y) : 0.f;
        h[(size_t)bn*D_ + d] = hv;
        h16[(size_t)bn*D_ + d] = f2h(hv);
    }
}

// ---------------------------------------------------------------------------
// Hcat init: Hcat[bn, 0:1024|1024:4096|4096:7168] = h16[bn] @ [n2e|Wmi2|Whh]^T
// Grid (112, 25). TM=32, TN=64.
// ---------------------------------------------------------------------------
__global__ __launch_bounds__(256) void k_hcat0(
    const unsigned short* __restrict__ h16, const unsigned short* __restrict__ n2e16,
    const unsigned short* __restrict__ Wmi16, const unsigned short* __restrict__ Whh16,
    float* __restrict__ Hcat)
{
    int m0 = blockIdx.y * 32;
    int n0 = blockIdx.x * 64;
    const unsigned short* Bp; int ldb; int nl;
    if (n0 < 1024)      { Bp = n2e16;        ldb = D_;  nl = n0; }
    else if (n0 < 4096) { Bp = Wmi16 + 2048; ldb = G3_; nl = n0 - 1024; }
    else                { Bp = Whh16;        ldb = D_;  nl = n0 - 4096; }
    __shared__ _Float16 sA[32][72];
    __shared__ _Float16 sB[64][72];
    int tid = threadIdx.x;
    int w = tid >> 6, l = tid & 63;
    int l15 = l & 15, q = l >> 4;
    int wm = (w & 1) * 16, wn = (w >> 1) * 32;
    int arow = tid >> 3, achk = (tid & 7) * 8;
    int gmA = m0 + arow;
    f32x4 acc[2] = {};
    for (int k0 = 0; k0 < D_; k0 += 64) {
        *(uint4*)(&sA[arow][achk]) = *(const uint4*)(h16 + (size_t)gmA*D_ + k0 + achk);
        *(uint4*)(&sB[arow][achk])      = *(const uint4*)(Bp + (size_t)(nl + arow)*ldb + k0 + achk);
        *(uint4*)(&sB[arow + 32][achk]) = *(const uint4*)(Bp + (size_t)(nl + arow + 32)*ldb + k0 + achk);
        __syncthreads();
#pragma unroll
        for (int ks = 0; ks < 64; ks += 32) {
            f16x8 a  = *(const f16x8*)(&sA[wm + l15][ks + q*8]);
            f16x8 b0 = *(const f16x8*)(&sB[wn + l15][ks + q*8]);
            f16x8 b1 = *(const f16x8*)(&sB[wn + 16 + l15][ks + q*8]);
            acc[0] = MFMA16(a, b0, acc[0]);
            acc[1] = MFMA16(a, b1, acc[1]);
        }
        __syncthreads();
    }
    for (int j = 0; j < 2; ++j)
        for (int r = 0; r < 4; ++r) {
            int row = wm + q*4 + r;
            Hcat[(size_t)(m0 + row)*HC7 + n0 + wn + j*16 + l15] = acc[j][r];
        }
}

// ---------------------------------------------------------------------------
// K_front: blocks [0,800): compaction + arcsum (float4) + per-row scalars +
//          stale esum/Tmi contributions for rows whose Hcat is current.
//          blocks [800, 800+112*26): Hcat update GEMM TM=32/TN=64 for PREV
//          rows (more, thinner blocks for latency hiding); GEMM blocks
//          contribute fresh esum/Tmi for rows also active at s.
// Block 0 zeroes gatepre.
// ---------------------------------------------------------------------------
__global__ __launch_bounds__(256) void k_front(
    const float* __restrict__ inc, const int* __restrict__ emask,
    const float* __restrict__ Esmi, float* __restrict__ arcsum,
    int* __restrict__ cntp, int* __restrict__ lst, float* __restrict__ rro,
    float* __restrict__ scl,
    const int* __restrict__ prevcnt, const int* __restrict__ prevlist,
    const unsigned short* __restrict__ h16, const unsigned short* __restrict__ n2e16,
    const unsigned short* __restrict__ Wmi16, const unsigned short* __restrict__ Whh16,
    float* __restrict__ Hcat, float* __restrict__ gatepre,
    float* __restrict__ esumP, float* __restrict__ TmiP, float* __restrict__ wsumP,
    int s)
{
    int tid = threadIdx.x, bid = blockIdx.x;
    if (bid == 0 && tid < 32) gatepre[tid] = 0.f;
    if (bid < BN_) {
        int m = bid;
        int b = m / N_;
        float r = emask[m] ? inc[(size_t)m*S_ + s] : 0.f;
        if (r <= 0.f) return;
        __shared__ int sidx, nwa;
        __shared__ float wav[S_]; __shared__ int wai[S_];
        if (tid == 0) { sidx = atomicAdd(cntp, 1); nwa = 0; }
        __syncthreads();
        int idx = sidx;
        float denomA = fmaxf((float)(s - 1), 1.f);
        float wa = 0.f;
        if (tid < s) {
            float iv = inc[(size_t)m*S_ + tid];
            if (iv > 0.f) {
                wa = iv * r * expf(-1.f + (float)tid / denomA);
                int p = atomicAdd(&nwa, 1);
                wav[p] = wa; wai[p] = tid;
            }
        }
        float dA = block_sum(wa);
        float rm = 0.f;
        if (tid < N_) rm = emask[b*N_ + tid] ? inc[((size_t)b*N_ + tid)*S_ + s] : 0.f;
        float wsum = block_sum(rm);
        __syncthreads();
        int na = nwa;
        float sclA = 1.f / fmaxf(dA, 1e-8f);
        if (tid == 0) {
            lst[idx] = m; rro[idx] = r;
            scl[idx] = r / fmaxf(r * (wsum - r), 1e-8f);
            wsumP[b] = wsum;
        }
        // esum/Tmi: rows NOT updated at s-1 have current Hcat -> accumulate here.
        float rprev = (s > 0) ? inc[(size_t)m*S_ + (s-1)] : 0.f;
        if (rprev <= 0.f) {
            const float4* hp = (const float4*)(Hcat + (size_t)m*HC7);
#pragma unroll
            for (int j2 = 0; j2 < 4; ++j2) {
                float4 hv = hp[tid + 256*j2];
                int c = (tid + 256*j2) * 4;
                float* dst = (c < 1024) ? (esumP + (size_t)b*D_ + c)
                                        : (TmiP + (size_t)b*G3_ + (c - 1024));
                atomicAdd(dst + 0, r*hv.x); atomicAdd(dst + 1, r*hv.y);
                atomicAdd(dst + 2, r*hv.z); atomicAdd(dst + 3, r*hv.w);
            }
        }
        // arcsum [3072]: 3 x float4 per thread (numerics identical to scalar)
        f32x4 a4[3];
#pragma unroll
        for (int k = 0; k < 3; ++k) a4[k] = (f32x4){0.f,0.f,0.f,0.f};
        for (int j = 0; j < na; ++j) {
            float wj = wav[j];
            const f32x4* ep = (const f32x4*)(Esmi + ((size_t)b*S_ + wai[j])*G3_);
#pragma unroll
            for (int k = 0; k < 3; ++k) {
                f32x4 e = ep[tid + 256*k];
#pragma unroll
                for (int q = 0; q < 4; ++q) a4[k][q] += wj * e[q];
            }
        }
        f32x4* ao = (f32x4*)(arcsum + (size_t)idx*G3_);
#pragma unroll
        for (int k = 0; k < 3; ++k) {
            f32x4 v;
#pragma unroll
            for (int q = 0; q < 4; ++q) v[q] = a4[k][q] * sclA;
            ao[tid + 256*k] = v;
        }
    } else {
        int pM = *prevcnt;
        int t = bid - BN_;
        int nt = t % 112, mt = t / 112;
        int m0 = mt * 32;
        if (m0 >= pM) return;
        int n0 = nt * 64;
        const unsigned short* Bp; int ldb; int nl;
        if (n0 < 1024)      { Bp = n2e16;        ldb = D_;  nl = n0; }
        else if (n0 < 4096) { Bp = Wmi16 + 2048; ldb = G3_; nl = n0 - 1024; }
        else                { Bp = Whh16;        ldb = D_;  nl = n0 - 4096; }
        __shared__ _Float16 sA[32][72];
        __shared__ _Float16 sB[64][72];
        __shared__ int slist[32];
        __shared__ float srn[32];
        __shared__ int sbb[32];
        if (tid < 32) {
            int gm = m0 + tid;
            int m = (gm < pM) ? prevlist[gm] : 0;
            slist[tid] = m;
            float rn = 0.f;
            if (gm < pM) rn = emask[m] ? inc[(size_t)m*S_ + s] : 0.f;
            srn[tid] = rn;
            sbb[tid] = m / N_;
        }
        __syncthreads();
        int w = tid >> 6, l = tid & 63;
        int l15 = l & 15, q = l >> 4;
        int wm = (w & 1) * 16, wn = (w >> 1) * 32;
        int arow = tid >> 3, achk = (tid & 7) * 8;
        f32x4 acc[2] = {};
        for (int k0 = 0; k0 < D_; k0 += 64) {
            {
                int gm = m0 + arow;
                uint4 v = make_uint4(0u,0u,0u,0u);
                if (gm < pM) v = *(const uint4*)(h16 + (size_t)slist[arow]*D_ + k0 + achk);
                *(uint4*)(&sA[arow][achk]) = v;
            }
            *(uint4*)(&sB[arow][achk])      = *(const uint4*)(Bp + (size_t)(nl + arow)*ldb + k0 + achk);
            *(uint4*)(&sB[arow + 32][achk]) = *(const uint4*)(Bp + (size_t)(nl + arow + 32)*ldb + k0 + achk);
            __syncthreads();
#pragma unroll
            for (int ks = 0; ks < 64; ks += 32) {
                f16x8 a  = *(const f16x8*)(&sA[wm + l15][ks + q*8]);
                f16x8 b0 = *(const f16x8*)(&sB[wn + l15][ks + q*8]);
                f16x8 b1 = *(const f16x8*)(&sB[wn + 16 + l15][ks + q*8]);
                acc[0] = MFMA16(a, b0, acc[0]);
                acc[1] = MFMA16(a, b1, acc[1]);
            }
            __syncthreads();
        }
        for (int nj = 0; nj < 2; ++nj)
            for (int r4 = 0; r4 < 4; ++r4) {
                int row = wm + q*4 + r4;
                int gm = m0 + row;
                if (gm < pM) {
                    float v = acc[nj][r4];
                    int c = n0 + wn + nj*16 + l15;
                    Hcat[(size_t)slist[row]*HC7 + c] = v;
                    float rn = srn[row];
                    if (rn > 0.f && c < 4096) {
                        float* dst = (c < 1024)
                            ? (esumP + (size_t)sbb[row]*D_ + c)
                            : (TmiP + (size_t)sbb[row]*G3_ + (c - 1024));
                        atomicAdd(dst, rn * v);
                    }
                }
            }
    }
}

// ---------------------------------------------------------------------------
// K_mid (grid 224): [0,32) light e_s + gate MLP; [32,224) Emi/Esmi GEMV,
// one 32-col x one-segment tile per block (more blocks, better latency
// hiding); all 8 batches share one Wmi16 read. Block 0 resets next counter.
// ---------------------------------------------------------------------------
__global__ __launch_bounds__(256) void k_mid(
    const float* __restrict__ esumP, const float* __restrict__ wsumP,
    float* __restrict__ esumZ, float* __restrict__ TmiZ, float* __restrict__ wsumZ,
    const float* __restrict__ n2eb, const float* __restrict__ pre_t2e,
    const float* __restrict__ elng, const float* __restrict__ elnb,
    const float* __restrict__ gW1, const float* __restrict__ gb1,
    const float* __restrict__ gW2, const unsigned short* __restrict__ Wmi16,
    float* __restrict__ esbuf, float* __restrict__ gatepre,
    float* __restrict__ Emi, float* __restrict__ Esmi,
    int* __restrict__ ctrl, int par, int s)
{
    int bid = blockIdx.x, tid = threadIdx.x;
    if (bid < 32) {
        __shared__ float se[D_];
        int b = bid >> 2, seg = bid & 3;
        if (bid == 0 && tid == 0) ctrl[1 - par] = 0;
        esumZ[(size_t)b*D_ + seg*256 + tid] = 0.f;
#pragma unroll
        for (int j = 0; j < 3; ++j) TmiZ[(size_t)b*G3_ + seg*768 + j*256 + tid] = 0.f;
        if (seg == 0 && tid == 0) wsumZ[b] = 0.f;
        float invw = 1.f / fmaxf(wsumP[b], 1.f);
        float4 ev = ((const float4*)(esumP + (size_t)b*D_))[tid];
        float4 nb = ((const float4*)n2eb)[tid];
        float4 pt = ((const float4*)(pre_t2e + ((size_t)b*S_ + s)*D_))[tid];
        float x[4] = { ev.x*invw + nb.x + pt.x, ev.y*invw + nb.y + pt.y,
                       ev.z*invw + nb.z + pt.z, ev.w*invw + nb.w + pt.w };
        float mean = block_sum(x[0]+x[1]+x[2]+x[3]) * (1.f / D_);
        float lv = 0.f;
#pragma unroll
        for (int k = 0; k < 4; ++k) { float d = x[k] - mean; lv += d * d; }
        float inv = rsqrtf(block_sum(lv) * (1.f / D_) + 1e-5f);
        float4 lg = ((const float4*)elng)[tid];
        float4 lb = ((const float4*)elnb)[tid];
        float y0 = (x[0]-mean)*inv*lg.x + lb.x;
        float y1 = (x[1]-mean)*inv*lg.y + lb.y;
        float y2 = (x[2]-mean)*inv*lg.z + lb.z;
        float y3 = (x[3]-mean)*inv*lg.w + lb.w;
        int d4 = tid * 4;
        se[d4] = y0; se[d4+1] = y1; se[d4+2] = y2; se[d4+3] = y3;
        if (seg == 0)
            ((float4*)(esbuf + ((size_t)b*S_ + s)*D_))[tid] = make_float4(y0,y1,y2,y3);
        __syncthreads();
        if (tid < 64) {
            int u = seg * 64 + tid;
            float acc = gb1[u];
            const float* w1 = gW1 + (size_t)u * D_;
            for (int j = 0; j < D_; j += 4) {
                float4 w = *(const float4*)(w1 + j);
                acc += w.x*se[j] + w.y*se[j+1] + w.z*se[j+2] + w.w*se[j+3];
            }
            float hg = gelu_f(acc);
            for (int c = 0; c < 3; ++c) {
                float p = wave_sum(gW2[c*256 + u] * hg);
                if (tid == 0) atomicAdd(gatepre + b*4 + c, p);
            }
        }
    } else {
        __shared__ float se32[8][1028];
        int w = tid >> 6, lane = tid & 63;
        for (int bb = 0; bb < 2; ++bb) {
            int b = w*2 + bb;
            float invw = 1.f / fmaxf(wsumP[b], 1.f);
            int d0 = lane * 16;
            const float4* ep = (const float4*)(esumP + (size_t)b*D_ + d0);
            const float4* np = (const float4*)(n2eb + d0);
            const float4* pp = (const float4*)(pre_t2e + ((size_t)b*S_ + s)*D_ + d0);
            float x[16]; float sm = 0.f;
#pragma unroll
            for (int j = 0; j < 4; ++j) {
                float4 e = ep[j], n = np[j], p = pp[j];
                x[j*4+0] = e.x*invw + n.x + p.x;
                x[j*4+1] = e.y*invw + n.y + p.y;
                x[j*4+2] = e.z*invw + n.z + p.z;
                x[j*4+3] = e.w*invw + n.w + p.w;
                sm += x[j*4+0] + x[j*4+1] + x[j*4+2] + x[j*4+3];
            }
            float mean = wave_allsum(sm) * (1.f / D_);
            float lv = 0.f;
#pragma unroll
            for (int j = 0; j < 16; ++j) { float d = x[j] - mean; lv += d * d; }
            float inv = rsqrtf(wave_allsum(lv) * (1.f / D_) + 1e-5f);
            const float4* lgp = (const float4*)(elng + d0);
            const float4* lbp = (const float4*)(elnb + d0);
#pragma unroll
            for (int j = 0; j < 4; ++j) {
                float4 lg = lgp[j], lb = lbp[j];
                se32[b][d0 + j*4 + 0] = (x[j*4+0]-mean)*inv*lg.x + lb.x;
                se32[b][d0 + j*4 + 1] = (x[j*4+1]-mean)*inv*lg.y + lb.y;
                se32[b][d0 + j*4 + 2] = (x[j*4+2]-mean)*inv*lg.z + lb.z;
                se32[b][d0 + j*4 + 3] = (x[j*4+3]-mean)*inv*lg.w + lb.w;
            }
        }
        __syncthreads();
        int t = bid - 32;
        int seg = t & 1;
        int c0 = (t >> 1) * 32;
        int colg = tid >> 5, t31 = tid & 31;
        int cb = c0 + colg * 4;
        float accA[4][8] = {};
#pragma unroll
        for (int i = 0; i < 8; ++i) {
            int kh = t31*4 + i*128;
            float wf[4][4];
#pragma unroll
            for (int c = 0; c < 4; ++c) {
                union { uint2 u; _Float16 h[4]; } cv;
                cv.u = *(const uint2*)(Wmi16 + (size_t)(cb + c)*G3_ + seg*1024 + kh);
                wf[c][0] = (float)cv.h[0]; wf[c][1] = (float)cv.h[1];
                wf[c][2] = (float)cv.h[2]; wf[c][3] = (float)cv.h[3];
            }
#pragma unroll
            for (int b = 0; b < 8; ++b) {
                float4 sv = *(const float4*)(&se32[b][kh]);
#pragma unroll
                for (int c = 0; c < 4; ++c)
                    accA[c][b] += wf[c][0]*sv.x + wf[c][1]*sv.y
                                + wf[c][2]*sv.z + wf[c][3]*sv.w;
            }
        }
#pragma unroll
        for (int off = 16; off >= 1; off >>= 1) {
#pragma unroll
            for (int c = 0; c < 4; ++c)
#pragma unroll
                for (int b = 0; b < 8; ++b)
                    accA[c][b] += __shfl_down(accA[c][b], off, 32);
        }
        if (t31 == 0) {
#pragma unroll
            for (int c = 0; c < 4; ++c) {
                int col = cb + c;
#pragma unroll
                for (int b = 0; b < 8; ++b) {
                    if (seg == 0) Emi[(size_t)b*G3_ + col] = accA[c][b];
                    else Esmi[((size_t)b*S_ + s)*G3_ + col] = accA[c][b];
                }
            }
        }
    }
}

// ---------------------------------------------------------------------------
// K_fin: GRU assembly + LN + clip + h update. Single-pass float4 loads
// (latency-bound kernel: ~180 blocks over 256 CUs; fewer, wider loads).
// ---------------------------------------------------------------------------
__global__ __launch_bounds__(256) void k_fin(
    const int* __restrict__ lst, const int* __restrict__ cntp,
    const float* __restrict__ rro, const float* __restrict__ scl,
    const float* __restrict__ gatepre, const float* __restrict__ gb2,
    const float* __restrict__ Hcat, const float* __restrict__ Emi,
    const float* __restrict__ arcsum, const float* __restrict__ Tmi,
    const float* __restrict__ gBm, const float* __restrict__ bih,
    const float* __restrict__ bhh,
    const float* __restrict__ ulng, const float* __restrict__ ulnb,
    float* __restrict__ h, unsigned short* __restrict__ h16, int s)
{
    int row = blockIdx.x;
    if (row >= *cntp) return;
    int bn = lst[row];
    int b = bn / N_;
    int tid = threadIdx.x;
    float t0 = gatepre[b*4+0] + gb2[0];
    float t1 = gatepre[b*4+1] + gb2[1];
    float t2 = gatepre[b*4+2] + gb2[2];
    float mx = fmaxf(t0, fmaxf(t1, t2));
    float e0 = expf(t0-mx), e1 = expf(t1-mx), e2 = expf(t2-mx);
    float si = 1.f / (e0 + e1 + e2);
    float g0 = e0*si, g1 = (s > 0) ? e1*si : 0.f, g2 = e2*si;
    float rv = rro[row];
    float sI = scl[row];
    const f32x4* Hmi4 = (const f32x4*)(Hcat + (size_t)bn*HC7 + 1024);
    const f32x4* Hhh4 = (const f32x4*)(Hcat + (size_t)bn*HC7 + 4096);
    const f32x4* em4  = (const f32x4*)(Emi + (size_t)b*G3_);
    const f32x4* as4  = (const f32x4*)(arcsum + (size_t)row*G3_);
    const f32x4* tm4  = (const f32x4*)(Tmi + (size_t)b*G3_);
    const f32x4* gB4  = (const f32x4*)gBm;
    const f32x4* bih4 = (const f32x4*)bih;
    const f32x4* bhh4 = (const f32x4*)bhh;
    const f32x4* h4   = (const f32x4*)(h + (size_t)bn*D_);
    f32x4 ip[3];
#pragma unroll
    for (int c = 0; c < 3; ++c) {
        int dd4 = c*256 + tid;
        f32x4 tm_ = tm4[dd4], hm_ = Hmi4[dd4], em_ = em4[dd4], as_ = as4[dd4];
        f32x4 b0 = gB4[dd4], b1 = gB4[768 + dd4];
        f32x4 b2 = gB4[1536 + dd4], b3 = gB4[2304 + dd4];
        f32x4 bi = bih4[dd4];
#pragma unroll
        for (int j = 0; j < 4; ++j) {
            float gint = tm_[j] - rv * hm_[j];
            ip[c][j] = RSC * (g0*em_[j] + g1*as_[j] + g2*sI*gint)
                     + g0*b0[j] + g1*b1[j] + g2*b2[j] + rv*b3[j] + bi[j];
        }
    }
    f32x4 a0 = Hhh4[tid],       c0 = bhh4[tid];
    f32x4 a1 = Hhh4[256 + tid], c1 = bhh4[256 + tid];
    f32x4 a2 = Hhh4[512 + tid], c2 = bhh4[512 + tid];
    f32x4 hvv = h4[tid];
    f32x4 u4; float lsum = 0.f;
#pragma unroll
    for (int j = 0; j < 4; ++j) {
        float r = 1.f / (1.f + expf(-(ip[0][j] + a0[j] + c0[j])));
        float z = 1.f / (1.f + expf(-(ip[1][j] + a1[j] + c1[j])));
        float nn = tanhf(ip[2][j] + r * (a2[j] + c2[j]));
        u4[j] = (1.f - z) * nn + z * hvv[j];
        lsum += u4[j];
    }
    float mean = block_sum(lsum) * (1.f / D_);
    float lv = 0.f;
#pragma unroll
    for (int j = 0; j < 4; ++j) { float d = u4[j] - mean; lv += d * d; }
    float inv = rsqrtf(block_sum(lv) * (1.f / D_) + 1e-5f);
    f32x4 lg = ((const f32x4*)ulng)[tid];
    f32x4 lb = ((const f32x4*)ulnb)[tid];
    f32x4 y4; ushort4 o;
#pragma unroll
    for (int j = 0; j < 4; ++j) {
        float y = (u4[j] - mean) * inv * lg[j] + lb[j];
        y4[j] = fminf(fmaxf(y, -50.f), 50.f);
    }
    *(f32x4*)(h + (size_t)bn*D_ + tid*4) = y4;
    o.x = f2h(y4[0]); o.y = f2h(y4[1]); o.z = f2h(y4[2]); o.w = f2h(y4[3]);
    *(ushort4*)(h16 + (size_t)bn*D_ + tid*4) = o;
}

// ---------------------------------------------------------------------------
// Final: buf = LN(buf + scene, res_ln) in-place; also fp16 copy.
// ---------------------------------------------------------------------------
__global__ __launch_bounds__(256) void k_resln(
    float* __restrict__ buf, const float* __restrict__ scene,
    const float* __restrict__ g, const float* __restrict__ bt,
    unsigned short* __restrict__ H16)
{
    size_t row = blockIdx.x;
    int tid = threadIdx.x;
    float x[4]; float lsum = 0.f;
    for (int k = 0; k < 4; ++k) {
        int d = tid + 256*k;
        x[k] = buf[row*D_ + d] + scene[row*D_ + d];
        lsum += x[k];
    }
    float mean = block_sum(lsum) * (1.f / D_);
    float lv = 0.f;
    for (int k = 0; k < 4; ++k) { float d = x[k] - mean; lv += d * d; }
    float inv = rsqrtf(block_sum(lv) * (1.f / D_) + 1e-5f);
    for (int k = 0; k < 4; ++k) {
        int d = tid + 256*k;
        float y = (x[k] - mean) * inv * g[d] + bt[d];
        buf[row*D_ + d] = y;
        H16[row*D_ + d] = f2h(y);
    }
}

// ---------------------------------------------------------------------------
// Final: H = LN(gelu(G), eo_ln); plus h_fin copy blocks.
// ---------------------------------------------------------------------------
__global__ __launch_bounds__(256) void k_final(
    const float* __restrict__ G, const float* __restrict__ g, const float* __restrict__ bt,
    float* __restrict__ outH, const float* __restrict__ h, float* __restrict__ outh)
{
    int tid = threadIdx.x;
    if (blockIdx.x < B_*S_) {
        size_t row = blockIdx.x;
        float x[4]; float lsum = 0.f;
        for (int k = 0; k < 4; ++k) {
            x[k] = gelu_f(G[row*D_ + tid + 256*k]);
            lsum += x[k];
        }
        float mean = block_sum(lsum) * (1.f / D_);
        float lv = 0.f;
        for (int k = 0; k < 4; ++k) { float d = x[k] - mean; lv += d * d; }
        float inv = rsqrtf(block_sum(lv) * (1.f / D_) + 1e-5f);
        for (int k = 0; k < 4; ++k) {
            int d = tid + 256*k;
            outH[row*D_ + d] = (x[k] - mean) * inv * g[d] + bt[d];
        }
    } else {
        size_t bn = blockIdx.x - B_*S_;
        for (int d = tid; d < D_; d += 256)
            outh[bn*D_ + d] = h[bn*D_ + d];
    }
}

// ---------------------------------------------------------------------------
extern "C" void kernel_launch(void* const* d_in, const int* in_sizes, int n_in,
                              void* d_out, int out_size, void* d_ws, size_t ws_size,
                              hipStream_t stream)
{
    const float* scene = (const float*)d_in[0];
    const float* inc   = (const float*)d_in[1];
    const int*   etype = (const int*)d_in[3];
    const int*   emask = (const int*)d_in[4];
    const float* nemb  = (const float*)d_in[5];
    const float* temb  = (const float*)d_in[6];
    const float* nameW = (const float*)d_in[7];
    const float* nlg   = (const float*)d_in[8];
    const float* nlb   = (const float*)d_in[9];
    const float* n2eW  = (const float*)d_in[10];
    const float* n2eb  = (const float*)d_in[11];
    const float* t2eW  = (const float*)d_in[12];
    const float* t2eb  = (const float*)d_in[13];
    const float* elng  = (const float*)d_in[14];
    const float* elnb  = (const float*)d_in[15];
    const float* gW1   = (const float*)d_in[16];
    const float* gb1   = (const float*)d_in[17];
    const float* gW2   = (const float*)d_in[18];
    const float* gb2   = (const float*)d_in[19];
    const float* msW   = (const float*)d_in[20];
    const float* msB   = (const float*)d_in[21];
    const float* maW   = (const float*)d_in[22];
    const float* maB   = (const float*)d_in[23];
    const float* miW   = (const float*)d_in[24];
    const float* miB   = (const float*)d_in[25];
    const float* rolew = (const float*)d_in[26];
    const float* Wih   = (const float*)d_in[27];
    const float* Whh   = (const float*)d_in[28];
    const float* bih   = (const float*)d_in[29];
    const float* bhh   = (const float*)d_in[30];
    const float* ulng  = (const float*)d_in[31];
    const float* ulnb  = (const float*)d_in[32];
    const float* eoW   = (const float*)d_in[33];
    const float* eoB   = (const float*)d_in[34];
    const float* eolng = (const float*)d_in[35];
    const float* eolnb = (const float*)d_in[36];
    const float* rlng  = (const float*)d_in[37];
    const float* rlnb  = (const float*)d_in[38];

    float* outH = (float*)d_out;                    // [B,S,D] — doubles as esbuf
    float* outh = outH + (size_t)B_*S_*D_;          // [B,N,D] h_fin

    float* W = (float*)d_ws;
    size_t o = 0;
    int*   ctrl     = (int*)(W + o); o += 64;            // [cnt0, cnt1]
    float* esum2    = W + o; o += 2*(size_t)B_*D_;       // parity sum r*Hcat[:,0:1024]
    float* Tmi2     = W + o; o += 2*(size_t)B_*G3_;      // parity sum r*Hcat[:,1024:4096]
    float* wsum2    = W + o; o += 16;                    // parity per-batch sum r
    float* gatepre  = W + o; o += 32;
    float* rowrole  = W + o; o += 2*BN_;
    float* sclbuf   = W + o; o += BN_;
    int*   list     = (int*)(W + o); o += 2*BN_;
    float* hbuf     = W + o; o += (size_t)BN_*D_;
    float* Hcat     = W + o; o += (size_t)BN_*HC7;
    float* pre_t2e  = W + o; o += (size_t)B_*S_*D_;
    float* gBm      = W + o; o += 4*G3_;
    float* Emi      = W + o; o += (size_t)B_*G3_;
    float* Esmi     = W + o; o += (size_t)B_*S_*G3_;
    float* arcsum   = W + o; o += (size_t)BN_*G3_;
    float* tmp      = W + o; o += (size_t)BN_*D_;        // P (init) and G (final)
    unsigned short* U = (unsigned short*)(W + o);
    size_t uo = 0;
    unsigned short* h16    = U + uo; uo += (size_t)BN_*D_;
    unsigned short* H16    = U + uo; uo += (size_t)B_*S_*D_;
    unsigned short* Wih16  = U + uo; uo += (size_t)G3_*D_;
    unsigned short* Whh16  = U + uo; uo += (size_t)G3_*D_;
    unsigned short* n2e16  = U + uo; uo += (size_t)D_*D_;
    unsigned short* eoW16  = U + uo; uo += (size_t)D_*D_;
    unsigned short* nW16   = U + uo; uo += (size_t)D_*ND_;
    unsigned short* nE16   = U + uo; uo += (size_t)BN_*ND_;
    unsigned short* t2e16  = U + uo; uo += (size_t)D_*D_;
    unsigned short* sc16   = U + uo; uo += (size_t)B_*S_*D_;
    unsigned short* WcatT16= U + uo; uo += (size_t)G3_*D_;
    unsigned short* Wmi16  = U + uo; uo += (size_t)G3_*G3_;
    unsigned short* bias4  = U + uo; uo += 4*D_;

    // zero ctrl + both parities of esum/Tmi/wsum in one shot
    hipMemsetAsync(ctrl, 0,
        (64 + 2*(size_t)B_*D_ + 2*(size_t)B_*G3_ + 16) * sizeof(float), stream);

    // ---- conversions (per call; inputs restored each timed call) ----
    #define CVT(src, dst, r, c, ld) \
        k_f2h<<<(((size_t)(r)*(c)/4 + 255)/256), 256, 0, stream>>>(src, dst, r, c, ld)
    CVT(Wih,   Wih16, G3_, D_,  D_);
    CVT(Whh,   Whh16, G3_, D_,  D_);
    CVT(n2eW,  n2e16, D_,  D_,  D_);
    CVT(nameW, nW16,  D_,  ND_, ND_);
    CVT(nemb,  nE16,  BN_, ND_, ND_);
    CVT(eoW,   eoW16, D_,  D_,  D_);
    CVT(t2eW,  t2e16, D_,  D_,  D_);
    CVT(scene, sc16,  B_*S_, D_, D_);
    CVT(msB,   bias4 + 0,    1, D_, D_);
    CVT(maB,   bias4 + D_,   1, D_, D_);
    CVT(miB,   bias4 + 2*D_, 1, D_, D_);
    CVT(rolew, bias4 + 3*D_, 1, D_, D_);
    #undef CVT
    // WcatT16[seg*1024 + k][d] = {ms,ma,mi}W[d][k]  (transposed, fp16)
    k_f2hT<<<dim3(32,32), 256, 0, stream>>>(msW, WcatT16, D_, D_, D_, 0);
    k_f2hT<<<dim3(32,32), 256, 0, stream>>>(maW, WcatT16, D_, D_, D_, D_);
    k_f2hT<<<dim3(32,32), 256, 0, stream>>>(miW, WcatT16, D_, D_, D_, 2*D_);

    // Wmi16 = 256 * (Wih @ Wcat)  [3072,3072] fp16 (cols: es|arc|int segs)
    k_mfma16_nt<<<dim3(G3_/128, G3_/64), 256, 0, stream>>>(
        Wih16, WcatT16, nullptr, nullptr, Wmi16, 256.f, G3_, G3_, D_);
    // gBm[4,3072] = [msB|maB|miB|rolew] @ Wih^T
    k_mfma16_nt<<<dim3(G3_/128, 1), 256, 0, stream>>>(
        bias4, Wih16, nullptr, gBm, nullptr, 1.f, 4, G3_, D_);
    // pre_t2e[b,s,:] = t2e(scene) + t2eb
    k_mfma16_nt<<<dim3(D_/128, (B_*S_+63)/64), 256, 0, stream>>>(
        sc16, t2e16, t2eb, pre_t2e, nullptr, 1.f, B_*S_, D_, D_);
    // init: P = name_embs @ name_W^T ; h0 ; Hcat0
    k_mfma16_nt<<<dim3(D_/128, (BN_+63)/64), 256, 0, stream>>>(
        nE16, nW16, nullptr, tmp, nullptr, 1.f, BN_, D_, ND_);
    k_h0<<<BN_, 256, 0, stream>>>(tmp, etype, emask, temb, nlg, nlb, hbuf, h16);
    k_hcat0<<<dim3(112, 25), 256, 0, stream>>>(h16, n2e16, Wmi16, Whh16, Hcat);

    for (int s = 0; s < S_; ++s) {
        int par = s & 1;
        int*   cntp = ctrl + par;
        int*   pcnt = ctrl + (1 - par);
        int*   lst  = list + par * BN_;
        int*   plst = list + (1 - par) * BN_;
        float* rro  = rowrole + par * BN_;
        float* esumP = esum2 + (size_t)par * B_*D_;
        float* esumZ = esum2 + (size_t)(1 - par) * B_*D_;
        float* TmiP  = Tmi2 + (size_t)par * B_*G3_;
        float* TmiZ  = Tmi2 + (size_t)(1 - par) * B_*G3_;
        float* wsumP = wsum2 + par * 8;
        float* wsumZ = wsum2 + (1 - par) * 8;
        k_front<<<BN_ + 112*26, 256, 0, stream>>>(inc, emask, Esmi, arcsum,
            cntp, lst, rro, sclbuf, pcnt, plst, h16, n2e16, Wmi16, Whh16,
            Hcat, gatepre, esumP, TmiP, wsumP, s);
        k_mid<<<224, 256, 0, stream>>>(esumP, wsumP, esumZ, TmiZ, wsumZ,
            n2eb, pre_t2e, elng, elnb, gW1, gb1, gW2, Wmi16,
            outH, gatepre, Emi, Esmi, ctrl, par, s);
        k_fin<<<BN_, 256, 0, stream>>>(lst, cntp, rro, sclbuf, gatepre, gb2,
            Hcat, Emi, arcsum, TmiP, gBm, bih, bhh, ulng, ulnb, hbuf, h16, s);
    }

    // epilogue: H = LN(gelu(LN(es + scene) @ eo_W^T + eo_b)); h_fin copy
    k_resln<<<B_*S_, 256, 0, stream>>>(outH, scene, rlng, rlnb, H16);
    k_mfma16_nt<<<dim3(D_/128, (B_*S_+63)/64), 256, 0, stream>>>(
        H16, eoW16, eoB, tmp, nullptr, 1.f, B_*S_, D_, D_);
    k_final<<<B_*S_ + BN_, 256, 0, stream>>>(tmp, eolng, eolnb, outH, hbuf, outh);
}